// Round 9
// baseline (1802.319 us; speedup 1.0000x reference)
//
#include <hip/hip_runtime.h>
#include <cstdint>
#include <cstddef>

#define NEG_INF (-3.0e38f)

typedef __attribute__((ext_vector_type(8))) short short8;
typedef __attribute__((ext_vector_type(4))) float f32x4;

__device__ inline unsigned short bf16_rne(float x) {
    unsigned u = __float_as_uint(x);
    unsigned r = u + 0x7fffu + ((u >> 16) & 1u);
    return (unsigned short)(r >> 16);
}
__device__ inline float bf16_tof(unsigned short h) {
    return __uint_as_float(((unsigned)h) << 16);
}

// ---------------- prep: normalize keys/hard + bf16 hi/lo split of hn ----------------
__global__ void prep_norm_k(const float* __restrict__ keys,
                            const float* __restrict__ hard,
                            float* __restrict__ knR,   // [800][128] normalized keys
                            float* __restrict__ hn,    // [800][128] normalized hard
                            unsigned short* __restrict__ hh,  // [800][128] bf16 hi
                            unsigned short* __restrict__ hl) {// [800][128] bf16 lo
    int m = blockIdx.x;      // 0..799
    int c = threadIdx.x;     // 0..127
    float kv = keys[m * 128 + c];
    float hv = hard[m * 128 + c];
    __shared__ float s1[128];
    __shared__ float s2[128];
    s1[c] = kv * kv;
    s2[c] = hv * hv;
    __syncthreads();
    for (int off = 64; off > 0; off >>= 1) {
        if (c < off) { s1[c] += s1[c + off]; s2[c] += s2[c + off]; }
        __syncthreads();
    }
    float ks = 1.0f / fmaxf(sqrtf(s1[0]), 1e-12f);
    float hs = 1.0f / fmaxf(sqrtf(s2[0]), 1e-12f);
    knR[m * 128 + c] = kv * ks;
    float hnv = hv * hs;
    hn[m * 128 + c] = hnv;
    unsigned short hi = bf16_rne(hnv);
    hh[m * 128 + c] = hi;
    hl[m * 128 + c] = bf16_rne(hnv - bf16_tof(hi));
}

__global__ void prep_c0_k(const float* __restrict__ values, float* __restrict__ c0) {
    int c = threadIdx.x;  // 128 threads
    float s = 0.f;
    for (int m = 0; m < 10; ++m) s += values[m * 128 + c];
    c0[c] = s * 0.1f;
}

// ---------------- center conv1+pool: only pooled rect [45,83)^2 ----------------
__global__ void ce1_k(const float* __restrict__ x,   // (16,1,256,256)
                      const float* __restrict__ w,   // (32,1,3,3)
                      const float* __restrict__ bias,
                      float* __restrict__ out) {     // (16,32,128,128) rect only
    int bx = blockIdx.x;            // 16 b * 2 cog * 6 tiles
    int b = bx / 12, rem = bx % 12;
    int cog = rem / 6, tile = rem % 6;
    int idx = tile * 256 + threadIdx.x;
    if (idx >= 1444) return;
    int ph = 45 + idx / 38, pw = 45 + idx % 38;
    const float* xb = x + (size_t)b * 65536;
    float win[4][4];
#pragma unroll
    for (int r = 0; r < 4; ++r) {
        int ih = 2 * ph - 1 + r;
        bool vr = (ih >= 96 && ih < 160);
#pragma unroll
        for (int c = 0; c < 4; ++c) {
            int iw = 2 * pw - 1 + c;
            win[r][c] = (vr && iw >= 96 && iw < 160) ? xb[ih * 256 + iw] : 0.f;
        }
    }
#pragma unroll
    for (int co8 = 0; co8 < 16; ++co8) {
        int co = cog * 16 + co8;
        const float* w9 = w + co * 9;
        float bv = bias[co];
        float a00 = bv, a01 = bv, a10 = bv, a11 = bv;
#pragma unroll
        for (int kh = 0; kh < 3; ++kh)
#pragma unroll
            for (int kw = 0; kw < 3; ++kw) {
                float wv = w9[kh * 3 + kw];
                a00 += win[kh][kw] * wv;
                a01 += win[kh][kw + 1] * wv;
                a10 += win[kh + 1][kw] * wv;
                a11 += win[kh + 1][kw + 1] * wv;
            }
        float mx = fmaxf(fmaxf(a00, a01), fmaxf(a10, a11));
        out[((size_t)b * 32 + co) * 16384 + ph * 128 + pw] = fmaxf(mx, 0.f);
    }
}

// ---------------- skip conv1+pool: full, 16 co per thread ----------------
__global__ void se1_k(const float* __restrict__ x,   // (16,1,256,256)
                      const float* __restrict__ w,   // (16,1,3,3)
                      const float* __restrict__ bias,
                      float* __restrict__ out) {     // (16,16,128,128)
    int bx = blockIdx.x;            // 16 b * 64 tiles
    int b = bx >> 6, tile = bx & 63;
    int idx = tile * 256 + threadIdx.x;   // 0..16383
    int ph = idx >> 7, pw = idx & 127;
    const float* xb = x + (size_t)b * 65536;
    float win[4][4];
#pragma unroll
    for (int r = 0; r < 4; ++r) {
        int ih = 2 * ph - 1 + r;
        bool vr = (ih >= 0 && ih < 256);
#pragma unroll
        for (int c = 0; c < 4; ++c) {
            int iw = 2 * pw - 1 + c;
            win[r][c] = (vr && iw >= 0 && iw < 256) ? xb[ih * 256 + iw] : 0.f;
        }
    }
#pragma unroll
    for (int co = 0; co < 16; ++co) {
        const float* w9 = w + co * 9;
        float bv = bias[co];
        float a00 = bv, a01 = bv, a10 = bv, a11 = bv;
#pragma unroll
        for (int kh = 0; kh < 3; ++kh)
#pragma unroll
            for (int kw = 0; kw < 3; ++kw) {
                float wv = w9[kh * 3 + kw];
                a00 += win[kh][kw] * wv;
                a01 += win[kh][kw + 1] * wv;
                a10 += win[kh + 1][kw] * wv;
                a11 += win[kh + 1][kw + 1] * wv;
            }
        float mx = fmaxf(fmaxf(a00, a01), fmaxf(a10, a11));
        out[((size_t)b * 16 + co) * 16384 + idx] = fmaxf(mx, 0.f);
    }
}

// ---------------- center conv2 v3 (32->128) + relu + pool -> query-major zcq ----------------
__global__ void __launch_bounds__(256) ce2_v3(
        const float* __restrict__ zc1,  // (16,32,128,128)
        const float* __restrict__ w,    // (128,32,3,3)
        const float* __restrict__ bias,
        float* __restrict__ zcq) {      // (16*324, 128) query-major
    int bx = blockIdx.x;                // 16 b * 16 cog
    int b = bx >> 4, cog = bx & 15;
    const float* ib = zc1 + (size_t)b * 32 * 16384;
    for (int px = threadIdx.x; px < 324; px += 256) {
        int h = 23 + px / 18, ww = 23 + px % 18;
        float acc[8][4];
#pragma unroll
        for (int c8 = 0; c8 < 8; ++c8)
#pragma unroll
            for (int t = 0; t < 4; ++t) acc[c8][t] = 0.f;
        for (int ci = 0; ci < 32; ++ci) {
            const float* p = ib + ci * 16384 + (2 * h - 1) * 128 + (2 * ww - 1);
            float win[4][4];
#pragma unroll
            for (int r = 0; r < 4; ++r)
#pragma unroll
                for (int s = 0; s < 4; ++s) win[r][s] = p[r * 128 + s];
#pragma unroll
            for (int c8 = 0; c8 < 8; ++c8) {
                const float* w9 = w + ((size_t)(cog * 8 + c8) * 32 + ci) * 9;
#pragma unroll
                for (int kh = 0; kh < 3; ++kh)
#pragma unroll
                    for (int kw = 0; kw < 3; ++kw) {
                        float wv = w9[kh * 3 + kw];
                        acc[c8][0] += win[kh][kw] * wv;
                        acc[c8][1] += win[kh][kw + 1] * wv;
                        acc[c8][2] += win[kh + 1][kw] * wv;
                        acc[c8][3] += win[kh + 1][kw + 1] * wv;
                    }
            }
        }
#pragma unroll
        for (int c8 = 0; c8 < 8; ++c8) {
            int co = cog * 8 + c8;
            float mx = fmaxf(fmaxf(acc[c8][0], acc[c8][1]), fmaxf(acc[c8][2], acc[c8][3])) + bias[co];
            zcq[((size_t)(b * 324 + px)) * 128 + co] = fmaxf(mx, 0.f);
        }
    }
}

// ---------------- skip conv2 (16->128) + relu + pool, 8 co per thread ----------------
__global__ void se2_v2(const float* __restrict__ zs1,  // (16,16,128,128)
                       const float* __restrict__ w,    // (128,16,3,3)
                       const float* __restrict__ bias,
                       float* __restrict__ zs) {       // (16,128,64,64)
    int bx = blockIdx.x;            // 16 b * 16 cog * 16 tiles = 4096
    int b = bx >> 8, rem = bx & 255;
    int cog = rem >> 4, tile = rem & 15;
    int px = tile * 256 + threadIdx.x;  // 0..4095
    int ph = px >> 6, pw = px & 63;
    const float* ib = zs1 + (size_t)b * 16 * 16384;
    float acc[8][4];
#pragma unroll
    for (int c8 = 0; c8 < 8; ++c8)
#pragma unroll
        for (int t = 0; t < 4; ++t) acc[c8][t] = 0.f;
    for (int ci = 0; ci < 16; ++ci) {
        const float* p = ib + ci * 16384;
        float win[4][4];
#pragma unroll
        for (int r = 0; r < 4; ++r) {
            int rr = 2 * ph - 1 + r;
            bool vr = (rr >= 0 && rr < 128);
#pragma unroll
            for (int s = 0; s < 4; ++s) {
                int cc = 2 * pw - 1 + s;
                win[r][s] = (vr && cc >= 0 && cc < 128) ? p[rr * 128 + cc] : 0.f;
            }
        }
#pragma unroll
        for (int c8 = 0; c8 < 8; ++c8) {
            const float* w9 = w + ((size_t)(cog * 8 + c8) * 16 + ci) * 9;
#pragma unroll
            for (int kh = 0; kh < 3; ++kh)
#pragma unroll
                for (int kw = 0; kw < 3; ++kw) {
                    float wv = w9[kh * 3 + kw];
                    acc[c8][0] += win[kh][kw] * wv;
                    acc[c8][1] += win[kh][kw + 1] * wv;
                    acc[c8][2] += win[kh + 1][kw] * wv;
                    acc[c8][3] += win[kh + 1][kw + 1] * wv;
                }
        }
    }
#pragma unroll
    for (int c8 = 0; c8 < 8; ++c8) {
        int co = cog * 8 + c8;
        float bv = bias[co];
        float mx = fmaxf(fmaxf(acc[c8][0], acc[c8][1]), fmaxf(acc[c8][2], acc[c8][3])) + bv;
        zs[((size_t)b * 128 + co) * 4096 + px] = fmaxf(mx, 0.f);
    }
}

// ---------------- center matching v2 (unchanged) ----------------
__global__ void __launch_bounds__(256) match_center_v2(
        const float* __restrict__ zcq,    // (16*324, 128) raw queries
        const float* __restrict__ knR,    // (800,128) normalized keys
        const float* __restrict__ values, // (800,128)
        float* __restrict__ dcat) {       // (16,256,64,64), ch 0..127
    __shared__ float shk[128 * 65];
    __shared__ float qint[4 * 256];
    int tid = threadIdx.x;
    int w = tid >> 6, lane = tid & 63;
    int g0 = blockIdx.x * 8 + 2 * w;

#pragma unroll
    for (int i = 0; i < 2; ++i) {
        const float* qp = zcq + (size_t)(g0 + i) * 128;
        float v0 = qp[lane], v1 = qp[lane + 64];
        float ss = v0 * v0 + v1 * v1;
#pragma unroll
        for (int off = 32; off > 0; off >>= 1) ss += __shfl_xor(ss, off);
        float sc = 1.0f / fmaxf(sqrtf(ss), 1e-12f);
        qint[w * 256 + lane * 2 + i] = v0 * sc;
        qint[w * 256 + (lane + 64) * 2 + i] = v1 * sc;
    }

    float sim2[2][13];
#pragma unroll
    for (int k = 0; k < 13; ++k) { sim2[0][k] = 0.f; sim2[1][k] = 0.f; }

    for (int chunk = 0; chunk < 13; ++chunk) {
        int mbase = chunk << 6;
        __syncthreads();
#pragma unroll
        for (int t = 0; t < 8; ++t) {
            int idx = tid + t * 256;
            int kk = idx >> 5, c4 = idx & 31;
            int m = mbase + kk;
            float4 kv = (m < 800) ? *(const float4*)(knR + (size_t)m * 128 + c4 * 4)
                                  : make_float4(0.f, 0.f, 0.f, 0.f);
            shk[(4 * c4 + 0) * 65 + kk] = kv.x;
            shk[(4 * c4 + 1) * 65 + kk] = kv.y;
            shk[(4 * c4 + 2) * 65 + kk] = kv.z;
            shk[(4 * c4 + 3) * 65 + kk] = kv.w;
        }
        __syncthreads();
        float s0 = sim2[0][chunk], s1 = sim2[1][chunk];
        const float* qw = qint + w * 256;
#pragma unroll 4
        for (int c2 = 0; c2 < 64; ++c2) {
            float4 qq = *(const float4*)(qw + c2 * 4);
            float k0 = shk[(2 * c2) * 65 + lane];
            float k1 = shk[(2 * c2 + 1) * 65 + lane];
            s0 += qq.x * k0; s1 += qq.y * k0;
            s0 += qq.z * k1; s1 += qq.w * k1;
        }
        sim2[0][chunk] = s0; sim2[1][chunk] = s1;
    }

#pragma unroll
    for (int i = 0; i < 2; ++i) {
        int g = g0 + i;
        int b = g / 324, q = g - b * 324;
        int h = 23 + q / 18, ww = 23 + q % 18;
        int p = h * 64 + ww;

        float sim[13];
#pragma unroll
        for (int k = 0; k < 13; ++k)
            sim[k] = (lane + (k << 6) < 800) ? sim2[i][k] : NEG_INF;

        float topv[11]; int topm[11];
#pragma unroll
        for (int t = 0; t < 11; ++t) {
            float bvv = NEG_INF; int bm = 0x7fffffff;
#pragma unroll
            for (int k = 0; k < 13; ++k) {
                if (sim[k] > bvv) { bvv = sim[k]; bm = lane + (k << 6); }
            }
#pragma unroll
            for (int off = 32; off > 0; off >>= 1) {
                float ov = __shfl_xor(bvv, off);
                int om = __shfl_xor(bm, off);
                if (ov > bvv || (ov == bvv && om < bm)) { bvv = ov; bm = om; }
            }
            topv[t] = bvv; topm[t] = bm;
            if ((bm & 63) == lane) {
                int kk = bm >> 6;
#pragma unroll
                for (int k = 0; k < 13; ++k)
                    if (k == kk) sim[k] = NEG_INF;
            }
        }
        if (topv[9] - topv[10] < 1e-4f) {
            double s9 = 0.0, s10 = 0.0;
            const float* k9 = knR + (size_t)topm[9] * 128;
            const float* k10 = knR + (size_t)topm[10] * 128;
            for (int c = 0; c < 128; ++c) {
                double qc = (double)qint[w * 256 + c * 2 + i];
                s9 += qc * (double)k9[c];
                s10 += qc * (double)k10[c];
            }
            if ((s10 > s9) || (s10 == s9 && topm[10] < topm[9])) {
                topv[9] = topv[10]; topm[9] = topm[10];
            }
        }
        float mx = topv[0];
        float e[10], ssum = 0.f;
#pragma unroll
        for (int t = 0; t < 10; ++t) { e[t] = expf(topv[t] - mx); ssum += e[t]; }
        float inv = 1.0f / ssum;
        float o0 = 0.f, o1 = 0.f;
#pragma unroll
        for (int t = 0; t < 10; ++t) {
            float wt = e[t] * inv;
            const float* vr = values + (size_t)topm[t] * 128;
            o0 += wt * vr[lane];
            o1 += wt * vr[lane + 64];
        }
        float* ob = dcat + ((size_t)b * 256) * 4096 + p;
        ob[(size_t)lane * 4096] = o0;
        ob[(size_t)(lane + 64) * 4096] = o1;
    }
}

// ---------------- constant fill for out-of-region center matches ----------------
__global__ void fill_c0_k(const float* __restrict__ c0, float* __restrict__ dcat) {
    int idx = blockIdx.x * 256 + threadIdx.x;
    int p = idx & 4095;
    int c = (idx >> 12) & 127;
    int b = idx >> 19;
    int h = p >> 6, ww = p & 63;
    if (h >= 23 && h <= 40 && ww >= 23 && ww <= 40) return;
    dcat[((size_t)b * 256 + c) * 4096 + p] = c0[c];
}

// ---------------- skip matching v5: split-bf16 MFMA, windowed exact rescore ----------------
// 64 q x 800 k per block. sim = qhi*khi + qhi*klo + qlo*khi via mfma_f32_16x16x32_bf16.
__global__ void __launch_bounds__(256, 2) match_skip_v5(
        const float* __restrict__ zs,    // (16,128,64,64) raw queries
        const float* __restrict__ hn,    // (800,128) normalized fp32 (rescore)
        const unsigned short* __restrict__ hh,  // (800,128) bf16 hi
        const unsigned short* __restrict__ hl,  // (800,128) bf16 lo
        const float* __restrict__ hard,  // (800,128) raw
        float* __restrict__ dcat) {      // ch 128..255
    __shared__ unsigned short sm[32768]; // 64KB: qhi[0:8192] qlo[8192:16384] khi[16384:24576] klo[24576:32768]
    int b = blockIdx.x >> 6, pt = blockIdx.x & 63;
    int pbase = pt * 64;
    int tid = threadIdx.x;
    int w = tid >> 6, lane = tid & 63;
    int l15 = lane & 15, quad = lane >> 4;

    // ---- stage queries (bf16 hi/lo, XOR-swizzled at 16B) ----
    {
        int p = tid & 63, c0 = tid >> 6;
        for (int k = 0; k < 32; ++k) {
            int c = c0 + k * 4;
            float v = zs[((size_t)b * 128 + c) * 4096 + pbase + p];
            unsigned short hi = bf16_rne(v);
            unsigned short lo = bf16_rne(v - bf16_tof(hi));
            int off = p * 128 + (((c >> 3) ^ (p & 15)) << 3) + (c & 7);
            sm[off] = hi;
            sm[8192 + off] = lo;
        }
    }

    float v1[4], v2[4]; int i1[4], i2[4];
#pragma unroll
    for (int u = 0; u < 4; ++u) { v1[u] = NEG_INF; v2[u] = NEG_INF; i1[u] = 0x7fffffff; i2[u] = 0x7fffffff; }

    for (int chunk = 0; chunk < 13; ++chunk) {
        int mbase = chunk << 6;
        __syncthreads();
        // stage 64 keys hi/lo (coalesced 16B reads, swizzled 16B writes)
#pragma unroll
        for (int t = 0; t < 4; ++t) {
            int idx = tid + t * 256;          // 0..1023
            int row = idx >> 4, cb = idx & 15;
            int gm = mbase + row;
            uint4 dh = make_uint4(0u, 0u, 0u, 0u), dl = make_uint4(0u, 0u, 0u, 0u);
            if (gm < 800) {
                dh = *(const uint4*)(hh + (size_t)gm * 128 + cb * 8);
                dl = *(const uint4*)(hl + (size_t)gm * 128 + cb * 8);
            }
            int off = row * 128 + ((cb ^ (row & 15)) << 3);
            *(uint4*)&sm[16384 + off] = dh;
            *(uint4*)&sm[24576 + off] = dl;
        }
        __syncthreads();

        f32x4 acc[4];
#pragma unroll
        for (int kt = 0; kt < 4; ++kt) acc[kt] = (f32x4){0.f, 0.f, 0.f, 0.f};

#pragma unroll
        for (int ks = 0; ks < 4; ++ks) {
            int qrow = 16 * w + l15;
            int cb = ks * 4 + quad;
            int qoff = qrow * 128 + ((cb ^ (qrow & 15)) << 3);
            short8 ahi = *(const short8*)&sm[qoff];
            short8 alo = *(const short8*)&sm[8192 + qoff];
#pragma unroll
            for (int kt = 0; kt < 4; ++kt) {
                int krow = l15 + 16 * kt;
                int koff = krow * 128 + ((cb ^ (krow & 15)) << 3);
                short8 bhi = *(const short8*)&sm[16384 + koff];
                short8 blo = *(const short8*)&sm[24576 + koff];
                acc[kt] = __builtin_amdgcn_mfma_f32_16x16x32_bf16(alo, bhi, acc[kt], 0, 0, 0);
                acc[kt] = __builtin_amdgcn_mfma_f32_16x16x32_bf16(ahi, blo, acc[kt], 0, 0, 0);
                acc[kt] = __builtin_amdgcn_mfma_f32_16x16x32_bf16(ahi, bhi, acc[kt], 0, 0, 0);
            }
        }
        // per-lane top-2 update: lane's query u: 16w+quad*4+u; key: mbase+16kt+l15
#pragma unroll
        for (int kt = 0; kt < 4; ++kt) {
            int m = mbase + 16 * kt + l15;
            if (m < 800) {
#pragma unroll
                for (int u = 0; u < 4; ++u) {
                    float sv = acc[kt][u];
                    if (sv > v1[u] || (sv == v1[u] && m < i1[u])) {
                        v2[u] = v1[u]; i2[u] = i1[u]; v1[u] = sv; i1[u] = m;
                    } else if (sv > v2[u] || (sv == v2[u] && m < i2[u])) {
                        v2[u] = sv; i2[u] = m;
                    }
                }
            }
        }
    }
    __syncthreads();
    // cross-slot reduction scratch over key region
    float4* red = (float4*)&sm[16384];   // [64 q][17 slots] float4 = 17408 B = 8704 shorts
#pragma unroll
    for (int u = 0; u < 4; ++u) {
        int q = 16 * w + quad * 4 + u;
        red[q * 17 + l15] = make_float4(v1[u], v2[u], __int_as_float(i1[u]), __int_as_float(i2[u]));
    }
    __syncthreads();
    // FIX (R8 bug): sm is indexed in SHORTS; red spans 8704 shorts, so scratch
    // starts at sm[16384 + 8704] (byte 50176), NOT 16384 + 8704*2 (OOB past 64KB).
    int* bi_sh = (int*)&sm[16384 + 8704];  // [64] ints = 256 B, ends at byte 50432
    if (tid < 64) {
        int q = tid;
        // pass 1: approx max
        float V1 = NEG_INF; int I1 = 0x7fffffff;
        for (int k = 0; k < 16; ++k) {
            float4 e = red[q * 17 + k];
            float cv[2] = { e.x, e.y };
            int ci_[2] = { __float_as_int(e.z), __float_as_int(e.w) };
#pragma unroll
            for (int t = 0; t < 2; ++t) {
                if (cv[t] > V1 || (cv[t] == V1 && ci_[t] < I1)) { V1 = cv[t]; I1 = ci_[t]; }
            }
        }
        // qn2 from bf16 (guard width only)
        float qn2 = 0.f;
        for (int c = 0; c < 128; ++c) {
            int off = q * 128 + (((c >> 3) ^ (q & 15)) << 3) + (c & 7);
            float qc = bf16_tof(sm[off]) + bf16_tof(sm[8192 + off]);
            qn2 += qc * qc;
        }
        float tau = 1.5e-4f * sqrtf(qn2) + 1e-12f;
        float thr = V1 - tau;
        // count candidates within the window
        int ncand = 0;
        for (int k = 0; k < 16; ++k) {
            float4 e = red[q * 17 + k];
            if (e.x >= thr && __float_as_int(e.z) != 0x7fffffff) ++ncand;
            if (e.y >= thr && __float_as_int(e.w) != 0x7fffffff) ++ncand;
        }
        int bi = I1;
        if (ncand > 1) {  // exact fp64 rescore of every candidate (exact q from global)
            double bestd = -1.0e300; int besti = 0x7fffffff;
            for (int k = 0; k < 16; ++k) {
                float4 e = red[q * 17 + k];
                float cv[2] = { e.x, e.y };
                int ci_[2] = { __float_as_int(e.z), __float_as_int(e.w) };
                for (int t = 0; t < 2; ++t) {
                    if (cv[t] >= thr && ci_[t] != 0x7fffffff) {
                        const float* hr = hn + (size_t)ci_[t] * 128;
                        double d = 0.0;
                        for (int c = 0; c < 128; ++c) {
                            double qc = (double)zs[((size_t)b * 128 + c) * 4096 + pbase + q];
                            d += qc * (double)hr[c];
                        }
                        if (d > bestd || (d == bestd && ci_[t] < besti)) { bestd = d; besti = ci_[t]; }
                    }
                }
            }
            bi = besti;
        }
        bi_sh[q] = bi;
    }
    __syncthreads();
    // coalesced epilogue: channel-major writes
    {
        int q = tid & 63, seg = tid >> 6;
        int bi = bi_sh[q];
        const float* hr = hard + (size_t)bi * 128;
        float* ob = dcat + ((size_t)b * 256 + 128) * 4096 + pbase + q;
#pragma unroll
        for (int i = 0; i < 32; ++i) {
            int c = seg * 32 + i;
            ob[(size_t)c * 4096] = hr[c];
        }
    }
}

// ---------------- decoder conv1 v5: weight-staged LDS, 4 px/thread, K-split 4 ----------------
__global__ void __launch_bounds__(256, 3) dec1_v5(
        const float* __restrict__ dcat, // (16,256,64,64)
        const float* __restrict__ w,    // (64,256,3,3)
        float* __restrict__ pA, float* __restrict__ pB,
        float* __restrict__ pC, float* __restrict__ pD) {
    __shared__ float xs[2][4760];       // 4 ci x 34x35 halo tile
    __shared__ float wsh[2][768];       // 4 ci x 16 co x 12
    int bx = blockIdx.x;                // 16b * 4cog * 4tiles * 4ks = 1024
    int b = bx >> 6, rem = bx & 63;
    int cog = rem >> 4, tile = (rem >> 2) & 3, ks = rem & 3;
    int ph0 = (tile >> 1) * 32, pw0 = (tile & 1) * 32;
    int tid = threadIdx.x;
    int pr = tid >> 4, pc = tid & 15;

    const float* ib = dcat + ((size_t)b * 256 + (size_t)ks * 64) * 4096;
    const float* wb = w + (size_t)(cog * 16) * 2304 + (size_t)ks * 64 * 9;

    int xg[19];
#pragma unroll
    for (int k = 0; k < 19; ++k) {
        int f = tid + k * 256;
        xg[k] = -1;
        if (f < 4760) {
            int ci_l = f / 1190, pos = f % 1190;
            int r = pos / 35, c = pos % 35;
            int row = ph0 - 1 + r, col = pw0 - 1 + c;
            if (c < 34 && row >= 0 && row < 64 && col >= 0 && col < 64)
                xg[k] = ci_l * 4096 + row * 64 + col;
        }
    }
    int wg[3], wl[3];
#pragma unroll
    for (int k = 0; k < 3; ++k) {
        int t = tid + k * 256;
        wg[k] = -1; wl[k] = 0;
        if (t < 576) {
            int ci_l = t / 144, r2 = t % 144;
            int co = r2 / 9, j = r2 % 9;
            wg[k] = co * 2304 + ci_l * 9 + j;
            wl[k] = ci_l * 192 + co * 12 + j;
        }
    }

#pragma unroll
    for (int k = 0; k < 19; ++k) {
        int f = tid + k * 256;
        if (f < 4760) xs[0][f] = (xg[k] >= 0) ? ib[xg[k]] : 0.f;
    }
#pragma unroll
    for (int k = 0; k < 3; ++k)
        if (wg[k] >= 0) wsh[0][wl[k]] = wb[wg[k]];
    __syncthreads();

    float acc[16][4];
#pragma unroll
    for (int co = 0; co < 16; ++co)
#pragma unroll
        for (int q = 0; q < 4; ++q) acc[co][q] = 0.f;

    for (int chunk = 0; chunk < 16; ++chunk) {
        int cur = chunk & 1;
        float pfx[19], pfw[3];
        if (chunk < 15) {
            const float* ibn = ib + (size_t)(chunk + 1) * 4 * 4096;
            const float* wbn = wb + (chunk + 1) * 36;
#pragma unroll
            for (int k = 0; k < 19; ++k) {
                int f = tid + k * 256;
                if (f < 4760) pfx[k] = (xg[k] >= 0) ? ibn[xg[k]] : 0.f;
            }
#pragma unroll
            for (int k = 0; k < 3; ++k)
                if (wg[k] >= 0) pfw[k] = wbn[wg[k]];
        }
#pragma unroll 2
        for (int ci_l = 0; ci_l < 4; ++ci_l) {
            const float* xp = &xs[cur][ci_l * 1190 + (2 * pr) * 35 + 2 * pc];
            float xw[4][4];
#pragma unroll
            for (int r = 0; r < 4; ++r)
#pragma unroll
                for (int c = 0; c < 4; ++c) xw[r][c] = xp[r * 35 + c];
            const float* wp = &wsh[cur][ci_l * 192];
#pragma unroll
            for (int co = 0; co < 16; ++co) {
                float4 w0 = *(const float4*)(wp + co * 12);
                float4 w1 = *(const float4*)(wp + co * 12 + 4);
                float4 w2 = *(const float4*)(wp + co * 12 + 8);
                float wv[9] = { w0.x, w0.y, w0.z, w0.w, w1.x, w1.y, w1.z, w1.w, w2.x };
#pragma unroll
                for (int q = 0; q < 4; ++q) {
                    int qr = q >> 1, qc = q & 1;
                    float s = acc[co][q];
#pragma unroll
                    for (int kh = 0; kh < 3; ++kh)
#pragma unroll
                        for (int kw = 0; kw < 3; ++kw)
                            s += xw[qr + kh][qc + kw] * wv[kh * 3 + kw];
                    acc[co][q] = s;
                }
            }
        }
        if (chunk < 15) {
#pragma unroll
            for (int k = 0; k < 19; ++k) {
                int f = tid + k * 256;
                if (f < 4760) xs[1 - cur][f] = pfx[k];
            }
#pragma unroll
            for (int k = 0; k < 3; ++k)
                if (wg[k] >= 0) wsh[1 - cur][wl[k]] = pfw[k];
            __syncthreads();
        }
    }
    float* base = (ks == 0) ? pA : (ks == 1) ? pB : (ks == 2) ? pC : pD;
    float* ob = base + ((size_t)b * 64 + cog * 16) * 4096;
#pragma unroll
    for (int co = 0; co < 16; ++co)
#pragma unroll
        for (int q = 0; q < 4; ++q) {
            int row = ph0 + 2 * pr + (q >> 1), col = pw0 + 2 * pc + (q & 1);
            ob[(size_t)co * 4096 + row * 64 + col] = acc[co][q];
        }
}

// ---------------- dec1 partial reduce: d1 = relu(pA+pB+pC+pD + bias), in-place over pA ----------------
__global__ void dec1_add_k4(float* __restrict__ pA, const float* __restrict__ pB,
                            const float* __restrict__ pC, const float* __restrict__ pD,
                            const float* __restrict__ bias) {
    int idx = blockIdx.x * 256 + threadIdx.x;  // 4194304
    int c = (idx >> 12) & 63;
    float v = pA[idx] + pB[idx] + pC[idx] + pD[idx] + bias[c];
    pA[idx] = fmaxf(v, 0.f);
}

// ---------------- transposed conv v2: quad-parity, 16 co per thread ----------------
template <int CIN, int COUT, int COG, int H>
__global__ void __launch_bounds__(256) tconv_v2(
        const float* __restrict__ x,   // (16,CIN,H,H)
        const float* __restrict__ w,   // (CIN,COUT,4,4)
        const float* __restrict__ bias,
        float* __restrict__ out) {     // (16,COUT,2H,2H)
    constexpr int NCOG = COUT / COG;
    constexpr int TPS = H / 16;
    constexpr int TILES = TPS * TPS;
    constexpr int HO = 2 * H;
    int bx = blockIdx.x;
    int b = bx / (NCOG * TILES), rem = bx % (NCOG * TILES);
    int cog = rem / TILES, tile = rem % TILES;
    int ti = tile / TPS, tj = tile % TPS;
    int tid = threadIdx.x;
    int i = ti * 16 + (tid >> 4);
    int j = tj * 16 + (tid & 15);

    float acc[2][2][COG];
#pragma unroll
    for (int pr = 0; pr < 2; ++pr)
#pragma unroll
        for (int pc = 0; pc < 2; ++pc)
#pragma unroll
            for (int co = 0; co < COG; ++co) acc[pr][pc][co] = 0.f;

    const float* xb = x + (size_t)b * CIN * H * H;
    for (int ci = 0; ci < CIN; ++ci) {
        const float* xp = xb + (size_t)ci * H * H;
        float xr[3][3];
#pragma unroll
        for (int dr = 0; dr < 3; ++dr) {
            int gr = i - 1 + dr;
            bool vr = (gr >= 0 && gr < H);
#pragma unroll
            for (int dc = 0; dc < 3; ++dc) {
                int gc = j - 1 + dc;
                xr[dr][dc] = (vr && gc >= 0 && gc < H) ? xp[gr * H + gc] : 0.f;
            }
        }
#pragma unroll
        for (int co = 0; co < COG; ++co) {
            const float* wp = w + (((size_t)ci * COUT + cog * COG + co) << 4);
            float wr[16];
#pragma unroll
            for (int k = 0; k < 16; ++k) wr[k] = wp[k];
#pragma unroll
            for (int pr = 0; pr < 2; ++pr)
#pragma unroll
                for (int a = 0; a < 2; ++a)
#pragma unroll
                    for (int pc = 0; pc < 2; ++pc)
#pragma unroll
                        for (int bb = 0; bb < 2; ++bb)
                            acc[pr][pc][co] += xr[pr + a][pc + bb] *
                                               wr[(3 - pr - 2 * a) * 4 + (3 - pc - 2 * bb)];
        }
    }
#pragma unroll
    for (int co = 0; co < COG; ++co) {
        float bv = bias[cog * COG + co];
        float* ob = out + ((size_t)b * COUT + cog * COG + co) * HO * HO;
#pragma unroll
        for (int pr = 0; pr < 2; ++pr)
#pragma unroll
            for (int pc = 0; pc < 2; ++pc)
                ob[(2 * i + pr) * HO + 2 * j + pc] = fmaxf(acc[pr][pc][co] + bv, 0.f);
    }
}

// ---------------- final conv (16->1) 3x3, 4 px per thread ----------------
__global__ void final_v2(const float* __restrict__ t2,  // (16,16,256,256)
                         const float* __restrict__ w,   // (1,16,3,3)
                         const float* __restrict__ bias,
                         float* __restrict__ out) {     // (16,1,256,256)
    int g = blockIdx.x * 256 + threadIdx.x;
    int pxb = g * 4;
    int b = pxb >> 16, p = pxb & 65535;
    int h = p >> 8, c0 = p & 255;
    const float* tb = t2 + (size_t)b * 16 * 65536;
    float acc[4];
    float bv = bias[0];
#pragma unroll
    for (int t = 0; t < 4; ++t) acc[t] = bv;
    for (int ci = 0; ci < 16; ++ci) {
        const float* pp = tb + (size_t)ci * 65536;
        const float* w9 = w + ci * 9;
        float win[3][6];
#pragma unroll
        for (int dr = 0; dr < 3; ++dr) {
            int rr = h - 1 + dr;
            bool vr = (rr >= 0 && rr < 256);
#pragma unroll
            for (int dc = 0; dc < 6; ++dc) {
                int cc = c0 - 1 + dc;
                win[dr][dc] = (vr && cc >= 0 && cc < 256) ? pp[rr * 256 + cc] : 0.f;
            }
        }
#pragma unroll
        for (int t = 0; t < 4; ++t)
#pragma unroll
            for (int dr = 0; dr < 3; ++dr)
#pragma unroll
                for (int dc = 0; dc < 3; ++dc)
                    acc[t] += win[dr][t + dc] * w9[dr * 3 + dc];
    }
    *(float4*)(out + pxb) = make_float4(acc[0], acc[1], acc[2], acc[3]);
}

// ---------------- launch ----------------
extern "C" void kernel_launch(void* const* d_in, const int* in_sizes, int n_in,
                              void* d_out, int out_size, void* d_ws, size_t ws_size,
                              hipStream_t stream) {
    (void)in_sizes; (void)n_in; (void)out_size; (void)ws_size;
    const float* x     = (const float*)d_in[0];
    const float* cw1   = (const float*)d_in[1];
    const float* cb1   = (const float*)d_in[2];
    const float* cw2   = (const float*)d_in[3];
    const float* cb2   = (const float*)d_in[4];
    const float* sw1   = (const float*)d_in[5];
    const float* sb1   = (const float*)d_in[6];
    const float* sw2   = (const float*)d_in[7];
    const float* sb2   = (const float*)d_in[8];
    const float* mkeys = (const float*)d_in[9];
    const float* mvals = (const float*)d_in[10];
    const float* mhard = (const float*)d_in[11];
    const float* dw1   = (const float*)d_in[12];
    const float* db1   = (const float*)d_in[13];
    const float* tw1   = (const float*)d_in[14];
    const float* tb1   = (const float*)d_in[15];
    const float* tw2   = (const float*)d_in[16];
    const float* tb2   = (const float*)d_in[17];
    const float* dw2   = (const float*)d_in[18];
    const float* db2   = (const float*)d_in[19];
    float* out = (float*)d_out;
    float* ws  = (float*)d_ws;

    const size_t OFF_KN  = 0;                   // knR: 800*128
    const size_t OFF_HN  = 102400;              // hn:  800*128
    const size_t OFF_C0  = 204800;              // c0:  128
    const size_t OFF_R14 = 204928;              // zc1 -> zs -> (pC|pD) -> t1
    const size_t OFF_R2  = OFF_R14 + 8388608;   // dec1 partial B
    const size_t OFF_R3  = OFF_R2 + 8388608;    // zs1 -> dec1 partial A / d1
    const size_t OFF_R5  = OFF_R3 + 4194304;    // dcat -> t2
    const size_t OFF_ZCQ = OFF_R5 + 16777216;   // zcq: 16*324*128
    const size_t OFF_HH  = OFF_ZCQ + 663552;    // hh: 800*128 u16 = 51200 floats
    const size_t OFF_HL  = OFF_HH + 51200;      // hl: 51200 floats

    float* knR  = ws + OFF_KN;
    float* hn   = ws + OFF_HN;
    float* c0   = ws + OFF_C0;
    float* zc1  = ws + OFF_R14;
    float* zs   = ws + OFF_R14;
    float* t1   = ws + OFF_R14;
    float* pC   = ws + OFF_R14;                 // zs dead after match_skip
    float* pD   = ws + OFF_R14 + 4194304;
    float* pB   = ws + OFF_R2;
    float* zs1  = ws + OFF_R3;
    float* d1b  = ws + OFF_R3;
    float* dcat = ws + OFF_R5;
    float* t2   = ws + OFF_R5;
    float* zcq  = ws + OFF_ZCQ;
    unsigned short* hhp = (unsigned short*)(ws + OFF_HH);
    unsigned short* hlp = (unsigned short*)(ws + OFF_HL);

    prep_norm_k<<<800, 128, 0, stream>>>(mkeys, mhard, knR, hn, hhp, hlp);
    prep_c0_k<<<1, 128, 0, stream>>>(mvals, c0);

    ce1_k<<<16 * 2 * 6, 256, 0, stream>>>(x, cw1, cb1, zc1);
    se1_k<<<16 * 64, 256, 0, stream>>>(x, sw1, sb1, zs1);
    ce2_v3<<<16 * 16, 256, 0, stream>>>(zc1, cw2, cb2, zcq);
    se2_v2<<<16 * 16 * 16, 256, 0, stream>>>(zs1, sw2, sb2, zs);  // overwrites zc1 (dead)

    match_center_v2<<<648, 256, 0, stream>>>(zcq, knR, mvals, dcat);
    fill_c0_k<<<32768, 256, 0, stream>>>(c0, dcat);
    match_skip_v5<<<16 * 64, 256, 0, stream>>>(zs, hn, hhp, hlp, mhard, dcat);

    dec1_v5<<<1024, 256, 0, stream>>>(dcat, dw1, d1b, pB, pC, pD);  // pC/pD overwrite zs (dead)
    dec1_add_k4<<<16384, 256, 0, stream>>>(d1b, pB, pC, pD, db1);

    tconv_v2<64, 32, 16, 64><<<16 * 2 * 16, 256, 0, stream>>>(d1b, tw1, tb1, t1);   // overwrites pC/pD (dead)
    tconv_v2<32, 16, 16, 128><<<16 * 1 * 64, 256, 0, stream>>>(t1, tw2, tb2, t2);   // overwrites dcat (dead)
    final_v2<<<1024, 256, 0, stream>>>(t2, dw2, db2, out);
}

// Round 10
// 1190.195 us; speedup vs baseline: 1.5143x; 1.5143x over previous
//
#include <hip/hip_runtime.h>
#include <cstdint>
#include <cstddef>

#define NEG_INF (-3.0e38f)

typedef __attribute__((ext_vector_type(8))) short short8;
typedef __attribute__((ext_vector_type(4))) float f32x4;

__device__ inline unsigned short bf16_rne(float x) {
    unsigned u = __float_as_uint(x);
    unsigned r = u + 0x7fffu + ((u >> 16) & 1u);
    return (unsigned short)(r >> 16);
}
__device__ inline float bf16_tof(unsigned short h) {
    return __uint_as_float(((unsigned)h) << 16);
}

// ---------------- prep: normalize keys/hard + bf16 hi/lo split of hn ----------------
__global__ void prep_norm_k(const float* __restrict__ keys,
                            const float* __restrict__ hard,
                            float* __restrict__ knR,   // [800][128] normalized keys
                            float* __restrict__ hn,    // [800][128] normalized hard
                            unsigned short* __restrict__ hh,  // [800][128] bf16 hi
                            unsigned short* __restrict__ hl) {// [800][128] bf16 lo
    int m = blockIdx.x;      // 0..799
    int c = threadIdx.x;     // 0..127
    float kv = keys[m * 128 + c];
    float hv = hard[m * 128 + c];
    __shared__ float s1[128];
    __shared__ float s2[128];
    s1[c] = kv * kv;
    s2[c] = hv * hv;
    __syncthreads();
    for (int off = 64; off > 0; off >>= 1) {
        if (c < off) { s1[c] += s1[c + off]; s2[c] += s2[c + off]; }
        __syncthreads();
    }
    float ks = 1.0f / fmaxf(sqrtf(s1[0]), 1e-12f);
    float hs = 1.0f / fmaxf(sqrtf(s2[0]), 1e-12f);
    knR[m * 128 + c] = kv * ks;
    float hnv = hv * hs;
    hn[m * 128 + c] = hnv;
    unsigned short hi = bf16_rne(hnv);
    hh[m * 128 + c] = hi;
    hl[m * 128 + c] = bf16_rne(hnv - bf16_tof(hi));
}

__global__ void prep_c0_k(const float* __restrict__ values, float* __restrict__ c0) {
    int c = threadIdx.x;  // 128 threads
    float s = 0.f;
    for (int m = 0; m < 10; ++m) s += values[m * 128 + c];
    c0[c] = s * 0.1f;
}

// ---------------- center conv1+pool: only pooled rect [45,83)^2 ----------------
__global__ void ce1_k(const float* __restrict__ x,   // (16,1,256,256)
                      const float* __restrict__ w,   // (32,1,3,3)
                      const float* __restrict__ bias,
                      float* __restrict__ out) {     // (16,32,128,128) rect only
    int bx = blockIdx.x;            // 16 b * 2 cog * 6 tiles
    int b = bx / 12, rem = bx % 12;
    int cog = rem / 6, tile = rem % 6;
    int idx = tile * 256 + threadIdx.x;
    if (idx >= 1444) return;
    int ph = 45 + idx / 38, pw = 45 + idx % 38;
    const float* xb = x + (size_t)b * 65536;
    float win[4][4];
#pragma unroll
    for (int r = 0; r < 4; ++r) {
        int ih = 2 * ph - 1 + r;
        bool vr = (ih >= 96 && ih < 160);
#pragma unroll
        for (int c = 0; c < 4; ++c) {
            int iw = 2 * pw - 1 + c;
            win[r][c] = (vr && iw >= 96 && iw < 160) ? xb[ih * 256 + iw] : 0.f;
        }
    }
#pragma unroll
    for (int co8 = 0; co8 < 16; ++co8) {
        int co = cog * 16 + co8;
        const float* w9 = w + co * 9;
        float bv = bias[co];
        float a00 = bv, a01 = bv, a10 = bv, a11 = bv;
#pragma unroll
        for (int kh = 0; kh < 3; ++kh)
#pragma unroll
            for (int kw = 0; kw < 3; ++kw) {
                float wv = w9[kh * 3 + kw];
                a00 += win[kh][kw] * wv;
                a01 += win[kh][kw + 1] * wv;
                a10 += win[kh + 1][kw] * wv;
                a11 += win[kh + 1][kw + 1] * wv;
            }
        float mx = fmaxf(fmaxf(a00, a01), fmaxf(a10, a11));
        out[((size_t)b * 32 + co) * 16384 + ph * 128 + pw] = fmaxf(mx, 0.f);
    }
}

// ---------------- skip conv1+pool: full, 16 co per thread ----------------
__global__ void se1_k(const float* __restrict__ x,   // (16,1,256,256)
                      const float* __restrict__ w,   // (16,1,3,3)
                      const float* __restrict__ bias,
                      float* __restrict__ out) {     // (16,16,128,128)
    int bx = blockIdx.x;            // 16 b * 64 tiles
    int b = bx >> 6, tile = bx & 63;
    int idx = tile * 256 + threadIdx.x;   // 0..16383
    int ph = idx >> 7, pw = idx & 127;
    const float* xb = x + (size_t)b * 65536;
    float win[4][4];
#pragma unroll
    for (int r = 0; r < 4; ++r) {
        int ih = 2 * ph - 1 + r;
        bool vr = (ih >= 0 && ih < 256);
#pragma unroll
        for (int c = 0; c < 4; ++c) {
            int iw = 2 * pw - 1 + c;
            win[r][c] = (vr && iw >= 0 && iw < 256) ? xb[ih * 256 + iw] : 0.f;
        }
    }
#pragma unroll
    for (int co = 0; co < 16; ++co) {
        const float* w9 = w + co * 9;
        float bv = bias[co];
        float a00 = bv, a01 = bv, a10 = bv, a11 = bv;
#pragma unroll
        for (int kh = 0; kh < 3; ++kh)
#pragma unroll
            for (int kw = 0; kw < 3; ++kw) {
                float wv = w9[kh * 3 + kw];
                a00 += win[kh][kw] * wv;
                a01 += win[kh][kw + 1] * wv;
                a10 += win[kh + 1][kw] * wv;
                a11 += win[kh + 1][kw + 1] * wv;
            }
        float mx = fmaxf(fmaxf(a00, a01), fmaxf(a10, a11));
        out[((size_t)b * 16 + co) * 16384 + idx] = fmaxf(mx, 0.f);
    }
}

// ---------------- center conv2 v3 (32->128) + relu + pool -> query-major zcq ----------------
__global__ void __launch_bounds__(256) ce2_v3(
        const float* __restrict__ zc1,  // (16,32,128,128)
        const float* __restrict__ w,    // (128,32,3,3)
        const float* __restrict__ bias,
        float* __restrict__ zcq) {      // (16*324, 128) query-major
    int bx = blockIdx.x;                // 16 b * 16 cog
    int b = bx >> 4, cog = bx & 15;
    const float* ib = zc1 + (size_t)b * 32 * 16384;
    for (int px = threadIdx.x; px < 324; px += 256) {
        int h = 23 + px / 18, ww = 23 + px % 18;
        float acc[8][4];
#pragma unroll
        for (int c8 = 0; c8 < 8; ++c8)
#pragma unroll
            for (int t = 0; t < 4; ++t) acc[c8][t] = 0.f;
        for (int ci = 0; ci < 32; ++ci) {
            const float* p = ib + ci * 16384 + (2 * h - 1) * 128 + (2 * ww - 1);
            float win[4][4];
#pragma unroll
            for (int r = 0; r < 4; ++r)
#pragma unroll
                for (int s = 0; s < 4; ++s) win[r][s] = p[r * 128 + s];
#pragma unroll
            for (int c8 = 0; c8 < 8; ++c8) {
                const float* w9 = w + ((size_t)(cog * 8 + c8) * 32 + ci) * 9;
#pragma unroll
                for (int kh = 0; kh < 3; ++kh)
#pragma unroll
                    for (int kw = 0; kw < 3; ++kw) {
                        float wv = w9[kh * 3 + kw];
                        acc[c8][0] += win[kh][kw] * wv;
                        acc[c8][1] += win[kh][kw + 1] * wv;
                        acc[c8][2] += win[kh + 1][kw] * wv;
                        acc[c8][3] += win[kh + 1][kw + 1] * wv;
                    }
            }
        }
#pragma unroll
        for (int c8 = 0; c8 < 8; ++c8) {
            int co = cog * 8 + c8;
            float mx = fmaxf(fmaxf(acc[c8][0], acc[c8][1]), fmaxf(acc[c8][2], acc[c8][3])) + bias[co];
            zcq[((size_t)(b * 324 + px)) * 128 + co] = fmaxf(mx, 0.f);
        }
    }
}

// ---------------- skip conv2 (16->128) + relu + pool, 8 co per thread ----------------
__global__ void se2_v2(const float* __restrict__ zs1,  // (16,16,128,128)
                       const float* __restrict__ w,    // (128,16,3,3)
                       const float* __restrict__ bias,
                       float* __restrict__ zs) {       // (16,128,64,64)
    int bx = blockIdx.x;            // 16 b * 16 cog * 16 tiles = 4096
    int b = bx >> 8, rem = bx & 255;
    int cog = rem >> 4, tile = rem & 15;
    int px = tile * 256 + threadIdx.x;  // 0..4095
    int ph = px >> 6, pw = px & 63;
    const float* ib = zs1 + (size_t)b * 16 * 16384;
    float acc[8][4];
#pragma unroll
    for (int c8 = 0; c8 < 8; ++c8)
#pragma unroll
        for (int t = 0; t < 4; ++t) acc[c8][t] = 0.f;
    for (int ci = 0; ci < 16; ++ci) {
        const float* p = ib + ci * 16384;
        float win[4][4];
#pragma unroll
        for (int r = 0; r < 4; ++r) {
            int rr = 2 * ph - 1 + r;
            bool vr = (rr >= 0 && rr < 128);
#pragma unroll
            for (int s = 0; s < 4; ++s) {
                int cc = 2 * pw - 1 + s;
                win[r][s] = (vr && cc >= 0 && cc < 128) ? p[rr * 128 + cc] : 0.f;
            }
        }
#pragma unroll
        for (int c8 = 0; c8 < 8; ++c8) {
            const float* w9 = w + ((size_t)(cog * 8 + c8) * 16 + ci) * 9;
#pragma unroll
            for (int kh = 0; kh < 3; ++kh)
#pragma unroll
                for (int kw = 0; kw < 3; ++kw) {
                    float wv = w9[kh * 3 + kw];
                    acc[c8][0] += win[kh][kw] * wv;
                    acc[c8][1] += win[kh][kw + 1] * wv;
                    acc[c8][2] += win[kh + 1][kw] * wv;
                    acc[c8][3] += win[kh + 1][kw + 1] * wv;
                }
        }
    }
#pragma unroll
    for (int c8 = 0; c8 < 8; ++c8) {
        int co = cog * 8 + c8;
        float bv = bias[co];
        float mx = fmaxf(fmaxf(acc[c8][0], acc[c8][1]), fmaxf(acc[c8][2], acc[c8][3])) + bv;
        zs[((size_t)b * 128 + co) * 4096 + px] = fmaxf(mx, 0.f);
    }
}

// ---------------- center matching v2 (unchanged) ----------------
__global__ void __launch_bounds__(256) match_center_v2(
        const float* __restrict__ zcq,    // (16*324, 128) raw queries
        const float* __restrict__ knR,    // (800,128) normalized keys
        const float* __restrict__ values, // (800,128)
        float* __restrict__ dcat) {       // (16,256,64,64), ch 0..127
    __shared__ float shk[128 * 65];
    __shared__ float qint[4 * 256];
    int tid = threadIdx.x;
    int w = tid >> 6, lane = tid & 63;
    int g0 = blockIdx.x * 8 + 2 * w;

#pragma unroll
    for (int i = 0; i < 2; ++i) {
        const float* qp = zcq + (size_t)(g0 + i) * 128;
        float v0 = qp[lane], v1 = qp[lane + 64];
        float ss = v0 * v0 + v1 * v1;
#pragma unroll
        for (int off = 32; off > 0; off >>= 1) ss += __shfl_xor(ss, off);
        float sc = 1.0f / fmaxf(sqrtf(ss), 1e-12f);
        qint[w * 256 + lane * 2 + i] = v0 * sc;
        qint[w * 256 + (lane + 64) * 2 + i] = v1 * sc;
    }

    float sim2[2][13];
#pragma unroll
    for (int k = 0; k < 13; ++k) { sim2[0][k] = 0.f; sim2[1][k] = 0.f; }

    for (int chunk = 0; chunk < 13; ++chunk) {
        int mbase = chunk << 6;
        __syncthreads();
#pragma unroll
        for (int t = 0; t < 8; ++t) {
            int idx = tid + t * 256;
            int kk = idx >> 5, c4 = idx & 31;
            int m = mbase + kk;
            float4 kv = (m < 800) ? *(const float4*)(knR + (size_t)m * 128 + c4 * 4)
                                  : make_float4(0.f, 0.f, 0.f, 0.f);
            shk[(4 * c4 + 0) * 65 + kk] = kv.x;
            shk[(4 * c4 + 1) * 65 + kk] = kv.y;
            shk[(4 * c4 + 2) * 65 + kk] = kv.z;
            shk[(4 * c4 + 3) * 65 + kk] = kv.w;
        }
        __syncthreads();
        float s0 = sim2[0][chunk], s1 = sim2[1][chunk];
        const float* qw = qint + w * 256;
#pragma unroll 4
        for (int c2 = 0; c2 < 64; ++c2) {
            float4 qq = *(const float4*)(qw + c2 * 4);
            float k0 = shk[(2 * c2) * 65 + lane];
            float k1 = shk[(2 * c2 + 1) * 65 + lane];
            s0 += qq.x * k0; s1 += qq.y * k0;
            s0 += qq.z * k1; s1 += qq.w * k1;
        }
        sim2[0][chunk] = s0; sim2[1][chunk] = s1;
    }

#pragma unroll
    for (int i = 0; i < 2; ++i) {
        int g = g0 + i;
        int b = g / 324, q = g - b * 324;
        int h = 23 + q / 18, ww = 23 + q % 18;
        int p = h * 64 + ww;

        float sim[13];
#pragma unroll
        for (int k = 0; k < 13; ++k)
            sim[k] = (lane + (k << 6) < 800) ? sim2[i][k] : NEG_INF;

        float topv[11]; int topm[11];
#pragma unroll
        for (int t = 0; t < 11; ++t) {
            float bvv = NEG_INF; int bm = 0x7fffffff;
#pragma unroll
            for (int k = 0; k < 13; ++k) {
                if (sim[k] > bvv) { bvv = sim[k]; bm = lane + (k << 6); }
            }
#pragma unroll
            for (int off = 32; off > 0; off >>= 1) {
                float ov = __shfl_xor(bvv, off);
                int om = __shfl_xor(bm, off);
                if (ov > bvv || (ov == bvv && om < bm)) { bvv = ov; bm = om; }
            }
            topv[t] = bvv; topm[t] = bm;
            if ((bm & 63) == lane) {
                int kk = bm >> 6;
#pragma unroll
                for (int k = 0; k < 13; ++k)
                    if (k == kk) sim[k] = NEG_INF;
            }
        }
        if (topv[9] - topv[10] < 1e-4f) {
            double s9 = 0.0, s10 = 0.0;
            const float* k9 = knR + (size_t)topm[9] * 128;
            const float* k10 = knR + (size_t)topm[10] * 128;
            for (int c = 0; c < 128; ++c) {
                double qc = (double)qint[w * 256 + c * 2 + i];
                s9 += qc * (double)k9[c];
                s10 += qc * (double)k10[c];
            }
            if ((s10 > s9) || (s10 == s9 && topm[10] < topm[9])) {
                topv[9] = topv[10]; topm[9] = topm[10];
            }
        }
        float mx = topv[0];
        float e[10], ssum = 0.f;
#pragma unroll
        for (int t = 0; t < 10; ++t) { e[t] = expf(topv[t] - mx); ssum += e[t]; }
        float inv = 1.0f / ssum;
        float o0 = 0.f, o1 = 0.f;
#pragma unroll
        for (int t = 0; t < 10; ++t) {
            float wt = e[t] * inv;
            const float* vr = values + (size_t)topm[t] * 128;
            o0 += wt * vr[lane];
            o1 += wt * vr[lane + 64];
        }
        float* ob = dcat + ((size_t)b * 256) * 4096 + p;
        ob[(size_t)lane * 4096] = o0;
        ob[(size_t)(lane + 64) * 4096] = o1;
    }
}

// ---------------- constant fill for out-of-region center matches ----------------
__global__ void fill_c0_k(const float* __restrict__ c0, float* __restrict__ dcat) {
    int idx = blockIdx.x * 256 + threadIdx.x;
    int p = idx & 4095;
    int c = (idx >> 12) & 127;
    int b = idx >> 19;
    int h = p >> 6, ww = p & 63;
    if (h >= 23 && h <= 40 && ww >= 23 && ww <= 40) return;
    dcat[((size_t)b * 256 + c) * 4096 + p] = c0[c];
}

// ---------------- skip matching v5: split-bf16 MFMA, windowed exact rescore ----------------
__global__ void __launch_bounds__(256, 2) match_skip_v5(
        const float* __restrict__ zs,    // (16,128,64,64) raw queries
        const float* __restrict__ hn,    // (800,128) normalized fp32 (rescore)
        const unsigned short* __restrict__ hh,  // (800,128) bf16 hi
        const unsigned short* __restrict__ hl,  // (800,128) bf16 lo
        const float* __restrict__ hard,  // (800,128) raw
        float* __restrict__ dcat) {      // ch 128..255
    __shared__ unsigned short sm[32768]; // 64KB: qhi[0:8192] qlo[8192:16384] khi[16384:24576] klo[24576:32768]
    int b = blockIdx.x >> 6, pt = blockIdx.x & 63;
    int pbase = pt * 64;
    int tid = threadIdx.x;
    int w = tid >> 6, lane = tid & 63;
    int l15 = lane & 15, quad = lane >> 4;

    // ---- stage queries (bf16 hi/lo, XOR-swizzled at 16B) ----
    {
        int p = tid & 63, c0 = tid >> 6;
        for (int k = 0; k < 32; ++k) {
            int c = c0 + k * 4;
            float v = zs[((size_t)b * 128 + c) * 4096 + pbase + p];
            unsigned short hi = bf16_rne(v);
            unsigned short lo = bf16_rne(v - bf16_tof(hi));
            int off = p * 128 + (((c >> 3) ^ (p & 15)) << 3) + (c & 7);
            sm[off] = hi;
            sm[8192 + off] = lo;
        }
    }

    float v1[4], v2[4]; int i1[4], i2[4];
#pragma unroll
    for (int u = 0; u < 4; ++u) { v1[u] = NEG_INF; v2[u] = NEG_INF; i1[u] = 0x7fffffff; i2[u] = 0x7fffffff; }

    for (int chunk = 0; chunk < 13; ++chunk) {
        int mbase = chunk << 6;
        __syncthreads();
#pragma unroll
        for (int t = 0; t < 4; ++t) {
            int idx = tid + t * 256;          // 0..1023
            int row = idx >> 4, cb = idx & 15;
            int gm = mbase + row;
            uint4 dh = make_uint4(0u, 0u, 0u, 0u), dl = make_uint4(0u, 0u, 0u, 0u);
            if (gm < 800) {
                dh = *(const uint4*)(hh + (size_t)gm * 128 + cb * 8);
                dl = *(const uint4*)(hl + (size_t)gm * 128 + cb * 8);
            }
            int off = row * 128 + ((cb ^ (row & 15)) << 3);
            *(uint4*)&sm[16384 + off] = dh;
            *(uint4*)&sm[24576 + off] = dl;
        }
        __syncthreads();

        f32x4 acc[4];
#pragma unroll
        for (int kt = 0; kt < 4; ++kt) acc[kt] = (f32x4){0.f, 0.f, 0.f, 0.f};

#pragma unroll
        for (int ks = 0; ks < 4; ++ks) {
            int qrow = 16 * w + l15;
            int cb = ks * 4 + quad;
            int qoff = qrow * 128 + ((cb ^ (qrow & 15)) << 3);
            short8 ahi = *(const short8*)&sm[qoff];
            short8 alo = *(const short8*)&sm[8192 + qoff];
#pragma unroll
            for (int kt = 0; kt < 4; ++kt) {
                int krow = l15 + 16 * kt;
                int koff = krow * 128 + ((cb ^ (krow & 15)) << 3);
                short8 bhi = *(const short8*)&sm[16384 + koff];
                short8 blo = *(const short8*)&sm[24576 + koff];
                acc[kt] = __builtin_amdgcn_mfma_f32_16x16x32_bf16(alo, bhi, acc[kt], 0, 0, 0);
                acc[kt] = __builtin_amdgcn_mfma_f32_16x16x32_bf16(ahi, blo, acc[kt], 0, 0, 0);
                acc[kt] = __builtin_amdgcn_mfma_f32_16x16x32_bf16(ahi, bhi, acc[kt], 0, 0, 0);
            }
        }
#pragma unroll
        for (int kt = 0; kt < 4; ++kt) {
            int m = mbase + 16 * kt + l15;
            if (m < 800) {
#pragma unroll
                for (int u = 0; u < 4; ++u) {
                    float sv = acc[kt][u];
                    if (sv > v1[u] || (sv == v1[u] && m < i1[u])) {
                        v2[u] = v1[u]; i2[u] = i1[u]; v1[u] = sv; i1[u] = m;
                    } else if (sv > v2[u] || (sv == v2[u] && m < i2[u])) {
                        v2[u] = sv; i2[u] = m;
                    }
                }
            }
        }
    }
    __syncthreads();
    float4* red = (float4*)&sm[16384];   // [64 q][17 slots] float4 = 17408 B = 8704 shorts
#pragma unroll
    for (int u = 0; u < 4; ++u) {
        int q = 16 * w + quad * 4 + u;
        red[q * 17 + l15] = make_float4(v1[u], v2[u], __int_as_float(i1[u]), __int_as_float(i2[u]));
    }
    __syncthreads();
    int* bi_sh = (int*)&sm[16384 + 8704];  // [64] ints, in-bounds (ends at byte 50432)
    if (tid < 64) {
        int q = tid;
        float V1 = NEG_INF; int I1 = 0x7fffffff;
        for (int k = 0; k < 16; ++k) {
            float4 e = red[q * 17 + k];
            float cv[2] = { e.x, e.y };
            int ci_[2] = { __float_as_int(e.z), __float_as_int(e.w) };
#pragma unroll
            for (int t = 0; t < 2; ++t) {
                if (cv[t] > V1 || (cv[t] == V1 && ci_[t] < I1)) { V1 = cv[t]; I1 = ci_[t]; }
            }
        }
        float qn2 = 0.f;
        for (int c = 0; c < 128; ++c) {
            int off = q * 128 + (((c >> 3) ^ (q & 15)) << 3) + (c & 7);
            float qc = bf16_tof(sm[off]) + bf16_tof(sm[8192 + off]);
            qn2 += qc * qc;
        }
        float tau = 1.5e-4f * sqrtf(qn2) + 1e-12f;
        float thr = V1 - tau;
        int ncand = 0;
        for (int k = 0; k < 16; ++k) {
            float4 e = red[q * 17 + k];
            if (e.x >= thr && __float_as_int(e.z) != 0x7fffffff) ++ncand;
            if (e.y >= thr && __float_as_int(e.w) != 0x7fffffff) ++ncand;
        }
        int bi = I1;
        if (ncand > 1) {
            double bestd = -1.0e300; int besti = 0x7fffffff;
            for (int k = 0; k < 16; ++k) {
                float4 e = red[q * 17 + k];
                float cv[2] = { e.x, e.y };
                int ci_[2] = { __float_as_int(e.z), __float_as_int(e.w) };
                for (int t = 0; t < 2; ++t) {
                    if (cv[t] >= thr && ci_[t] != 0x7fffffff) {
                        const float* hr = hn + (size_t)ci_[t] * 128;
                        double d = 0.0;
                        for (int c = 0; c < 128; ++c) {
                            double qc = (double)zs[((size_t)b * 128 + c) * 4096 + pbase + q];
                            d += qc * (double)hr[c];
                        }
                        if (d > bestd || (d == bestd && ci_[t] < besti)) { bestd = d; besti = ci_[t]; }
                    }
                }
            }
            bi = besti;
        }
        bi_sh[q] = bi;
    }
    __syncthreads();
    {
        int q = tid & 63, seg = tid >> 6;
        int bi = bi_sh[q];
        const float* hr = hard + (size_t)bi * 128;
        float* ob = dcat + ((size_t)b * 256 + 128) * 4096 + pbase + q;
#pragma unroll
        for (int i = 0; i < 32; ++i) {
            int c = seg * 32 + i;
            ob[(size_t)c * 4096] = hr[c];
        }
    }
}

// ---------------- decoder conv1 v4 (R7 revert): weight-staged LDS, 4 px/thread, K-split 2 ----------------
// NOTE: launch_bounds(256,3)+K-split-4 (R9) forced VGPR spills (WRITE_SIZE 1.14GB scratch). Keep (256,2).
__global__ void __launch_bounds__(256, 2) dec1_v4(
        const float* __restrict__ dcat, // (16,256,64,64)
        const float* __restrict__ w,    // (64,256,3,3)
        float* __restrict__ pA,         // partial ksplit 0
        float* __restrict__ pB) {       // partial ksplit 1
    __shared__ float xs[2][4760];       // 4 ci x 34x35 halo tile
    __shared__ float wsh[2][768];       // 4 ci x 16 co x 12
    int bx = blockIdx.x;
    int b = bx >> 5, rem = bx & 31;
    int cog = rem >> 3, tile = (rem >> 1) & 3, ks = rem & 1;
    int ph0 = (tile >> 1) * 32, pw0 = (tile & 1) * 32;
    int tid = threadIdx.x;
    int pr = tid >> 4, pc = tid & 15;

    const float* ib = dcat + ((size_t)b * 256 + (size_t)ks * 128) * 4096;
    const float* wb = w + (size_t)(cog * 16) * 2304 + (size_t)ks * 128 * 9;

    int xg[19];
#pragma unroll
    for (int k = 0; k < 19; ++k) {
        int f = tid + k * 256;
        xg[k] = -1;
        if (f < 4760) {
            int ci_l = f / 1190, pos = f % 1190;
            int r = pos / 35, c = pos % 35;
            int row = ph0 - 1 + r, col = pw0 - 1 + c;
            if (c < 34 && row >= 0 && row < 64 && col >= 0 && col < 64)
                xg[k] = ci_l * 4096 + row * 64 + col;
        }
    }
    int wg[3], wl[3];
#pragma unroll
    for (int k = 0; k < 3; ++k) {
        int t = tid + k * 256;
        wg[k] = -1; wl[k] = 0;
        if (t < 576) {
            int ci_l = t / 144, r2 = t % 144;
            int co = r2 / 9, j = r2 % 9;
            wg[k] = co * 2304 + ci_l * 9 + j;
            wl[k] = ci_l * 192 + co * 12 + j;
        }
    }

#pragma unroll
    for (int k = 0; k < 19; ++k) {
        int f = tid + k * 256;
        if (f < 4760) xs[0][f] = (xg[k] >= 0) ? ib[xg[k]] : 0.f;
    }
#pragma unroll
    for (int k = 0; k < 3; ++k)
        if (wg[k] >= 0) wsh[0][wl[k]] = wb[wg[k]];
    __syncthreads();

    float acc[16][4];
#pragma unroll
    for (int co = 0; co < 16; ++co)
#pragma unroll
        for (int q = 0; q < 4; ++q) acc[co][q] = 0.f;

    for (int chunk = 0; chunk < 32; ++chunk) {
        int cur = chunk & 1;
        float pfx[19], pfw[3];
        if (chunk < 31) {
            const float* ibn = ib + (size_t)(chunk + 1) * 4 * 4096;
            const float* wbn = wb + (chunk + 1) * 36;
#pragma unroll
            for (int k = 0; k < 19; ++k) {
                int f = tid + k * 256;
                if (f < 4760) pfx[k] = (xg[k] >= 0) ? ibn[xg[k]] : 0.f;
            }
#pragma unroll
            for (int k = 0; k < 3; ++k)
                if (wg[k] >= 0) pfw[k] = wbn[wg[k]];
        }
#pragma unroll 2
        for (int ci_l = 0; ci_l < 4; ++ci_l) {
            const float* xp = &xs[cur][ci_l * 1190 + (2 * pr) * 35 + 2 * pc];
            float xw[4][4];
#pragma unroll
            for (int r = 0; r < 4; ++r)
#pragma unroll
                for (int c = 0; c < 4; ++c) xw[r][c] = xp[r * 35 + c];
            const float* wp = &wsh[cur][ci_l * 192];
#pragma unroll
            for (int co = 0; co < 16; ++co) {
                float4 w0 = *(const float4*)(wp + co * 12);
                float4 w1 = *(const float4*)(wp + co * 12 + 4);
                float4 w2 = *(const float4*)(wp + co * 12 + 8);
                float wv[9] = { w0.x, w0.y, w0.z, w0.w, w1.x, w1.y, w1.z, w1.w, w2.x };
#pragma unroll
                for (int q = 0; q < 4; ++q) {
                    int qr = q >> 1, qc = q & 1;
                    float s = acc[co][q];
#pragma unroll
                    for (int kh = 0; kh < 3; ++kh)
#pragma unroll
                        for (int kw = 0; kw < 3; ++kw)
                            s += xw[qr + kh][qc + kw] * wv[kh * 3 + kw];
                    acc[co][q] = s;
                }
            }
        }
        if (chunk < 31) {
#pragma unroll
            for (int k = 0; k < 19; ++k) {
                int f = tid + k * 256;
                if (f < 4760) xs[1 - cur][f] = pfx[k];
            }
#pragma unroll
            for (int k = 0; k < 3; ++k)
                if (wg[k] >= 0) wsh[1 - cur][wl[k]] = pfw[k];
            __syncthreads();
        }
    }
    float* ob = ((ks == 0) ? pA : pB) + ((size_t)b * 64 + cog * 16) * 4096;
#pragma unroll
    for (int co = 0; co < 16; ++co)
#pragma unroll
        for (int q = 0; q < 4; ++q) {
            int row = ph0 + 2 * pr + (q >> 1), col = pw0 + 2 * pc + (q & 1);
            ob[(size_t)co * 4096 + row * 64 + col] = acc[co][q];
        }
}

// ---------------- dec1 partial reduce: d1 = relu(pA + pB + bias), in-place over pA ----------------
__global__ void dec1_add_k(float* __restrict__ pA, const float* __restrict__ pB,
                           const float* __restrict__ bias) {
    int idx = blockIdx.x * 256 + threadIdx.x;  // 4194304
    int c = (idx >> 12) & 63;
    float v = pA[idx] + pB[idx] + bias[c];
    pA[idx] = fmaxf(v, 0.f);
}

// ---------------- transposed conv v2: quad-parity, 16 co per thread ----------------
template <int CIN, int COUT, int COG, int H>
__global__ void __launch_bounds__(256) tconv_v2(
        const float* __restrict__ x,   // (16,CIN,H,H)
        const float* __restrict__ w,   // (CIN,COUT,4,4)
        const float* __restrict__ bias,
        float* __restrict__ out) {     // (16,COUT,2H,2H)
    constexpr int NCOG = COUT / COG;
    constexpr int TPS = H / 16;
    constexpr int TILES = TPS * TPS;
    constexpr int HO = 2 * H;
    int bx = blockIdx.x;
    int b = bx / (NCOG * TILES), rem = bx % (NCOG * TILES);
    int cog = rem / TILES, tile = rem % TILES;
    int ti = tile / TPS, tj = tile % TPS;
    int tid = threadIdx.x;
    int i = ti * 16 + (tid >> 4);
    int j = tj * 16 + (tid & 15);

    float acc[2][2][COG];
#pragma unroll
    for (int pr = 0; pr < 2; ++pr)
#pragma unroll
        for (int pc = 0; pc < 2; ++pc)
#pragma unroll
            for (int co = 0; co < COG; ++co) acc[pr][pc][co] = 0.f;

    const float* xb = x + (size_t)b * CIN * H * H;
    for (int ci = 0; ci < CIN; ++ci) {
        const float* xp = xb + (size_t)ci * H * H;
        float xr[3][3];
#pragma unroll
        for (int dr = 0; dr < 3; ++dr) {
            int gr = i - 1 + dr;
            bool vr = (gr >= 0 && gr < H);
#pragma unroll
            for (int dc = 0; dc < 3; ++dc) {
                int gc = j - 1 + dc;
                xr[dr][dc] = (vr && gc >= 0 && gc < H) ? xp[gr * H + gc] : 0.f;
            }
        }
#pragma unroll
        for (int co = 0; co < COG; ++co) {
            const float* wp = w + (((size_t)ci * COUT + cog * COG + co) << 4);
            float wr[16];
#pragma unroll
            for (int k = 0; k < 16; ++k) wr[k] = wp[k];
#pragma unroll
            for (int pr = 0; pr < 2; ++pr)
#pragma unroll
                for (int a = 0; a < 2; ++a)
#pragma unroll
                    for (int pc = 0; pc < 2; ++pc)
#pragma unroll
                        for (int bb = 0; bb < 2; ++bb)
                            acc[pr][pc][co] += xr[pr + a][pc + bb] *
                                               wr[(3 - pr - 2 * a) * 4 + (3 - pc - 2 * bb)];
        }
    }
#pragma unroll
    for (int co = 0; co < COG; ++co) {
        float bv = bias[cog * COG + co];
        float* ob = out + ((size_t)b * COUT + cog * COG + co) * HO * HO;
#pragma unroll
        for (int pr = 0; pr < 2; ++pr)
#pragma unroll
            for (int pc = 0; pc < 2; ++pc)
                ob[(2 * i + pr) * HO + 2 * j + pc] = fmaxf(acc[pr][pc][co] + bv, 0.f);
    }
}

// ---------------- final conv (16->1) 3x3, 4 px per thread ----------------
__global__ void final_v2(const float* __restrict__ t2,  // (16,16,256,256)
                         const float* __restrict__ w,   // (1,16,3,3)
                         const float* __restrict__ bias,
                         float* __restrict__ out) {     // (16,1,256,256)
    int g = blockIdx.x * 256 + threadIdx.x;
    int pxb = g * 4;
    int b = pxb >> 16, p = pxb & 65535;
    int h = p >> 8, c0 = p & 255;
    const float* tb = t2 + (size_t)b * 16 * 65536;
    float acc[4];
    float bv = bias[0];
#pragma unroll
    for (int t = 0; t < 4; ++t) acc[t] = bv;
    for (int ci = 0; ci < 16; ++ci) {
        const float* pp = tb + (size_t)ci * 65536;
        const float* w9 = w + ci * 9;
        float win[3][6];
#pragma unroll
        for (int dr = 0; dr < 3; ++dr) {
            int rr = h - 1 + dr;
            bool vr = (rr >= 0 && rr < 256);
#pragma unroll
            for (int dc = 0; dc < 6; ++dc) {
                int cc = c0 - 1 + dc;
                win[dr][dc] = (vr && cc >= 0 && cc < 256) ? pp[rr * 256 + cc] : 0.f;
            }
        }
#pragma unroll
        for (int t = 0; t < 4; ++t)
#pragma unroll
            for (int dr = 0; dr < 3; ++dr)
#pragma unroll
                for (int dc = 0; dc < 3; ++dc)
                    acc[t] += win[dr][t + dc] * w9[dr * 3 + dc];
    }
    *(float4*)(out + pxb) = make_float4(acc[0], acc[1], acc[2], acc[3]);
}

// ---------------- launch ----------------
extern "C" void kernel_launch(void* const* d_in, const int* in_sizes, int n_in,
                              void* d_out, int out_size, void* d_ws, size_t ws_size,
                              hipStream_t stream) {
    (void)in_sizes; (void)n_in; (void)out_size; (void)ws_size;
    const float* x     = (const float*)d_in[0];
    const float* cw1   = (const float*)d_in[1];
    const float* cb1   = (const float*)d_in[2];
    const float* cw2   = (const float*)d_in[3];
    const float* cb2   = (const float*)d_in[4];
    const float* sw1   = (const float*)d_in[5];
    const float* sb1   = (const float*)d_in[6];
    const float* sw2   = (const float*)d_in[7];
    const float* sb2   = (const float*)d_in[8];
    const float* mkeys = (const float*)d_in[9];
    const float* mvals = (const float*)d_in[10];
    const float* mhard = (const float*)d_in[11];
    const float* dw1   = (const float*)d_in[12];
    const float* db1   = (const float*)d_in[13];
    const float* tw1   = (const float*)d_in[14];
    const float* tb1   = (const float*)d_in[15];
    const float* tw2   = (const float*)d_in[16];
    const float* tb2   = (const float*)d_in[17];
    const float* dw2   = (const float*)d_in[18];
    const float* db2   = (const float*)d_in[19];
    float* out = (float*)d_out;
    float* ws  = (float*)d_ws;

    const size_t OFF_KN  = 0;                   // knR: 800*128
    const size_t OFF_HN  = 102400;              // hn:  800*128
    const size_t OFF_C0  = 204800;              // c0:  128
    const size_t OFF_R14 = 204928;              // zc1 -> zs -> t1
    const size_t OFF_R2  = OFF_R14 + 8388608;   // dec1 partial B
    const size_t OFF_R3  = OFF_R2 + 8388608;    // zs1 -> dec1 partial A / d1
    const size_t OFF_R5  = OFF_R3 + 4194304;    // dcat -> t2
    const size_t OFF_ZCQ = OFF_R5 + 16777216;   // zcq: 16*324*128
    const size_t OFF_HH  = OFF_ZCQ + 663552;    // hh: 800*128 u16 = 51200 floats
    const size_t OFF_HL  = OFF_HH + 51200;      // hl: 51200 floats

    float* knR  = ws + OFF_KN;
    float* hn   = ws + OFF_HN;
    float* c0   = ws + OFF_C0;
    float* zc1  = ws + OFF_R14;
    float* zs   = ws + OFF_R14;
    float* t1   = ws + OFF_R14;
    float* pB   = ws + OFF_R2;
    float* zs1  = ws + OFF_R3;
    float* d1b  = ws + OFF_R3;
    float* dcat = ws + OFF_R5;
    float* t2   = ws + OFF_R5;
    float* zcq  = ws + OFF_ZCQ;
    unsigned short* hhp = (unsigned short*)(ws + OFF_HH);
    unsigned short* hlp = (unsigned short*)(ws + OFF_HL);

    prep_norm_k<<<800, 128, 0, stream>>>(mkeys, mhard, knR, hn, hhp, hlp);
    prep_c0_k<<<1, 128, 0, stream>>>(mvals, c0);

    ce1_k<<<16 * 2 * 6, 256, 0, stream>>>(x, cw1, cb1, zc1);
    se1_k<<<16 * 64, 256, 0, stream>>>(x, sw1, sb1, zs1);
    ce2_v3<<<16 * 16, 256, 0, stream>>>(zc1, cw2, cb2, zcq);
    se2_v2<<<16 * 16 * 16, 256, 0, stream>>>(zs1, sw2, sb2, zs);  // overwrites zc1 (dead)

    match_center_v2<<<648, 256, 0, stream>>>(zcq, knR, mvals, dcat);
    fill_c0_k<<<32768, 256, 0, stream>>>(c0, dcat);
    match_skip_v5<<<16 * 64, 256, 0, stream>>>(zs, hn, hhp, hlp, mhard, dcat);

    dec1_v4<<<512, 256, 0, stream>>>(dcat, dw1, d1b, pB);
    dec1_add_k<<<16384, 256, 0, stream>>>(d1b, pB, db1);

    tconv_v2<64, 32, 16, 64><<<16 * 2 * 16, 256, 0, stream>>>(d1b, tw1, tb1, t1);   // overwrites zs (dead)
    tconv_v2<32, 16, 16, 128><<<16 * 1 * 64, 256, 0, stream>>>(t1, tw2, tb2, t2);   // overwrites dcat (dead)
    final_v2<<<1024, 256, 0, stream>>>(t2, dw2, db2, out);
}

// Round 11
// 1088.787 us; speedup vs baseline: 1.6553x; 1.0931x over previous
//
#include <hip/hip_runtime.h>
#include <cstdint>
#include <cstddef>

#define NEG_INF (-3.0e38f)

typedef __attribute__((ext_vector_type(8))) short short8;
typedef __attribute__((ext_vector_type(4))) float f32x4;

__device__ inline unsigned short bf16_rne(float x) {
    unsigned u = __float_as_uint(x);
    unsigned r = u + 0x7fffu + ((u >> 16) & 1u);
    return (unsigned short)(r >> 16);
}
__device__ inline float bf16_tof(unsigned short h) {
    return __uint_as_float(((unsigned)h) << 16);
}

// ---------------- prep: normalize keys/hard + bf16 hi/lo split of hn ----------------
__global__ void prep_norm_k(const float* __restrict__ keys,
                            const float* __restrict__ hard,
                            float* __restrict__ knR,   // [800][128] normalized keys
                            float* __restrict__ hn,    // [800][128] normalized hard
                            unsigned short* __restrict__ hh,  // [800][128] bf16 hi
                            unsigned short* __restrict__ hl) {// [800][128] bf16 lo
    int m = blockIdx.x;      // 0..799
    int c = threadIdx.x;     // 0..127
    float kv = keys[m * 128 + c];
    float hv = hard[m * 128 + c];
    __shared__ float s1[128];
    __shared__ float s2[128];
    s1[c] = kv * kv;
    s2[c] = hv * hv;
    __syncthreads();
    for (int off = 64; off > 0; off >>= 1) {
        if (c < off) { s1[c] += s1[c + off]; s2[c] += s2[c + off]; }
        __syncthreads();
    }
    float ks = 1.0f / fmaxf(sqrtf(s1[0]), 1e-12f);
    float hs = 1.0f / fmaxf(sqrtf(s2[0]), 1e-12f);
    knR[m * 128 + c] = kv * ks;
    float hnv = hv * hs;
    hn[m * 128 + c] = hnv;
    unsigned short hi = bf16_rne(hnv);
    hh[m * 128 + c] = hi;
    hl[m * 128 + c] = bf16_rne(hnv - bf16_tof(hi));
}

__global__ void prep_c0_k(const float* __restrict__ values, float* __restrict__ c0) {
    int c = threadIdx.x;  // 128 threads
    float s = 0.f;
    for (int m = 0; m < 10; ++m) s += values[m * 128 + c];
    c0[c] = s * 0.1f;
}

// ---------------- prep: dec1 weights -> chunked bf16 hi/lo, MFMA A-layout w/ bank swizzle ----------------
// dst[chunk][tap][cog][co32][g_store][j], g_store = g ^ ((co32>>2)&3)
__global__ void prep_w1_k(const float* __restrict__ dw1,   // (64,256,3,3)
                          unsigned short* __restrict__ wph,
                          unsigned short* __restrict__ wpl) {
    int idx = blockIdx.x * 256 + threadIdx.x;   // 147456 total
    int co = idx / 2304, r2 = idx % 2304;
    int ci = r2 / 9, tap = r2 % 9;
    float v = dw1[idx];
    int chunk = ci >> 5, cog = co >> 5, co32 = co & 31;
    int cil = ci & 31, g = cil >> 3, j = cil & 7;
    int gs = g ^ ((co32 >> 2) & 3);
    int off = ((((chunk * 9 + tap) * 2 + cog) * 32 + co32) * 4 + gs) * 8 + j;
    unsigned short hi = bf16_rne(v);
    wph[off] = hi;
    wpl[off] = bf16_rne(v - bf16_tof(hi));
}

// ---------------- center conv1+pool: only pooled rect [45,83)^2 ----------------
__global__ void ce1_k(const float* __restrict__ x,   // (16,1,256,256)
                      const float* __restrict__ w,   // (32,1,3,3)
                      const float* __restrict__ bias,
                      float* __restrict__ out) {     // (16,32,128,128) rect only
    int bx = blockIdx.x;            // 16 b * 2 cog * 6 tiles
    int b = bx / 12, rem = bx % 12;
    int cog = rem / 6, tile = rem % 6;
    int idx = tile * 256 + threadIdx.x;
    if (idx >= 1444) return;
    int ph = 45 + idx / 38, pw = 45 + idx % 38;
    const float* xb = x + (size_t)b * 65536;
    float win[4][4];
#pragma unroll
    for (int r = 0; r < 4; ++r) {
        int ih = 2 * ph - 1 + r;
        bool vr = (ih >= 96 && ih < 160);
#pragma unroll
        for (int c = 0; c < 4; ++c) {
            int iw = 2 * pw - 1 + c;
            win[r][c] = (vr && iw >= 96 && iw < 160) ? xb[ih * 256 + iw] : 0.f;
        }
    }
#pragma unroll
    for (int co8 = 0; co8 < 16; ++co8) {
        int co = cog * 16 + co8;
        const float* w9 = w + co * 9;
        float bv = bias[co];
        float a00 = bv, a01 = bv, a10 = bv, a11 = bv;
#pragma unroll
        for (int kh = 0; kh < 3; ++kh)
#pragma unroll
            for (int kw = 0; kw < 3; ++kw) {
                float wv = w9[kh * 3 + kw];
                a00 += win[kh][kw] * wv;
                a01 += win[kh][kw + 1] * wv;
                a10 += win[kh + 1][kw] * wv;
                a11 += win[kh + 1][kw + 1] * wv;
            }
        float mx = fmaxf(fmaxf(a00, a01), fmaxf(a10, a11));
        out[((size_t)b * 32 + co) * 16384 + ph * 128 + pw] = fmaxf(mx, 0.f);
    }
}

// ---------------- skip conv1+pool: full, 16 co per thread ----------------
__global__ void se1_k(const float* __restrict__ x,   // (16,1,256,256)
                      const float* __restrict__ w,   // (16,1,3,3)
                      const float* __restrict__ bias,
                      float* __restrict__ out) {     // (16,16,128,128)
    int bx = blockIdx.x;            // 16 b * 64 tiles
    int b = bx >> 6, tile = bx & 63;
    int idx = tile * 256 + threadIdx.x;   // 0..16383
    int ph = idx >> 7, pw = idx & 127;
    const float* xb = x + (size_t)b * 65536;
    float win[4][4];
#pragma unroll
    for (int r = 0; r < 4; ++r) {
        int ih = 2 * ph - 1 + r;
        bool vr = (ih >= 0 && ih < 256);
#pragma unroll
        for (int c = 0; c < 4; ++c) {
            int iw = 2 * pw - 1 + c;
            win[r][c] = (vr && iw >= 0 && iw < 256) ? xb[ih * 256 + iw] : 0.f;
        }
    }
#pragma unroll
    for (int co = 0; co < 16; ++co) {
        const float* w9 = w + co * 9;
        float bv = bias[co];
        float a00 = bv, a01 = bv, a10 = bv, a11 = bv;
#pragma unroll
        for (int kh = 0; kh < 3; ++kh)
#pragma unroll
            for (int kw = 0; kw < 3; ++kw) {
                float wv = w9[kh * 3 + kw];
                a00 += win[kh][kw] * wv;
                a01 += win[kh][kw + 1] * wv;
                a10 += win[kh + 1][kw] * wv;
                a11 += win[kh + 1][kw + 1] * wv;
            }
        float mx = fmaxf(fmaxf(a00, a01), fmaxf(a10, a11));
        out[((size_t)b * 16 + co) * 16384 + idx] = fmaxf(mx, 0.f);
    }
}

// ---------------- center conv2 v3 (32->128) + relu + pool -> query-major zcq ----------------
__global__ void __launch_bounds__(256) ce2_v3(
        const float* __restrict__ zc1,  // (16,32,128,128)
        const float* __restrict__ w,    // (128,32,3,3)
        const float* __restrict__ bias,
        float* __restrict__ zcq) {      // (16*324, 128) query-major
    int bx = blockIdx.x;                // 16 b * 16 cog
    int b = bx >> 4, cog = bx & 15;
    const float* ib = zc1 + (size_t)b * 32 * 16384;
    for (int px = threadIdx.x; px < 324; px += 256) {
        int h = 23 + px / 18, ww = 23 + px % 18;
        float acc[8][4];
#pragma unroll
        for (int c8 = 0; c8 < 8; ++c8)
#pragma unroll
            for (int t = 0; t < 4; ++t) acc[c8][t] = 0.f;
        for (int ci = 0; ci < 32; ++ci) {
            const float* p = ib + ci * 16384 + (2 * h - 1) * 128 + (2 * ww - 1);
            float win[4][4];
#pragma unroll
            for (int r = 0; r < 4; ++r)
#pragma unroll
                for (int s = 0; s < 4; ++s) win[r][s] = p[r * 128 + s];
#pragma unroll
            for (int c8 = 0; c8 < 8; ++c8) {
                const float* w9 = w + ((size_t)(cog * 8 + c8) * 32 + ci) * 9;
#pragma unroll
                for (int kh = 0; kh < 3; ++kh)
#pragma unroll
                    for (int kw = 0; kw < 3; ++kw) {
                        float wv = w9[kh * 3 + kw];
                        acc[c8][0] += win[kh][kw] * wv;
                        acc[c8][1] += win[kh][kw + 1] * wv;
                        acc[c8][2] += win[kh + 1][kw] * wv;
                        acc[c8][3] += win[kh + 1][kw + 1] * wv;
                    }
            }
        }
#pragma unroll
        for (int c8 = 0; c8 < 8; ++c8) {
            int co = cog * 8 + c8;
            float mx = fmaxf(fmaxf(acc[c8][0], acc[c8][1]), fmaxf(acc[c8][2], acc[c8][3])) + bias[co];
            zcq[((size_t)(b * 324 + px)) * 128 + co] = fmaxf(mx, 0.f);
        }
    }
}

// ---------------- skip conv2 (16->128) + relu + pool, 8 co per thread ----------------
__global__ void se2_v2(const float* __restrict__ zs1,  // (16,16,128,128)
                       const float* __restrict__ w,    // (128,16,3,3)
                       const float* __restrict__ bias,
                       float* __restrict__ zs) {       // (16,128,64,64)
    int bx = blockIdx.x;            // 16 b * 16 cog * 16 tiles = 4096
    int b = bx >> 8, rem = bx & 255;
    int cog = rem >> 4, tile = rem & 15;
    int px = tile * 256 + threadIdx.x;  // 0..4095
    int ph = px >> 6, pw = px & 63;
    const float* ib = zs1 + (size_t)b * 16 * 16384;
    float acc[8][4];
#pragma unroll
    for (int c8 = 0; c8 < 8; ++c8)
#pragma unroll
        for (int t = 0; t < 4; ++t) acc[c8][t] = 0.f;
    for (int ci = 0; ci < 16; ++ci) {
        const float* p = ib + ci * 16384;
        float win[4][4];
#pragma unroll
        for (int r = 0; r < 4; ++r) {
            int rr = 2 * ph - 1 + r;
            bool vr = (rr >= 0 && rr < 128);
#pragma unroll
            for (int s = 0; s < 4; ++s) {
                int cc = 2 * pw - 1 + s;
                win[r][s] = (vr && cc >= 0 && cc < 128) ? p[rr * 128 + cc] : 0.f;
            }
        }
#pragma unroll
        for (int c8 = 0; c8 < 8; ++c8) {
            const float* w9 = w + ((size_t)(cog * 8 + c8) * 16 + ci) * 9;
#pragma unroll
            for (int kh = 0; kh < 3; ++kh)
#pragma unroll
                for (int kw = 0; kw < 3; ++kw) {
                    float wv = w9[kh * 3 + kw];
                    acc[c8][0] += win[kh][kw] * wv;
                    acc[c8][1] += win[kh][kw + 1] * wv;
                    acc[c8][2] += win[kh + 1][kw] * wv;
                    acc[c8][3] += win[kh + 1][kw + 1] * wv;
                }
        }
    }
#pragma unroll
    for (int c8 = 0; c8 < 8; ++c8) {
        int co = cog * 8 + c8;
        float bv = bias[co];
        float mx = fmaxf(fmaxf(acc[c8][0], acc[c8][1]), fmaxf(acc[c8][2], acc[c8][3])) + bv;
        zs[((size_t)b * 128 + co) * 4096 + px] = fmaxf(mx, 0.f);
    }
}

// ---------------- center matching v2 (unchanged) ----------------
__global__ void __launch_bounds__(256) match_center_v2(
        const float* __restrict__ zcq,    // (16*324, 128) raw queries
        const float* __restrict__ knR,    // (800,128) normalized keys
        const float* __restrict__ values, // (800,128)
        float* __restrict__ dcat) {       // (16,256,64,64), ch 0..127
    __shared__ float shk[128 * 65];
    __shared__ float qint[4 * 256];
    int tid = threadIdx.x;
    int w = tid >> 6, lane = tid & 63;
    int g0 = blockIdx.x * 8 + 2 * w;

#pragma unroll
    for (int i = 0; i < 2; ++i) {
        const float* qp = zcq + (size_t)(g0 + i) * 128;
        float v0 = qp[lane], v1 = qp[lane + 64];
        float ss = v0 * v0 + v1 * v1;
#pragma unroll
        for (int off = 32; off > 0; off >>= 1) ss += __shfl_xor(ss, off);
        float sc = 1.0f / fmaxf(sqrtf(ss), 1e-12f);
        qint[w * 256 + lane * 2 + i] = v0 * sc;
        qint[w * 256 + (lane + 64) * 2 + i] = v1 * sc;
    }

    float sim2[2][13];
#pragma unroll
    for (int k = 0; k < 13; ++k) { sim2[0][k] = 0.f; sim2[1][k] = 0.f; }

    for (int chunk = 0; chunk < 13; ++chunk) {
        int mbase = chunk << 6;
        __syncthreads();
#pragma unroll
        for (int t = 0; t < 8; ++t) {
            int idx = tid + t * 256;
            int kk = idx >> 5, c4 = idx & 31;
            int m = mbase + kk;
            float4 kv = (m < 800) ? *(const float4*)(knR + (size_t)m * 128 + c4 * 4)
                                  : make_float4(0.f, 0.f, 0.f, 0.f);
            shk[(4 * c4 + 0) * 65 + kk] = kv.x;
            shk[(4 * c4 + 1) * 65 + kk] = kv.y;
            shk[(4 * c4 + 2) * 65 + kk] = kv.z;
            shk[(4 * c4 + 3) * 65 + kk] = kv.w;
        }
        __syncthreads();
        float s0 = sim2[0][chunk], s1 = sim2[1][chunk];
        const float* qw = qint + w * 256;
#pragma unroll 4
        for (int c2 = 0; c2 < 64; ++c2) {
            float4 qq = *(const float4*)(qw + c2 * 4);
            float k0 = shk[(2 * c2) * 65 + lane];
            float k1 = shk[(2 * c2 + 1) * 65 + lane];
            s0 += qq.x * k0; s1 += qq.y * k0;
            s0 += qq.z * k1; s1 += qq.w * k1;
        }
        sim2[0][chunk] = s0; sim2[1][chunk] = s1;
    }

#pragma unroll
    for (int i = 0; i < 2; ++i) {
        int g = g0 + i;
        int b = g / 324, q = g - b * 324;
        int h = 23 + q / 18, ww = 23 + q % 18;
        int p = h * 64 + ww;

        float sim[13];
#pragma unroll
        for (int k = 0; k < 13; ++k)
            sim[k] = (lane + (k << 6) < 800) ? sim2[i][k] : NEG_INF;

        float topv[11]; int topm[11];
#pragma unroll
        for (int t = 0; t < 11; ++t) {
            float bvv = NEG_INF; int bm = 0x7fffffff;
#pragma unroll
            for (int k = 0; k < 13; ++k) {
                if (sim[k] > bvv) { bvv = sim[k]; bm = lane + (k << 6); }
            }
#pragma unroll
            for (int off = 32; off > 0; off >>= 1) {
                float ov = __shfl_xor(bvv, off);
                int om = __shfl_xor(bm, off);
                if (ov > bvv || (ov == bvv && om < bm)) { bvv = ov; bm = om; }
            }
            topv[t] = bvv; topm[t] = bm;
            if ((bm & 63) == lane) {
                int kk = bm >> 6;
#pragma unroll
                for (int k = 0; k < 13; ++k)
                    if (k == kk) sim[k] = NEG_INF;
            }
        }
        if (topv[9] - topv[10] < 1e-4f) {
            double s9 = 0.0, s10 = 0.0;
            const float* k9 = knR + (size_t)topm[9] * 128;
            const float* k10 = knR + (size_t)topm[10] * 128;
            for (int c = 0; c < 128; ++c) {
                double qc = (double)qint[w * 256 + c * 2 + i];
                s9 += qc * (double)k9[c];
                s10 += qc * (double)k10[c];
            }
            if ((s10 > s9) || (s10 == s9 && topm[10] < topm[9])) {
                topv[9] = topv[10]; topm[9] = topm[10];
            }
        }
        float mx = topv[0];
        float e[10], ssum = 0.f;
#pragma unroll
        for (int t = 0; t < 10; ++t) { e[t] = expf(topv[t] - mx); ssum += e[t]; }
        float inv = 1.0f / ssum;
        float o0 = 0.f, o1 = 0.f;
#pragma unroll
        for (int t = 0; t < 10; ++t) {
            float wt = e[t] * inv;
            const float* vr = values + (size_t)topm[t] * 128;
            o0 += wt * vr[lane];
            o1 += wt * vr[lane + 64];
        }
        float* ob = dcat + ((size_t)b * 256) * 4096 + p;
        ob[(size_t)lane * 4096] = o0;
        ob[(size_t)(lane + 64) * 4096] = o1;
    }
}

// ---------------- constant fill for out-of-region center matches ----------------
__global__ void fill_c0_k(const float* __restrict__ c0, float* __restrict__ dcat) {
    int idx = blockIdx.x * 256 + threadIdx.x;
    int p = idx & 4095;
    int c = (idx >> 12) & 127;
    int b = idx >> 19;
    int h = p >> 6, ww = p & 63;
    if (h >= 23 && h <= 40 && ww >= 23 && ww <= 40) return;
    dcat[((size_t)b * 256 + c) * 4096 + p] = c0[c];
}

// ---------------- skip matching v5: split-bf16 MFMA, windowed exact rescore ----------------
__global__ void __launch_bounds__(256, 2) match_skip_v5(
        const float* __restrict__ zs,    // (16,128,64,64) raw queries
        const float* __restrict__ hn,    // (800,128) normalized fp32 (rescore)
        const unsigned short* __restrict__ hh,  // (800,128) bf16 hi
        const unsigned short* __restrict__ hl,  // (800,128) bf16 lo
        const float* __restrict__ hard,  // (800,128) raw
        float* __restrict__ dcat) {      // ch 128..255
    __shared__ unsigned short sm[32768]; // 64KB
    int b = blockIdx.x >> 6, pt = blockIdx.x & 63;
    int pbase = pt * 64;
    int tid = threadIdx.x;
    int w = tid >> 6, lane = tid & 63;
    int l15 = lane & 15, quad = lane >> 4;

    {
        int p = tid & 63, c0 = tid >> 6;
        for (int k = 0; k < 32; ++k) {
            int c = c0 + k * 4;
            float v = zs[((size_t)b * 128 + c) * 4096 + pbase + p];
            unsigned short hi = bf16_rne(v);
            unsigned short lo = bf16_rne(v - bf16_tof(hi));
            int off = p * 128 + (((c >> 3) ^ (p & 15)) << 3) + (c & 7);
            sm[off] = hi;
            sm[8192 + off] = lo;
        }
    }

    float v1[4], v2[4]; int i1[4], i2[4];
#pragma unroll
    for (int u = 0; u < 4; ++u) { v1[u] = NEG_INF; v2[u] = NEG_INF; i1[u] = 0x7fffffff; i2[u] = 0x7fffffff; }

    for (int chunk = 0; chunk < 13; ++chunk) {
        int mbase = chunk << 6;
        __syncthreads();
#pragma unroll
        for (int t = 0; t < 4; ++t) {
            int idx = tid + t * 256;          // 0..1023
            int row = idx >> 4, cb = idx & 15;
            int gm = mbase + row;
            uint4 dh = make_uint4(0u, 0u, 0u, 0u), dl = make_uint4(0u, 0u, 0u, 0u);
            if (gm < 800) {
                dh = *(const uint4*)(hh + (size_t)gm * 128 + cb * 8);
                dl = *(const uint4*)(hl + (size_t)gm * 128 + cb * 8);
            }
            int off = row * 128 + ((cb ^ (row & 15)) << 3);
            *(uint4*)&sm[16384 + off] = dh;
            *(uint4*)&sm[24576 + off] = dl;
        }
        __syncthreads();

        f32x4 acc[4];
#pragma unroll
        for (int kt = 0; kt < 4; ++kt) acc[kt] = (f32x4){0.f, 0.f, 0.f, 0.f};

#pragma unroll
        for (int ks = 0; ks < 4; ++ks) {
            int qrow = 16 * w + l15;
            int cb = ks * 4 + quad;
            int qoff = qrow * 128 + ((cb ^ (qrow & 15)) << 3);
            short8 ahi = *(const short8*)&sm[qoff];
            short8 alo = *(const short8*)&sm[8192 + qoff];
#pragma unroll
            for (int kt = 0; kt < 4; ++kt) {
                int krow = l15 + 16 * kt;
                int koff = krow * 128 + ((cb ^ (krow & 15)) << 3);
                short8 bhi = *(const short8*)&sm[16384 + koff];
                short8 blo = *(const short8*)&sm[24576 + koff];
                acc[kt] = __builtin_amdgcn_mfma_f32_16x16x32_bf16(alo, bhi, acc[kt], 0, 0, 0);
                acc[kt] = __builtin_amdgcn_mfma_f32_16x16x32_bf16(ahi, blo, acc[kt], 0, 0, 0);
                acc[kt] = __builtin_amdgcn_mfma_f32_16x16x32_bf16(ahi, bhi, acc[kt], 0, 0, 0);
            }
        }
#pragma unroll
        for (int kt = 0; kt < 4; ++kt) {
            int m = mbase + 16 * kt + l15;
            if (m < 800) {
#pragma unroll
                for (int u = 0; u < 4; ++u) {
                    float sv = acc[kt][u];
                    if (sv > v1[u] || (sv == v1[u] && m < i1[u])) {
                        v2[u] = v1[u]; i2[u] = i1[u]; v1[u] = sv; i1[u] = m;
                    } else if (sv > v2[u] || (sv == v2[u] && m < i2[u])) {
                        v2[u] = sv; i2[u] = m;
                    }
                }
            }
        }
    }
    __syncthreads();
    float4* red = (float4*)&sm[16384];   // [64 q][17 slots] float4 = 8704 shorts
#pragma unroll
    for (int u = 0; u < 4; ++u) {
        int q = 16 * w + quad * 4 + u;
        red[q * 17 + l15] = make_float4(v1[u], v2[u], __int_as_float(i1[u]), __int_as_float(i2[u]));
    }
    __syncthreads();
    int* bi_sh = (int*)&sm[16384 + 8704];  // [64] ints, in-bounds
    if (tid < 64) {
        int q = tid;
        float V1 = NEG_INF; int I1 = 0x7fffffff;
        for (int k = 0; k < 16; ++k) {
            float4 e = red[q * 17 + k];
            float cv[2] = { e.x, e.y };
            int ci_[2] = { __float_as_int(e.z), __float_as_int(e.w) };
#pragma unroll
            for (int t = 0; t < 2; ++t) {
                if (cv[t] > V1 || (cv[t] == V1 && ci_[t] < I1)) { V1 = cv[t]; I1 = ci_[t]; }
            }
        }
        float qn2 = 0.f;
        for (int c = 0; c < 128; ++c) {
            int off = q * 128 + (((c >> 3) ^ (q & 15)) << 3) + (c & 7);
            float qc = bf16_tof(sm[off]) + bf16_tof(sm[8192 + off]);
            qn2 += qc * qc;
        }
        float tau = 1.5e-4f * sqrtf(qn2) + 1e-12f;
        float thr = V1 - tau;
        int ncand = 0;
        for (int k = 0; k < 16; ++k) {
            float4 e = red[q * 17 + k];
            if (e.x >= thr && __float_as_int(e.z) != 0x7fffffff) ++ncand;
            if (e.y >= thr && __float_as_int(e.w) != 0x7fffffff) ++ncand;
        }
        int bi = I1;
        if (ncand > 1) {
            double bestd = -1.0e300; int besti = 0x7fffffff;
            for (int k = 0; k < 16; ++k) {
                float4 e = red[q * 17 + k];
                float cv[2] = { e.x, e.y };
                int ci_[2] = { __float_as_int(e.z), __float_as_int(e.w) };
                for (int t = 0; t < 2; ++t) {
                    if (cv[t] >= thr && ci_[t] != 0x7fffffff) {
                        const float* hr = hn + (size_t)ci_[t] * 128;
                        double d = 0.0;
                        for (int c = 0; c < 128; ++c) {
                            double qc = (double)zs[((size_t)b * 128 + c) * 4096 + pbase + q];
                            d += qc * (double)hr[c];
                        }
                        if (d > bestd || (d == bestd && ci_[t] < besti)) { bestd = d; besti = ci_[t]; }
                    }
                }
            }
            bi = besti;
        }
        bi_sh[q] = bi;
    }
    __syncthreads();
    {
        int q = tid & 63, seg = tid >> 6;
        int bi = bi_sh[q];
        const float* hr = hard + (size_t)bi * 128;
        float* ob = dcat + ((size_t)b * 256 + 128) * 4096 + pbase + q;
#pragma unroll
        for (int i = 0; i < 32; ++i) {
            int c = seg * 32 + i;
            ob[(size_t)c * 4096] = hr[c];
        }
    }
}

// ---------------- decoder conv1 v6: split-bf16 MFMA implicit GEMM, full-K, fused bias+relu ----------------
// block = (b, output row r0, cog of 32 co); M=32 co (2 m-tiles), N=64 px (4 n-tiles), K=8 ci-chunks x 9 taps
// LDS (shorts): xs_hi[0,6336) xs_lo[6336,12672) wsh_hi[12672,21888) wsh_lo[21888,31104) = 62208 B
__global__ void __launch_bounds__(256, 2) dec1_v6(
        const float* __restrict__ dcat, // (16,256,64,64)
        const unsigned short* __restrict__ wph,  // prepped weights hi
        const unsigned short* __restrict__ wpl,  // prepped weights lo
        const float* __restrict__ bias,
        float* __restrict__ d1) {       // (16,64,64,64)
    __shared__ unsigned short smem[31104];
    int bx = blockIdx.x;                // 16 b * 64 r0 * 2 cog = 2048
    int b = bx >> 7, rem = bx & 127;
    int r0 = rem >> 1, cog = rem & 1;
    int tid = threadIdx.x;
    int w = tid >> 6, lane = tid & 63;
    int l15 = lane & 15, quad = lane >> 4;
    int mt = w & 1, nh = w >> 1;        // wave: m-tile mt, n-tiles {2nh, 2nh+1}
    int gx = quad ^ ((l15 >> 2) & 3);   // A-read bank de-swizzle (matches prep_w1_k)

    // x staging descriptors: 3168 ci-pairs = (p 0..15, row 0..2, col 0..65)
    int lofA[13], gofA[13];
#pragma unroll
    for (int k = 0; k < 13; ++k) {
        int f = tid + k * 256;
        lofA[k] = 0; gofA[k] = -1;
        if (f < 3168) {
            int p = f / 198, rm = f % 198;
            int row = rm / 66, col = rm % 66;
            lofA[k] = ((row * 4 + (p >> 2)) * 66 + col) * 8 + (p & 3) * 2;
            int gr = r0 - 1 + row, gc = col - 1;
            if (gr >= 0 && gr < 64 && gc >= 0 && gc < 64)
                gofA[k] = (2 * p) * 4096 + gr * 64 + gc;
        }
    }
    // zero-prefill out-of-image LDS slots (persist across chunks; valid slots rewritten each chunk)
#pragma unroll
    for (int k = 0; k < 13; ++k) {
        int f = tid + k * 256;
        if (f < 3168 && gofA[k] < 0) {
            *(unsigned*)&smem[lofA[k]] = 0u;
            *(unsigned*)&smem[6336 + lofA[k]] = 0u;
        }
    }

    f32x4 acc[2];
    acc[0] = (f32x4){0.f, 0.f, 0.f, 0.f};
    acc[1] = (f32x4){0.f, 0.f, 0.f, 0.f};

    for (int chunk = 0; chunk < 8; ++chunk) {
        if (chunk) __syncthreads();
        // stage x (bf16 hi/lo pairs)
        const float* xb = dcat + ((size_t)b * 256 + chunk * 32) * 4096;
#pragma unroll
        for (int k = 0; k < 13; ++k) {
            if (gofA[k] >= 0) {
                float v0 = xb[gofA[k]];
                float v1 = xb[gofA[k] + 4096];
                unsigned short h0 = bf16_rne(v0), h1 = bf16_rne(v1);
                unsigned short l0 = bf16_rne(v0 - bf16_tof(h0));
                unsigned short l1 = bf16_rne(v1 - bf16_tof(h1));
                *(unsigned*)&smem[lofA[k]] = (unsigned)h0 | ((unsigned)h1 << 16);
                *(unsigned*)&smem[6336 + lofA[k]] = (unsigned)l0 | ((unsigned)l1 << 16);
            }
        }
        // stage weights: 1152 u16x8 per array
#pragma unroll
        for (int k = 0; k < 5; ++k) {
            int t = tid + k * 256;
            if (t < 1152) {
                int tap = t >> 7, wi = t & 127;
                size_t src = ((size_t)((chunk * 9 + tap) * 2 + cog)) * 1024 + wi * 8;
                int dst = 12672 + tap * 1024 + wi * 8;
                *(uint4*)&smem[dst]        = *(const uint4*)(wph + src);
                *(uint4*)&smem[dst + 9216] = *(const uint4*)(wpl + src);
            }
        }
        __syncthreads();
        // compute: 9 taps x 2 n-tiles x 3 passes
#pragma unroll
        for (int tap = 0; tap < 9; ++tap) {
            int kh = tap / 3, kw = tap % 3;
            int aoff = 12672 + tap * 1024 + (mt * 16 + l15) * 32 + gx * 8;
            short8 ahi = *(const short8*)&smem[aoff];
            short8 alo = *(const short8*)&smem[aoff + 9216];
#pragma unroll
            for (int n2 = 0; n2 < 2; ++n2) {
                int nt = nh * 2 + n2;
                int boff = ((kh * 4 + quad) * 66 + nt * 16 + l15 + kw) * 8;
                short8 bhi = *(const short8*)&smem[boff];
                short8 blo = *(const short8*)&smem[boff + 6336];
                acc[n2] = __builtin_amdgcn_mfma_f32_16x16x32_bf16(alo, bhi, acc[n2], 0, 0, 0);
                acc[n2] = __builtin_amdgcn_mfma_f32_16x16x32_bf16(ahi, blo, acc[n2], 0, 0, 0);
                acc[n2] = __builtin_amdgcn_mfma_f32_16x16x32_bf16(ahi, bhi, acc[n2], 0, 0, 0);
            }
        }
    }
    // epilogue: D row = quad*4+u (co within m-tile), col = l15 (px); bias + relu
#pragma unroll
    for (int n2 = 0; n2 < 2; ++n2) {
        int nt = nh * 2 + n2;
#pragma unroll
        for (int u = 0; u < 4; ++u) {
            int co = cog * 32 + mt * 16 + quad * 4 + u;
            float v = acc[n2][u] + bias[co];
            d1[((size_t)b * 64 + co) * 4096 + r0 * 64 + nt * 16 + l15] = fmaxf(v, 0.f);
        }
    }
}

// ---------------- transposed conv v2: quad-parity, 16 co per thread ----------------
template <int CIN, int COUT, int COG, int H>
__global__ void __launch_bounds__(256) tconv_v2(
        const float* __restrict__ x,   // (16,CIN,H,H)
        const float* __restrict__ w,   // (CIN,COUT,4,4)
        const float* __restrict__ bias,
        float* __restrict__ out) {     // (16,COUT,2H,2H)
    constexpr int NCOG = COUT / COG;
    constexpr int TPS = H / 16;
    constexpr int TILES = TPS * TPS;
    constexpr int HO = 2 * H;
    int bx = blockIdx.x;
    int b = bx / (NCOG * TILES), rem = bx % (NCOG * TILES);
    int cog = rem / TILES, tile = rem % TILES;
    int ti = tile / TPS, tj = tile % TPS;
    int tid = threadIdx.x;
    int i = ti * 16 + (tid >> 4);
    int j = tj * 16 + (tid & 15);

    float acc[2][2][COG];
#pragma unroll
    for (int pr = 0; pr < 2; ++pr)
#pragma unroll
        for (int pc = 0; pc < 2; ++pc)
#pragma unroll
            for (int co = 0; co < COG; ++co) acc[pr][pc][co] = 0.f;

    const float* xb = x + (size_t)b * CIN * H * H;
    for (int ci = 0; ci < CIN; ++ci) {
        const float* xp = xb + (size_t)ci * H * H;
        float xr[3][3];
#pragma unroll
        for (int dr = 0; dr < 3; ++dr) {
            int gr = i - 1 + dr;
            bool vr = (gr >= 0 && gr < H);
#pragma unroll
            for (int dc = 0; dc < 3; ++dc) {
                int gc = j - 1 + dc;
                xr[dr][dc] = (vr && gc >= 0 && gc < H) ? xp[gr * H + gc] : 0.f;
            }
        }
#pragma unroll
        for (int co = 0; co < COG; ++co) {
            const float* wp = w + (((size_t)ci * COUT + cog * COG + co) << 4);
            float wr[16];
#pragma unroll
            for (int k = 0; k < 16; ++k) wr[k] = wp[k];
#pragma unroll
            for (int pr = 0; pr < 2; ++pr)
#pragma unroll
                for (int a = 0; a < 2; ++a)
#pragma unroll
                    for (int pc = 0; pc < 2; ++pc)
#pragma unroll
                        for (int bb = 0; bb < 2; ++bb)
                            acc[pr][pc][co] += xr[pr + a][pc + bb] *
                                               wr[(3 - pr - 2 * a) * 4 + (3 - pc - 2 * bb)];
        }
    }
#pragma unroll
    for (int co = 0; co < COG; ++co) {
        float bv = bias[cog * COG + co];
        float* ob = out + ((size_t)b * COUT + cog * COG + co) * HO * HO;
#pragma unroll
        for (int pr = 0; pr < 2; ++pr)
#pragma unroll
            for (int pc = 0; pc < 2; ++pc)
                ob[(2 * i + pr) * HO + 2 * j + pc] = fmaxf(acc[pr][pc][co] + bv, 0.f);
    }
}

// ---------------- final conv (16->1) 3x3, 4 px per thread ----------------
__global__ void final_v2(const float* __restrict__ t2,  // (16,16,256,256)
                         const float* __restrict__ w,   // (1,16,3,3)
                         const float* __restrict__ bias,
                         float* __restrict__ out) {     // (16,1,256,256)
    int g = blockIdx.x * 256 + threadIdx.x;
    int pxb = g * 4;
    int b = pxb >> 16, p = pxb & 65535;
    int h = p >> 8, c0 = p & 255;
    const float* tb = t2 + (size_t)b * 16 * 65536;
    float acc[4];
    float bv = bias[0];
#pragma unroll
    for (int t = 0; t < 4; ++t) acc[t] = bv;
    for (int ci = 0; ci < 16; ++ci) {
        const float* pp = tb + (size_t)ci * 65536;
        const float* w9 = w + ci * 9;
        float win[3][6];
#pragma unroll
        for (int dr = 0; dr < 3; ++dr) {
            int rr = h - 1 + dr;
            bool vr = (rr >= 0 && rr < 256);
#pragma unroll
            for (int dc = 0; dc < 6; ++dc) {
                int cc = c0 - 1 + dc;
                win[dr][dc] = (vr && cc >= 0 && cc < 256) ? pp[rr * 256 + cc] : 0.f;
            }
        }
#pragma unroll
        for (int t = 0; t < 4; ++t)
#pragma unroll
            for (int dr = 0; dr < 3; ++dr)
#pragma unroll
                for (int dc = 0; dc < 3; ++dc)
                    acc[t] += win[dr][t + dc] * w9[dr * 3 + dc];
    }
    *(float4*)(out + pxb) = make_float4(acc[0], acc[1], acc[2], acc[3]);
}

// ---------------- launch ----------------
extern "C" void kernel_launch(void* const* d_in, const int* in_sizes, int n_in,
                              void* d_out, int out_size, void* d_ws, size_t ws_size,
                              hipStream_t stream) {
    (void)in_sizes; (void)n_in; (void)out_size; (void)ws_size;
    const float* x     = (const float*)d_in[0];
    const float* cw1   = (const float*)d_in[1];
    const float* cb1   = (const float*)d_in[2];
    const float* cw2   = (const float*)d_in[3];
    const float* cb2   = (const float*)d_in[4];
    const float* sw1   = (const float*)d_in[5];
    const float* sb1   = (const float*)d_in[6];
    const float* sw2   = (const float*)d_in[7];
    const float* sb2   = (const float*)d_in[8];
    const float* mkeys = (const float*)d_in[9];
    const float* mvals = (const float*)d_in[10];
    const float* mhard = (const float*)d_in[11];
    const float* dw1   = (const float*)d_in[12];
    const float* db1   = (const float*)d_in[13];
    const float* tw1   = (const float*)d_in[14];
    const float* tb1   = (const float*)d_in[15];
    const float* tw2   = (const float*)d_in[16];
    const float* tb2   = (const float*)d_in[17];
    const float* dw2   = (const float*)d_in[18];
    const float* db2   = (const float*)d_in[19];
    float* out = (float*)d_out;
    float* ws  = (float*)d_ws;

    const size_t OFF_KN  = 0;                   // knR: 800*128
    const size_t OFF_HN  = 102400;              // hn:  800*128
    const size_t OFF_C0  = 204800;              // c0:  128
    const size_t OFF_R14 = 204928;              // zc1 -> zs -> t1
    const size_t OFF_R2  = OFF_R14 + 8388608;   // (unused spare)
    const size_t OFF_R3  = OFF_R2 + 8388608;    // zs1 -> d1
    const size_t OFF_R5  = OFF_R3 + 4194304;    // dcat -> t2
    const size_t OFF_ZCQ = OFF_R5 + 16777216;   // zcq: 16*324*128
    const size_t OFF_HH  = OFF_ZCQ + 663552;    // hh: 800*128 u16 = 51200 floats
    const size_t OFF_HL  = OFF_HH + 51200;      // hl
    const size_t OFF_WH  = OFF_HL + 51200;      // wph: 147456 u16 = 73728 floats
    const size_t OFF_WL  = OFF_WH + 73728;      // wpl

    float* knR  = ws + OFF_KN;
    float* hn   = ws + OFF_HN;
    float* c0   = ws + OFF_C0;
    float* zc1  = ws + OFF_R14;
    float* zs   = ws + OFF_R14;
    float* t1   = ws + OFF_R14;
    float* zs1  = ws + OFF_R3;
    float* d1b  = ws + OFF_R3;
    float* dcat = ws + OFF_R5;
    float* t2   = ws + OFF_R5;
    float* zcq  = ws + OFF_ZCQ;
    unsigned short* hhp = (unsigned short*)(ws + OFF_HH);
    unsigned short* hlp = (unsigned short*)(ws + OFF_HL);
    unsigned short* wph = (unsigned short*)(ws + OFF_WH);
    unsigned short* wpl = (unsigned short*)(ws + OFF_WL);

    prep_norm_k<<<800, 128, 0, stream>>>(mkeys, mhard, knR, hn, hhp, hlp);
    prep_c0_k<<<1, 128, 0, stream>>>(mvals, c0);
    prep_w1_k<<<576, 256, 0, stream>>>(dw1, wph, wpl);

    ce1_k<<<16 * 2 * 6, 256, 0, stream>>>(x, cw1, cb1, zc1);
    se1_k<<<16 * 64, 256, 0, stream>>>(x, sw1, sb1, zs1);
    ce2_v3<<<16 * 16, 256, 0, stream>>>(zc1, cw2, cb2, zcq);
    se2_v2<<<16 * 16 * 16, 256, 0, stream>>>(zs1, sw2, sb2, zs);  // overwrites zc1 (dead)

    match_center_v2<<<648, 256, 0, stream>>>(zcq, knR, mvals, dcat);
    fill_c0_k<<<32768, 256, 0, stream>>>(c0, dcat);
    match_skip_v5<<<16 * 64, 256, 0, stream>>>(zs, hn, hhp, hlp, mhard, dcat);

    dec1_v6<<<2048, 256, 0, stream>>>(dcat, wph, wpl, db1, d1b);  // full-K MFMA, bias+relu fused

    tconv_v2<64, 32, 16, 64><<<16 * 2 * 16, 256, 0, stream>>>(d1b, tw1, tb1, t1);   // overwrites zs (dead)
    tconv_v2<32, 16, 16, 128><<<16 * 1 * 64, 256, 0, stream>>>(t1, tw2, tb2, t2);   // overwrites dcat (dead)
    final_v2<<<1024, 256, 0, stream>>>(t2, dw2, db2, out);
}

// Round 12
// 1011.428 us; speedup vs baseline: 1.7820x; 1.0765x over previous
//
#include <hip/hip_runtime.h>
#include <cstdint>
#include <cstddef>

#define NEG_INF (-3.0e38f)

typedef __attribute__((ext_vector_type(8))) short short8;
typedef __attribute__((ext_vector_type(4))) float f32x4;

__device__ inline unsigned short bf16_rne(float x) {
    unsigned u = __float_as_uint(x);
    unsigned r = u + 0x7fffu + ((u >> 16) & 1u);
    return (unsigned short)(r >> 16);
}
__device__ inline float bf16_tof(unsigned short h) {
    return __uint_as_float(((unsigned)h) << 16);
}

// ---------------- prep: normalize keys/hard + bf16 hi/lo split of hn ----------------
__global__ void prep_norm_k(const float* __restrict__ keys,
                            const float* __restrict__ hard,
                            float* __restrict__ knR,   // [800][128] normalized keys
                            float* __restrict__ hn,    // [800][128] normalized hard
                            unsigned short* __restrict__ hh,  // [800][128] bf16 hi
                            unsigned short* __restrict__ hl) {// [800][128] bf16 lo
    int m = blockIdx.x;      // 0..799
    int c = threadIdx.x;     // 0..127
    float kv = keys[m * 128 + c];
    float hv = hard[m * 128 + c];
    __shared__ float s1[128];
    __shared__ float s2[128];
    s1[c] = kv * kv;
    s2[c] = hv * hv;
    __syncthreads();
    for (int off = 64; off > 0; off >>= 1) {
        if (c < off) { s1[c] += s1[c + off]; s2[c] += s2[c + off]; }
        __syncthreads();
    }
    float ks = 1.0f / fmaxf(sqrtf(s1[0]), 1e-12f);
    float hs = 1.0f / fmaxf(sqrtf(s2[0]), 1e-12f);
    knR[m * 128 + c] = kv * ks;
    float hnv = hv * hs;
    hn[m * 128 + c] = hnv;
    unsigned short hi = bf16_rne(hnv);
    hh[m * 128 + c] = hi;
    hl[m * 128 + c] = bf16_rne(hnv - bf16_tof(hi));
}

__global__ void prep_c0_k(const float* __restrict__ values, float* __restrict__ c0) {
    int c = threadIdx.x;  // 128 threads
    float s = 0.f;
    for (int m = 0; m < 10; ++m) s += values[m * 128 + c];
    c0[c] = s * 0.1f;
}

// ---------------- prep: dec1 weights -> chunked bf16 hi/lo, MFMA A-layout w/ bank swizzle ----------------
__global__ void prep_w1_k(const float* __restrict__ dw1,   // (64,256,3,3)
                          unsigned short* __restrict__ wph,
                          unsigned short* __restrict__ wpl) {
    int idx = blockIdx.x * 256 + threadIdx.x;   // 147456 total
    int co = idx / 2304, r2 = idx % 2304;
    int ci = r2 / 9, tap = r2 % 9;
    float v = dw1[idx];
    int chunk = ci >> 5, cog = co >> 5, co32 = co & 31;
    int cil = ci & 31, g = cil >> 3, j = cil & 7;
    int gs = g ^ ((co32 >> 2) & 3);
    int off = ((((chunk * 9 + tap) * 2 + cog) * 32 + co32) * 4 + gs) * 8 + j;
    unsigned short hi = bf16_rne(v);
    wph[off] = hi;
    wpl[off] = bf16_rne(v - bf16_tof(hi));
}

// ---------------- center conv1+pool: only pooled rect [45,83)^2 ----------------
__global__ void ce1_k(const float* __restrict__ x,   // (16,1,256,256)
                      const float* __restrict__ w,   // (32,1,3,3)
                      const float* __restrict__ bias,
                      float* __restrict__ out) {     // (16,32,128,128) rect only
    int bx = blockIdx.x;            // 16 b * 2 cog * 6 tiles
    int b = bx / 12, rem = bx % 12;
    int cog = rem / 6, tile = rem % 6;
    int idx = tile * 256 + threadIdx.x;
    if (idx >= 1444) return;
    int ph = 45 + idx / 38, pw = 45 + idx % 38;
    const float* xb = x + (size_t)b * 65536;
    float win[4][4];
#pragma unroll
    for (int r = 0; r < 4; ++r) {
        int ih = 2 * ph - 1 + r;
        bool vr = (ih >= 96 && ih < 160);
#pragma unroll
        for (int c = 0; c < 4; ++c) {
            int iw = 2 * pw - 1 + c;
            win[r][c] = (vr && iw >= 96 && iw < 160) ? xb[ih * 256 + iw] : 0.f;
        }
    }
#pragma unroll
    for (int co8 = 0; co8 < 16; ++co8) {
        int co = cog * 16 + co8;
        const float* w9 = w + co * 9;
        float bv = bias[co];
        float a00 = bv, a01 = bv, a10 = bv, a11 = bv;
#pragma unroll
        for (int kh = 0; kh < 3; ++kh)
#pragma unroll
            for (int kw = 0; kw < 3; ++kw) {
                float wv = w9[kh * 3 + kw];
                a00 += win[kh][kw] * wv;
                a01 += win[kh][kw + 1] * wv;
                a10 += win[kh + 1][kw] * wv;
                a11 += win[kh + 1][kw + 1] * wv;
            }
        float mx = fmaxf(fmaxf(a00, a01), fmaxf(a10, a11));
        out[((size_t)b * 32 + co) * 16384 + ph * 128 + pw] = fmaxf(mx, 0.f);
    }
}

// ---------------- skip conv1+pool: full, 16 co per thread ----------------
__global__ void se1_k(const float* __restrict__ x,   // (16,1,256,256)
                      const float* __restrict__ w,   // (16,1,3,3)
                      const float* __restrict__ bias,
                      float* __restrict__ out) {     // (16,16,128,128)
    int bx = blockIdx.x;            // 16 b * 64 tiles
    int b = bx >> 6, tile = bx & 63;
    int idx = tile * 256 + threadIdx.x;   // 0..16383
    int ph = idx >> 7, pw = idx & 127;
    const float* xb = x + (size_t)b * 65536;
    float win[4][4];
#pragma unroll
    for (int r = 0; r < 4; ++r) {
        int ih = 2 * ph - 1 + r;
        bool vr = (ih >= 0 && ih < 256);
#pragma unroll
        for (int c = 0; c < 4; ++c) {
            int iw = 2 * pw - 1 + c;
            win[r][c] = (vr && iw >= 0 && iw < 256) ? xb[ih * 256 + iw] : 0.f;
        }
    }
#pragma unroll
    for (int co = 0; co < 16; ++co) {
        const float* w9 = w + co * 9;
        float bv = bias[co];
        float a00 = bv, a01 = bv, a10 = bv, a11 = bv;
#pragma unroll
        for (int kh = 0; kh < 3; ++kh)
#pragma unroll
            for (int kw = 0; kw < 3; ++kw) {
                float wv = w9[kh * 3 + kw];
                a00 += win[kh][kw] * wv;
                a01 += win[kh][kw + 1] * wv;
                a10 += win[kh + 1][kw] * wv;
                a11 += win[kh + 1][kw + 1] * wv;
            }
        float mx = fmaxf(fmaxf(a00, a01), fmaxf(a10, a11));
        out[((size_t)b * 16 + co) * 16384 + idx] = fmaxf(mx, 0.f);
    }
}

// ---------------- center conv2 v3 (32->128) + relu + pool -> query-major zcq ----------------
__global__ void __launch_bounds__(256) ce2_v3(
        const float* __restrict__ zc1,  // (16,32,128,128)
        const float* __restrict__ w,    // (128,32,3,3)
        const float* __restrict__ bias,
        float* __restrict__ zcq) {      // (16*324, 128) query-major
    int bx = blockIdx.x;                // 16 b * 16 cog
    int b = bx >> 4, cog = bx & 15;
    const float* ib = zc1 + (size_t)b * 32 * 16384;
    for (int px = threadIdx.x; px < 324; px += 256) {
        int h = 23 + px / 18, ww = 23 + px % 18;
        float acc[8][4];
#pragma unroll
        for (int c8 = 0; c8 < 8; ++c8)
#pragma unroll
            for (int t = 0; t < 4; ++t) acc[c8][t] = 0.f;
        for (int ci = 0; ci < 32; ++ci) {
            const float* p = ib + ci * 16384 + (2 * h - 1) * 128 + (2 * ww - 1);
            float win[4][4];
#pragma unroll
            for (int r = 0; r < 4; ++r)
#pragma unroll
                for (int s = 0; s < 4; ++s) win[r][s] = p[r * 128 + s];
#pragma unroll
            for (int c8 = 0; c8 < 8; ++c8) {
                const float* w9 = w + ((size_t)(cog * 8 + c8) * 32 + ci) * 9;
#pragma unroll
                for (int kh = 0; kh < 3; ++kh)
#pragma unroll
                    for (int kw = 0; kw < 3; ++kw) {
                        float wv = w9[kh * 3 + kw];
                        acc[c8][0] += win[kh][kw] * wv;
                        acc[c8][1] += win[kh][kw + 1] * wv;
                        acc[c8][2] += win[kh + 1][kw] * wv;
                        acc[c8][3] += win[kh + 1][kw + 1] * wv;
                    }
            }
        }
#pragma unroll
        for (int c8 = 0; c8 < 8; ++c8) {
            int co = cog * 8 + c8;
            float mx = fmaxf(fmaxf(acc[c8][0], acc[c8][1]), fmaxf(acc[c8][2], acc[c8][3])) + bias[co];
            zcq[((size_t)(b * 324 + px)) * 128 + co] = fmaxf(mx, 0.f);
        }
    }
}

// ---------------- skip conv2 (16->128) + relu + pool, 8 co per thread ----------------
__global__ void se2_v2(const float* __restrict__ zs1,  // (16,16,128,128)
                       const float* __restrict__ w,    // (128,16,3,3)
                       const float* __restrict__ bias,
                       float* __restrict__ zs) {       // (16,128,64,64)
    int bx = blockIdx.x;            // 16 b * 16 cog * 16 tiles = 4096
    int b = bx >> 8, rem = bx & 255;
    int cog = rem >> 4, tile = rem & 15;
    int px = tile * 256 + threadIdx.x;  // 0..4095
    int ph = px >> 6, pw = px & 63;
    const float* ib = zs1 + (size_t)b * 16 * 16384;
    float acc[8][4];
#pragma unroll
    for (int c8 = 0; c8 < 8; ++c8)
#pragma unroll
        for (int t = 0; t < 4; ++t) acc[c8][t] = 0.f;
    for (int ci = 0; ci < 16; ++ci) {
        const float* p = ib + ci * 16384;
        float win[4][4];
#pragma unroll
        for (int r = 0; r < 4; ++r) {
            int rr = 2 * ph - 1 + r;
            bool vr = (rr >= 0 && rr < 128);
#pragma unroll
            for (int s = 0; s < 4; ++s) {
                int cc = 2 * pw - 1 + s;
                win[r][s] = (vr && cc >= 0 && cc < 128) ? p[rr * 128 + cc] : 0.f;
            }
        }
#pragma unroll
        for (int c8 = 0; c8 < 8; ++c8) {
            const float* w9 = w + ((size_t)(cog * 8 + c8) * 16 + ci) * 9;
#pragma unroll
            for (int kh = 0; kh < 3; ++kh)
#pragma unroll
                for (int kw = 0; kw < 3; ++kw) {
                    float wv = w9[kh * 3 + kw];
                    acc[c8][0] += win[kh][kw] * wv;
                    acc[c8][1] += win[kh][kw + 1] * wv;
                    acc[c8][2] += win[kh + 1][kw] * wv;
                    acc[c8][3] += win[kh + 1][kw + 1] * wv;
                }
        }
    }
#pragma unroll
    for (int c8 = 0; c8 < 8; ++c8) {
        int co = cog * 8 + c8;
        float bv = bias[co];
        float mx = fmaxf(fmaxf(acc[c8][0], acc[c8][1]), fmaxf(acc[c8][2], acc[c8][3])) + bv;
        zs[((size_t)b * 128 + co) * 4096 + px] = fmaxf(mx, 0.f);
    }
}

// ---------------- center matching v2 (unchanged) ----------------
__global__ void __launch_bounds__(256) match_center_v2(
        const float* __restrict__ zcq,    // (16*324, 128) raw queries
        const float* __restrict__ knR,    // (800,128) normalized keys
        const float* __restrict__ values, // (800,128)
        float* __restrict__ dcat) {       // (16,256,64,64), ch 0..127
    __shared__ float shk[128 * 65];
    __shared__ float qint[4 * 256];
    int tid = threadIdx.x;
    int w = tid >> 6, lane = tid & 63;
    int g0 = blockIdx.x * 8 + 2 * w;

#pragma unroll
    for (int i = 0; i < 2; ++i) {
        const float* qp = zcq + (size_t)(g0 + i) * 128;
        float v0 = qp[lane], v1 = qp[lane + 64];
        float ss = v0 * v0 + v1 * v1;
#pragma unroll
        for (int off = 32; off > 0; off >>= 1) ss += __shfl_xor(ss, off);
        float sc = 1.0f / fmaxf(sqrtf(ss), 1e-12f);
        qint[w * 256 + lane * 2 + i] = v0 * sc;
        qint[w * 256 + (lane + 64) * 2 + i] = v1 * sc;
    }

    float sim2[2][13];
#pragma unroll
    for (int k = 0; k < 13; ++k) { sim2[0][k] = 0.f; sim2[1][k] = 0.f; }

    for (int chunk = 0; chunk < 13; ++chunk) {
        int mbase = chunk << 6;
        __syncthreads();
#pragma unroll
        for (int t = 0; t < 8; ++t) {
            int idx = tid + t * 256;
            int kk = idx >> 5, c4 = idx & 31;
            int m = mbase + kk;
            float4 kv = (m < 800) ? *(const float4*)(knR + (size_t)m * 128 + c4 * 4)
                                  : make_float4(0.f, 0.f, 0.f, 0.f);
            shk[(4 * c4 + 0) * 65 + kk] = kv.x;
            shk[(4 * c4 + 1) * 65 + kk] = kv.y;
            shk[(4 * c4 + 2) * 65 + kk] = kv.z;
            shk[(4 * c4 + 3) * 65 + kk] = kv.w;
        }
        __syncthreads();
        float s0 = sim2[0][chunk], s1 = sim2[1][chunk];
        const float* qw = qint + w * 256;
#pragma unroll 4
        for (int c2 = 0; c2 < 64; ++c2) {
            float4 qq = *(const float4*)(qw + c2 * 4);
            float k0 = shk[(2 * c2) * 65 + lane];
            float k1 = shk[(2 * c2 + 1) * 65 + lane];
            s0 += qq.x * k0; s1 += qq.y * k0;
            s0 += qq.z * k1; s1 += qq.w * k1;
        }
        sim2[0][chunk] = s0; sim2[1][chunk] = s1;
    }

#pragma unroll
    for (int i = 0; i < 2; ++i) {
        int g = g0 + i;
        int b = g / 324, q = g - b * 324;
        int h = 23 + q / 18, ww = 23 + q % 18;
        int p = h * 64 + ww;

        float sim[13];
#pragma unroll
        for (int k = 0; k < 13; ++k)
            sim[k] = (lane + (k << 6) < 800) ? sim2[i][k] : NEG_INF;

        float topv[11]; int topm[11];
#pragma unroll
        for (int t = 0; t < 11; ++t) {
            float bvv = NEG_INF; int bm = 0x7fffffff;
#pragma unroll
            for (int k = 0; k < 13; ++k) {
                if (sim[k] > bvv) { bvv = sim[k]; bm = lane + (k << 6); }
            }
#pragma unroll
            for (int off = 32; off > 0; off >>= 1) {
                float ov = __shfl_xor(bvv, off);
                int om = __shfl_xor(bm, off);
                if (ov > bvv || (ov == bvv && om < bm)) { bvv = ov; bm = om; }
            }
            topv[t] = bvv; topm[t] = bm;
            if ((bm & 63) == lane) {
                int kk = bm >> 6;
#pragma unroll
                for (int k = 0; k < 13; ++k)
                    if (k == kk) sim[k] = NEG_INF;
            }
        }
        if (topv[9] - topv[10] < 1e-4f) {
            double s9 = 0.0, s10 = 0.0;
            const float* k9 = knR + (size_t)topm[9] * 128;
            const float* k10 = knR + (size_t)topm[10] * 128;
            for (int c = 0; c < 128; ++c) {
                double qc = (double)qint[w * 256 + c * 2 + i];
                s9 += qc * (double)k9[c];
                s10 += qc * (double)k10[c];
            }
            if ((s10 > s9) || (s10 == s9 && topm[10] < topm[9])) {
                topv[9] = topv[10]; topm[9] = topm[10];
            }
        }
        float mx = topv[0];
        float e[10], ssum = 0.f;
#pragma unroll
        for (int t = 0; t < 10; ++t) { e[t] = expf(topv[t] - mx); ssum += e[t]; }
        float inv = 1.0f / ssum;
        float o0 = 0.f, o1 = 0.f;
#pragma unroll
        for (int t = 0; t < 10; ++t) {
            float wt = e[t] * inv;
            const float* vr = values + (size_t)topm[t] * 128;
            o0 += wt * vr[lane];
            o1 += wt * vr[lane + 64];
        }
        float* ob = dcat + ((size_t)b * 256) * 4096 + p;
        ob[(size_t)lane * 4096] = o0;
        ob[(size_t)(lane + 64) * 4096] = o1;
    }
}

// ---------------- constant fill for out-of-region center matches ----------------
__global__ void fill_c0_k(const float* __restrict__ c0, float* __restrict__ dcat) {
    int idx = blockIdx.x * 256 + threadIdx.x;
    int p = idx & 4095;
    int c = (idx >> 12) & 127;
    int b = idx >> 19;
    int h = p >> 6, ww = p & 63;
    if (h >= 23 && h <= 40 && ww >= 23 && ww <= 40) return;
    dcat[((size_t)b * 256 + c) * 4096 + p] = c0[c];
}

// ---------------- skip matching v5: split-bf16 MFMA, windowed exact rescore ----------------
__global__ void __launch_bounds__(256, 2) match_skip_v5(
        const float* __restrict__ zs,    // (16,128,64,64) raw queries
        const float* __restrict__ hn,    // (800,128) normalized fp32 (rescore)
        const unsigned short* __restrict__ hh,  // (800,128) bf16 hi
        const unsigned short* __restrict__ hl,  // (800,128) bf16 lo
        const float* __restrict__ hard,  // (800,128) raw
        float* __restrict__ dcat) {      // ch 128..255
    __shared__ unsigned short sm[32768]; // 64KB
    int b = blockIdx.x >> 6, pt = blockIdx.x & 63;
    int pbase = pt * 64;
    int tid = threadIdx.x;
    int w = tid >> 6, lane = tid & 63;
    int l15 = lane & 15, quad = lane >> 4;

    {
        int p = tid & 63, c0 = tid >> 6;
        for (int k = 0; k < 32; ++k) {
            int c = c0 + k * 4;
            float v = zs[((size_t)b * 128 + c) * 4096 + pbase + p];
            unsigned short hi = bf16_rne(v);
            unsigned short lo = bf16_rne(v - bf16_tof(hi));
            int off = p * 128 + (((c >> 3) ^ (p & 15)) << 3) + (c & 7);
            sm[off] = hi;
            sm[8192 + off] = lo;
        }
    }

    float v1[4], v2[4]; int i1[4], i2[4];
#pragma unroll
    for (int u = 0; u < 4; ++u) { v1[u] = NEG_INF; v2[u] = NEG_INF; i1[u] = 0x7fffffff; i2[u] = 0x7fffffff; }

    for (int chunk = 0; chunk < 13; ++chunk) {
        int mbase = chunk << 6;
        __syncthreads();
#pragma unroll
        for (int t = 0; t < 4; ++t) {
            int idx = tid + t * 256;          // 0..1023
            int row = idx >> 4, cb = idx & 15;
            int gm = mbase + row;
            uint4 dh = make_uint4(0u, 0u, 0u, 0u), dl = make_uint4(0u, 0u, 0u, 0u);
            if (gm < 800) {
                dh = *(const uint4*)(hh + (size_t)gm * 128 + cb * 8);
                dl = *(const uint4*)(hl + (size_t)gm * 128 + cb * 8);
            }
            int off = row * 128 + ((cb ^ (row & 15)) << 3);
            *(uint4*)&sm[16384 + off] = dh;
            *(uint4*)&sm[24576 + off] = dl;
        }
        __syncthreads();

        f32x4 acc[4];
#pragma unroll
        for (int kt = 0; kt < 4; ++kt) acc[kt] = (f32x4){0.f, 0.f, 0.f, 0.f};

#pragma unroll
        for (int ks = 0; ks < 4; ++ks) {
            int qrow = 16 * w + l15;
            int cb = ks * 4 + quad;
            int qoff = qrow * 128 + ((cb ^ (qrow & 15)) << 3);
            short8 ahi = *(const short8*)&sm[qoff];
            short8 alo = *(const short8*)&sm[8192 + qoff];
#pragma unroll
            for (int kt = 0; kt < 4; ++kt) {
                int krow = l15 + 16 * kt;
                int koff = krow * 128 + ((cb ^ (krow & 15)) << 3);
                short8 bhi = *(const short8*)&sm[16384 + koff];
                short8 blo = *(const short8*)&sm[24576 + koff];
                acc[kt] = __builtin_amdgcn_mfma_f32_16x16x32_bf16(alo, bhi, acc[kt], 0, 0, 0);
                acc[kt] = __builtin_amdgcn_mfma_f32_16x16x32_bf16(ahi, blo, acc[kt], 0, 0, 0);
                acc[kt] = __builtin_amdgcn_mfma_f32_16x16x32_bf16(ahi, bhi, acc[kt], 0, 0, 0);
            }
        }
#pragma unroll
        for (int kt = 0; kt < 4; ++kt) {
            int m = mbase + 16 * kt + l15;
            if (m < 800) {
#pragma unroll
                for (int u = 0; u < 4; ++u) {
                    float sv = acc[kt][u];
                    if (sv > v1[u] || (sv == v1[u] && m < i1[u])) {
                        v2[u] = v1[u]; i2[u] = i1[u]; v1[u] = sv; i1[u] = m;
                    } else if (sv > v2[u] || (sv == v2[u] && m < i2[u])) {
                        v2[u] = sv; i2[u] = m;
                    }
                }
            }
        }
    }
    __syncthreads();
    float4* red = (float4*)&sm[16384];   // [64 q][17 slots] float4 = 8704 shorts
#pragma unroll
    for (int u = 0; u < 4; ++u) {
        int q = 16 * w + quad * 4 + u;
        red[q * 17 + l15] = make_float4(v1[u], v2[u], __int_as_float(i1[u]), __int_as_float(i2[u]));
    }
    __syncthreads();
    int* bi_sh = (int*)&sm[16384 + 8704];  // [64] ints, in-bounds
    if (tid < 64) {
        int q = tid;
        float V1 = NEG_INF; int I1 = 0x7fffffff;
        for (int k = 0; k < 16; ++k) {
            float4 e = red[q * 17 + k];
            float cv[2] = { e.x, e.y };
            int ci_[2] = { __float_as_int(e.z), __float_as_int(e.w) };
#pragma unroll
            for (int t = 0; t < 2; ++t) {
                if (cv[t] > V1 || (cv[t] == V1 && ci_[t] < I1)) { V1 = cv[t]; I1 = ci_[t]; }
            }
        }
        float qn2 = 0.f;
        for (int c = 0; c < 128; ++c) {
            int off = q * 128 + (((c >> 3) ^ (q & 15)) << 3) + (c & 7);
            float qc = bf16_tof(sm[off]) + bf16_tof(sm[8192 + off]);
            qn2 += qc * qc;
        }
        float tau = 1.5e-4f * sqrtf(qn2) + 1e-12f;
        float thr = V1 - tau;
        int ncand = 0;
        for (int k = 0; k < 16; ++k) {
            float4 e = red[q * 17 + k];
            if (e.x >= thr && __float_as_int(e.z) != 0x7fffffff) ++ncand;
            if (e.y >= thr && __float_as_int(e.w) != 0x7fffffff) ++ncand;
        }
        int bi = I1;
        if (ncand > 1) {
            double bestd = -1.0e300; int besti = 0x7fffffff;
            for (int k = 0; k < 16; ++k) {
                float4 e = red[q * 17 + k];
                float cv[2] = { e.x, e.y };
                int ci_[2] = { __float_as_int(e.z), __float_as_int(e.w) };
                for (int t = 0; t < 2; ++t) {
                    if (cv[t] >= thr && ci_[t] != 0x7fffffff) {
                        const float* hr = hn + (size_t)ci_[t] * 128;
                        double d = 0.0;
                        for (int c = 0; c < 128; ++c) {
                            double qc = (double)zs[((size_t)b * 128 + c) * 4096 + pbase + q];
                            d += qc * (double)hr[c];
                        }
                        if (d > bestd || (d == bestd && ci_[t] < besti)) { bestd = d; besti = ci_[t]; }
                    }
                }
            }
            bi = besti;
        }
        bi_sh[q] = bi;
    }
    __syncthreads();
    {
        int q = tid & 63, seg = tid >> 6;
        int bi = bi_sh[q];
        const float* hr = hard + (size_t)bi * 128;
        float* ob = dcat + ((size_t)b * 256 + 128) * 4096 + pbase + q;
#pragma unroll
        for (int i = 0; i < 32; ++i) {
            int c = seg * 32 + i;
            ob[(size_t)c * 4096] = hr[c];
        }
    }
}

// ---------------- decoder conv1 v6: split-bf16 MFMA implicit GEMM, full-K, fused bias+relu ----------------
__global__ void __launch_bounds__(256, 2) dec1_v6(
        const float* __restrict__ dcat, // (16,256,64,64)
        const unsigned short* __restrict__ wph,  // prepped weights hi
        const unsigned short* __restrict__ wpl,  // prepped weights lo
        const float* __restrict__ bias,
        float* __restrict__ d1) {       // (16,64,64,64)
    __shared__ unsigned short smem[31104];
    int bx = blockIdx.x;                // 16 b * 64 r0 * 2 cog = 2048
    int b = bx >> 7, rem = bx & 127;
    int r0 = rem >> 1, cog = rem & 1;
    int tid = threadIdx.x;
    int w = tid >> 6, lane = tid & 63;
    int l15 = lane & 15, quad = lane >> 4;
    int mt = w & 1, nh = w >> 1;
    int gx = quad ^ ((l15 >> 2) & 3);

    int lofA[13], gofA[13];
#pragma unroll
    for (int k = 0; k < 13; ++k) {
        int f = tid + k * 256;
        lofA[k] = 0; gofA[k] = -1;
        if (f < 3168) {
            int p = f / 198, rm = f % 198;
            int row = rm / 66, col = rm % 66;
            lofA[k] = ((row * 4 + (p >> 2)) * 66 + col) * 8 + (p & 3) * 2;
            int gr = r0 - 1 + row, gc = col - 1;
            if (gr >= 0 && gr < 64 && gc >= 0 && gc < 64)
                gofA[k] = (2 * p) * 4096 + gr * 64 + gc;
        }
    }
#pragma unroll
    for (int k = 0; k < 13; ++k) {
        int f = tid + k * 256;
        if (f < 3168 && gofA[k] < 0) {
            *(unsigned*)&smem[lofA[k]] = 0u;
            *(unsigned*)&smem[6336 + lofA[k]] = 0u;
        }
    }

    f32x4 acc[2];
    acc[0] = (f32x4){0.f, 0.f, 0.f, 0.f};
    acc[1] = (f32x4){0.f, 0.f, 0.f, 0.f};

    for (int chunk = 0; chunk < 8; ++chunk) {
        if (chunk) __syncthreads();
        const float* xb = dcat + ((size_t)b * 256 + chunk * 32) * 4096;
#pragma unroll
        for (int k = 0; k < 13; ++k) {
            if (gofA[k] >= 0) {
                float v0 = xb[gofA[k]];
                float v1 = xb[gofA[k] + 4096];
                unsigned short h0 = bf16_rne(v0), h1 = bf16_rne(v1);
                unsigned short l0 = bf16_rne(v0 - bf16_tof(h0));
                unsigned short l1 = bf16_rne(v1 - bf16_tof(h1));
                *(unsigned*)&smem[lofA[k]] = (unsigned)h0 | ((unsigned)h1 << 16);
                *(unsigned*)&smem[6336 + lofA[k]] = (unsigned)l0 | ((unsigned)l1 << 16);
            }
        }
#pragma unroll
        for (int k = 0; k < 5; ++k) {
            int t = tid + k * 256;
            if (t < 1152) {
                int tap = t >> 7, wi = t & 127;
                size_t src = ((size_t)((chunk * 9 + tap) * 2 + cog)) * 1024 + wi * 8;
                int dst = 12672 + tap * 1024 + wi * 8;
                *(uint4*)&smem[dst]        = *(const uint4*)(wph + src);
                *(uint4*)&smem[dst + 9216] = *(const uint4*)(wpl + src);
            }
        }
        __syncthreads();
#pragma unroll
        for (int tap = 0; tap < 9; ++tap) {
            int kh = tap / 3, kw = tap % 3;
            int aoff = 12672 + tap * 1024 + (mt * 16 + l15) * 32 + gx * 8;
            short8 ahi = *(const short8*)&smem[aoff];
            short8 alo = *(const short8*)&smem[aoff + 9216];
#pragma unroll
            for (int n2 = 0; n2 < 2; ++n2) {
                int nt = nh * 2 + n2;
                int boff = ((kh * 4 + quad) * 66 + nt * 16 + l15 + kw) * 8;
                short8 bhi = *(const short8*)&smem[boff];
                short8 blo = *(const short8*)&smem[boff + 6336];
                acc[n2] = __builtin_amdgcn_mfma_f32_16x16x32_bf16(alo, bhi, acc[n2], 0, 0, 0);
                acc[n2] = __builtin_amdgcn_mfma_f32_16x16x32_bf16(ahi, blo, acc[n2], 0, 0, 0);
                acc[n2] = __builtin_amdgcn_mfma_f32_16x16x32_bf16(ahi, bhi, acc[n2], 0, 0, 0);
            }
        }
    }
#pragma unroll
    for (int n2 = 0; n2 < 2; ++n2) {
        int nt = nh * 2 + n2;
#pragma unroll
        for (int u = 0; u < 4; ++u) {
            int co = cog * 32 + mt * 16 + quad * 4 + u;
            float v = acc[n2][u] + bias[co];
            d1[((size_t)b * 64 + co) * 4096 + r0 * 64 + nt * 16 + l15] = fmaxf(v, 0.f);
        }
    }
}

// ---------------- transposed conv v3: quad-parity, weights staged in LDS, COG=8 ----------------
// NOTE (R11): v2 was latency-bound (VALU 15%) — VGPR 52 proves compiler couldn't keep
// acc[2][2][16]+wr[16] live and re-fetched weights per (ci,co) from memory. v3 stages the
// block's full weight slice (CIN*COG*16 floats) in LDS once; K-loop reads are wave-uniform
// b128 broadcasts (conflict-free). COG=8 keeps acc at 32 floats.
template <int CIN, int COUT, int COG, int H>
__global__ void __launch_bounds__(256) tconv_v3(
        const float* __restrict__ x,   // (16,CIN,H,H)
        const float* __restrict__ w,   // (CIN,COUT,4,4)
        const float* __restrict__ bias,
        float* __restrict__ out) {     // (16,COUT,2H,2H)
    constexpr int NCOG = COUT / COG;
    constexpr int TPS = H / 16;
    constexpr int TILES = TPS * TPS;
    constexpr int HO = 2 * H;
    __shared__ float wsh[CIN * COG * 16];
    int bx = blockIdx.x;
    int b = bx / (NCOG * TILES), rem = bx % (NCOG * TILES);
    int cog = rem / TILES, tile = rem % TILES;
    int ti = tile / TPS, tj = tile % TPS;
    int tid = threadIdx.x;

    // stage weights once (float4 granularity, coalesced)
    for (int f = tid; f < CIN * COG * 4; f += 256) {
        int ci = f / (COG * 4), r = f % (COG * 4);
        int co = r >> 2, qq = r & 3;
        *(float4*)&wsh[(ci * COG + co) * 16 + qq * 4] =
            *(const float4*)(w + (((size_t)ci * COUT + cog * COG + co) << 4) + qq * 4);
    }
    __syncthreads();

    int i = ti * 16 + (tid >> 4);
    int j = tj * 16 + (tid & 15);

    float acc[2][2][COG];
#pragma unroll
    for (int pr = 0; pr < 2; ++pr)
#pragma unroll
        for (int pc = 0; pc < 2; ++pc)
#pragma unroll
            for (int co = 0; co < COG; ++co) acc[pr][pc][co] = 0.f;

    const float* xb = x + (size_t)b * CIN * H * H;
    for (int ci = 0; ci < CIN; ++ci) {
        const float* xp = xb + (size_t)ci * H * H;
        float xr[3][3];
#pragma unroll
        for (int dr = 0; dr < 3; ++dr) {
            int gr = i - 1 + dr;
            bool vr = (gr >= 0 && gr < H);
#pragma unroll
            for (int dc = 0; dc < 3; ++dc) {
                int gc = j - 1 + dc;
                xr[dr][dc] = (vr && gc >= 0 && gc < H) ? xp[gr * H + gc] : 0.f;
            }
        }
        const float* wp = &wsh[ci * COG * 16];
#pragma unroll
        for (int co = 0; co < COG; ++co) {
            float4 w0 = *(const float4*)(wp + co * 16);
            float4 w1 = *(const float4*)(wp + co * 16 + 4);
            float4 w2 = *(const float4*)(wp + co * 16 + 8);
            float4 w3 = *(const float4*)(wp + co * 16 + 12);
            float wr[16] = { w0.x, w0.y, w0.z, w0.w, w1.x, w1.y, w1.z, w1.w,
                             w2.x, w2.y, w2.z, w2.w, w3.x, w3.y, w3.z, w3.w };
#pragma unroll
            for (int pr = 0; pr < 2; ++pr)
#pragma unroll
                for (int a = 0; a < 2; ++a)
#pragma unroll
                    for (int pc = 0; pc < 2; ++pc)
#pragma unroll
                        for (int bb = 0; bb < 2; ++bb)
                            acc[pr][pc][co] += xr[pr + a][pc + bb] *
                                               wr[(3 - pr - 2 * a) * 4 + (3 - pc - 2 * bb)];
        }
    }
#pragma unroll
    for (int co = 0; co < COG; ++co) {
        float bv = bias[cog * COG + co];
        float* ob = out + ((size_t)b * COUT + cog * COG + co) * HO * HO;
#pragma unroll
        for (int pr = 0; pr < 2; ++pr)
#pragma unroll
            for (int pc = 0; pc < 2; ++pc)
                ob[(2 * i + pr) * HO + 2 * j + pc] = fmaxf(acc[pr][pc][co] + bv, 0.f);
    }
}

// ---------------- final conv (16->1) 3x3, 4 px per thread ----------------
__global__ void final_v2(const float* __restrict__ t2,  // (16,16,256,256)
                         const float* __restrict__ w,   // (1,16,3,3)
                         const float* __restrict__ bias,
                         float* __restrict__ out) {     // (16,1,256,256)
    int g = blockIdx.x * 256 + threadIdx.x;
    int pxb = g * 4;
    int b = pxb >> 16, p = pxb & 65535;
    int h = p >> 8, c0 = p & 255;
    const float* tb = t2 + (size_t)b * 16 * 65536;
    float acc[4];
    float bv = bias[0];
#pragma unroll
    for (int t = 0; t < 4; ++t) acc[t] = bv;
    for (int ci = 0; ci < 16; ++ci) {
        const float* pp = tb + (size_t)ci * 65536;
        const float* w9 = w + ci * 9;
        float win[3][6];
#pragma unroll
        for (int dr = 0; dr < 3; ++dr) {
            int rr = h - 1 + dr;
            bool vr = (rr >= 0 && rr < 256);
#pragma unroll
            for (int dc = 0; dc < 6; ++dc) {
                int cc = c0 - 1 + dc;
                win[dr][dc] = (vr && cc >= 0 && cc < 256) ? pp[rr * 256 + cc] : 0.f;
            }
        }
#pragma unroll
        for (int t = 0; t < 4; ++t)
#pragma unroll
            for (int dr = 0; dr < 3; ++dr)
#pragma unroll
                for (int dc = 0; dc < 3; ++dc)
                    acc[t] += win[dr][t + dc] * w9[dr * 3 + dc];
    }
    *(float4*)(out + pxb) = make_float4(acc[0], acc[1], acc[2], acc[3]);
}

// ---------------- launch ----------------
extern "C" void kernel_launch(void* const* d_in, const int* in_sizes, int n_in,
                              void* d_out, int out_size, void* d_ws, size_t ws_size,
                              hipStream_t stream) {
    (void)in_sizes; (void)n_in; (void)out_size; (void)ws_size;
    const float* x     = (const float*)d_in[0];
    const float* cw1   = (const float*)d_in[1];
    const float* cb1   = (const float*)d_in[2];
    const float* cw2   = (const float*)d_in[3];
    const float* cb2   = (const float*)d_in[4];
    const float* sw1   = (const float*)d_in[5];
    const float* sb1   = (const float*)d_in[6];
    const float* sw2   = (const float*)d_in[7];
    const float* sb2   = (const float*)d_in[8];
    const float* mkeys = (const float*)d_in[9];
    const float* mvals = (const float*)d_in[10];
    const float* mhard = (const float*)d_in[11];
    const float* dw1   = (const float*)d_in[12];
    const float* db1   = (const float*)d_in[13];
    const float* tw1   = (const float*)d_in[14];
    const float* tb1   = (const float*)d_in[15];
    const float* tw2   = (const float*)d_in[16];
    const float* tb2   = (const float*)d_in[17];
    const float* dw2   = (const float*)d_in[18];
    const float* db2   = (const float*)d_in[19];
    float* out = (float*)d_out;
    float* ws  = (float*)d_ws;

    const size_t OFF_KN  = 0;                   // knR: 800*128
    const size_t OFF_HN  = 102400;              // hn:  800*128
    const size_t OFF_C0  = 204800;              // c0:  128
    const size_t OFF_R14 = 204928;              // zc1 -> zs -> t1
    const size_t OFF_R2  = OFF_R14 + 8388608;   // (spare)
    const size_t OFF_R3  = OFF_R2 + 8388608;    // zs1 -> d1
    const size_t OFF_R5  = OFF_R3 + 4194304;    // dcat -> t2
    const size_t OFF_ZCQ = OFF_R5 + 16777216;   // zcq: 16*324*128
    const size_t OFF_HH  = OFF_ZCQ + 663552;    // hh
    const size_t OFF_HL  = OFF_HH + 51200;      // hl
    const size_t OFF_WH  = OFF_HL + 51200;      // wph
    const size_t OFF_WL  = OFF_WH + 73728;      // wpl

    float* knR  = ws + OFF_KN;
    float* hn   = ws + OFF_HN;
    float* c0   = ws + OFF_C0;
    float* zc1  = ws + OFF_R14;
    float* zs   = ws + OFF_R14;
    float* t1   = ws + OFF_R14;
    float* zs1  = ws + OFF_R3;
    float* d1b  = ws + OFF_R3;
    float* dcat = ws + OFF_R5;
    float* t2   = ws + OFF_R5;
    float* zcq  = ws + OFF_ZCQ;
    unsigned short* hhp = (unsigned short*)(ws + OFF_HH);
    unsigned short* hlp = (unsigned short*)(ws + OFF_HL);
    unsigned short* wph = (unsigned short*)(ws + OFF_WH);
    unsigned short* wpl = (unsigned short*)(ws + OFF_WL);

    prep_norm_k<<<800, 128, 0, stream>>>(mkeys, mhard, knR, hn, hhp, hlp);
    prep_c0_k<<<1, 128, 0, stream>>>(mvals, c0);
    prep_w1_k<<<576, 256, 0, stream>>>(dw1, wph, wpl);

    ce1_k<<<16 * 2 * 6, 256, 0, stream>>>(x, cw1, cb1, zc1);
    se1_k<<<16 * 64, 256, 0, stream>>>(x, sw1, sb1, zs1);
    ce2_v3<<<16 * 16, 256, 0, stream>>>(zc1, cw2, cb2, zcq);
    se2_v2<<<16 * 16 * 16, 256, 0, stream>>>(zs1, sw2, sb2, zs);  // overwrites zc1 (dead)

    match_center_v2<<<648, 256, 0, stream>>>(zcq, knR, mvals, dcat);
    fill_c0_k<<<32768, 256, 0, stream>>>(c0, dcat);
    match_skip_v5<<<16 * 64, 256, 0, stream>>>(zs, hn, hhp, hlp, mhard, dcat);

    dec1_v6<<<2048, 256, 0, stream>>>(dcat, wph, wpl, db1, d1b);

    tconv_v3<64, 32, 8, 64><<<16 * 4 * 16, 256, 0, stream>>>(d1b, tw1, tb1, t1);    // overwrites zs (dead)
    tconv_v3<32, 16, 8, 128><<<16 * 2 * 64, 256, 0, stream>>>(t1, tw2, tb2, t2);    // overwrites dcat (dead)
    final_v2<<<1024, 256, 0, stream>>>(t2, dw2, db2, out);
}

// Round 13
// 1006.478 us; speedup vs baseline: 1.7907x; 1.0049x over previous
//
#include <hip/hip_runtime.h>
#include <cstdint>
#include <cstddef>

#define NEG_INF (-3.0e38f)

typedef __attribute__((ext_vector_type(8))) short short8;
typedef __attribute__((ext_vector_type(4))) float f32x4;

__device__ inline unsigned short bf16_rne(float x) {
    unsigned u = __float_as_uint(x);
    unsigned r = u + 0x7fffu + ((u >> 16) & 1u);
    return (unsigned short)(r >> 16);
}
__device__ inline float bf16_tof(unsigned short h) {
    return __uint_as_float(((unsigned)h) << 16);
}

// ---------------- prep: normalize keys/hard + bf16 hi/lo split of hn ----------------
__global__ void prep_norm_k(const float* __restrict__ keys,
                            const float* __restrict__ hard,
                            float* __restrict__ knR,   // [800][128] normalized keys
                            float* __restrict__ hn,    // [800][128] normalized hard
                            unsigned short* __restrict__ hh,  // [800][128] bf16 hi
                            unsigned short* __restrict__ hl) {// [800][128] bf16 lo
    int m = blockIdx.x;      // 0..799
    int c = threadIdx.x;     // 0..127
    float kv = keys[m * 128 + c];
    float hv = hard[m * 128 + c];
    __shared__ float s1[128];
    __shared__ float s2[128];
    s1[c] = kv * kv;
    s2[c] = hv * hv;
    __syncthreads();
    for (int off = 64; off > 0; off >>= 1) {
        if (c < off) { s1[c] += s1[c + off]; s2[c] += s2[c + off]; }
        __syncthreads();
    }
    float ks = 1.0f / fmaxf(sqrtf(s1[0]), 1e-12f);
    float hs = 1.0f / fmaxf(sqrtf(s2[0]), 1e-12f);
    knR[m * 128 + c] = kv * ks;
    float hnv = hv * hs;
    hn[m * 128 + c] = hnv;
    unsigned short hi = bf16_rne(hnv);
    hh[m * 128 + c] = hi;
    hl[m * 128 + c] = bf16_rne(hnv - bf16_tof(hi));
}

__global__ void prep_c0_k(const float* __restrict__ values, float* __restrict__ c0) {
    int c = threadIdx.x;  // 128 threads
    float s = 0.f;
    for (int m = 0; m < 10; ++m) s += values[m * 128 + c];
    c0[c] = s * 0.1f;
}

// ---------------- prep: dec1 weights -> chunked bf16 hi/lo, MFMA A-layout w/ bank swizzle ----------------
__global__ void prep_w1_k(const float* __restrict__ dw1,   // (64,256,3,3)
                          unsigned short* __restrict__ wph,
                          unsigned short* __restrict__ wpl) {
    int idx = blockIdx.x * 256 + threadIdx.x;   // 147456 total
    int co = idx / 2304, r2 = idx % 2304;
    int ci = r2 / 9, tap = r2 % 9;
    float v = dw1[idx];
    int chunk = ci >> 5, cog = co >> 5, co32 = co & 31;
    int cil = ci & 31, g = cil >> 3, j = cil & 7;
    int gs = g ^ ((co32 >> 2) & 3);
    int off = ((((chunk * 9 + tap) * 2 + cog) * 32 + co32) * 4 + gs) * 8 + j;
    unsigned short hi = bf16_rne(v);
    wph[off] = hi;
    wpl[off] = bf16_rne(v - bf16_tof(hi));
}

// ---------------- center conv1+pool: only pooled rect [45,83)^2 ----------------
__global__ void ce1_k(const float* __restrict__ x,   // (16,1,256,256)
                      const float* __restrict__ w,   // (32,1,3,3)
                      const float* __restrict__ bias,
                      float* __restrict__ out) {     // (16,32,128,128) rect only
    int bx = blockIdx.x;            // 16 b * 2 cog * 6 tiles
    int b = bx / 12, rem = bx % 12;
    int cog = rem / 6, tile = rem % 6;
    int idx = tile * 256 + threadIdx.x;
    if (idx >= 1444) return;
    int ph = 45 + idx / 38, pw = 45 + idx % 38;
    const float* xb = x + (size_t)b * 65536;
    float win[4][4];
#pragma unroll
    for (int r = 0; r < 4; ++r) {
        int ih = 2 * ph - 1 + r;
        bool vr = (ih >= 96 && ih < 160);
#pragma unroll
        for (int c = 0; c < 4; ++c) {
            int iw = 2 * pw - 1 + c;
            win[r][c] = (vr && iw >= 96 && iw < 160) ? xb[ih * 256 + iw] : 0.f;
        }
    }
#pragma unroll
    for (int co8 = 0; co8 < 16; ++co8) {
        int co = cog * 16 + co8;
        const float* w9 = w + co * 9;
        float bv = bias[co];
        float a00 = bv, a01 = bv, a10 = bv, a11 = bv;
#pragma unroll
        for (int kh = 0; kh < 3; ++kh)
#pragma unroll
            for (int kw = 0; kw < 3; ++kw) {
                float wv = w9[kh * 3 + kw];
                a00 += win[kh][kw] * wv;
                a01 += win[kh][kw + 1] * wv;
                a10 += win[kh + 1][kw] * wv;
                a11 += win[kh + 1][kw + 1] * wv;
            }
        float mx = fmaxf(fmaxf(a00, a01), fmaxf(a10, a11));
        out[((size_t)b * 32 + co) * 16384 + ph * 128 + pw] = fmaxf(mx, 0.f);
    }
}

// ---------------- skip conv1+pool: full, 16 co per thread ----------------
__global__ void se1_k(const float* __restrict__ x,   // (16,1,256,256)
                      const float* __restrict__ w,   // (16,1,3,3)
                      const float* __restrict__ bias,
                      float* __restrict__ out) {     // (16,16,128,128)
    int bx = blockIdx.x;            // 16 b * 64 tiles
    int b = bx >> 6, tile = bx & 63;
    int idx = tile * 256 + threadIdx.x;   // 0..16383
    int ph = idx >> 7, pw = idx & 127;
    const float* xb = x + (size_t)b * 65536;
    float win[4][4];
#pragma unroll
    for (int r = 0; r < 4; ++r) {
        int ih = 2 * ph - 1 + r;
        bool vr = (ih >= 0 && ih < 256);
#pragma unroll
        for (int c = 0; c < 4; ++c) {
            int iw = 2 * pw - 1 + c;
            win[r][c] = (vr && iw >= 0 && iw < 256) ? xb[ih * 256 + iw] : 0.f;
        }
    }
#pragma unroll
    for (int co = 0; co < 16; ++co) {
        const float* w9 = w + co * 9;
        float bv = bias[co];
        float a00 = bv, a01 = bv, a10 = bv, a11 = bv;
#pragma unroll
        for (int kh = 0; kh < 3; ++kh)
#pragma unroll
            for (int kw = 0; kw < 3; ++kw) {
                float wv = w9[kh * 3 + kw];
                a00 += win[kh][kw] * wv;
                a01 += win[kh][kw + 1] * wv;
                a10 += win[kh + 1][kw] * wv;
                a11 += win[kh + 1][kw + 1] * wv;
            }
        float mx = fmaxf(fmaxf(a00, a01), fmaxf(a10, a11));
        out[((size_t)b * 16 + co) * 16384 + idx] = fmaxf(mx, 0.f);
    }
}

// ---------------- center conv2 v3 (32->128) + relu + pool -> query-major zcq ----------------
__global__ void __launch_bounds__(256) ce2_v3(
        const float* __restrict__ zc1,  // (16,32,128,128)
        const float* __restrict__ w,    // (128,32,3,3)
        const float* __restrict__ bias,
        float* __restrict__ zcq) {      // (16*324, 128) query-major
    int bx = blockIdx.x;                // 16 b * 16 cog
    int b = bx >> 4, cog = bx & 15;
    const float* ib = zc1 + (size_t)b * 32 * 16384;
    for (int px = threadIdx.x; px < 324; px += 256) {
        int h = 23 + px / 18, ww = 23 + px % 18;
        float acc[8][4];
#pragma unroll
        for (int c8 = 0; c8 < 8; ++c8)
#pragma unroll
            for (int t = 0; t < 4; ++t) acc[c8][t] = 0.f;
        for (int ci = 0; ci < 32; ++ci) {
            const float* p = ib + ci * 16384 + (2 * h - 1) * 128 + (2 * ww - 1);
            float win[4][4];
#pragma unroll
            for (int r = 0; r < 4; ++r)
#pragma unroll
                for (int s = 0; s < 4; ++s) win[r][s] = p[r * 128 + s];
#pragma unroll
            for (int c8 = 0; c8 < 8; ++c8) {
                const float* w9 = w + ((size_t)(cog * 8 + c8) * 32 + ci) * 9;
#pragma unroll
                for (int kh = 0; kh < 3; ++kh)
#pragma unroll
                    for (int kw = 0; kw < 3; ++kw) {
                        float wv = w9[kh * 3 + kw];
                        acc[c8][0] += win[kh][kw] * wv;
                        acc[c8][1] += win[kh][kw + 1] * wv;
                        acc[c8][2] += win[kh + 1][kw] * wv;
                        acc[c8][3] += win[kh + 1][kw + 1] * wv;
                    }
            }
        }
#pragma unroll
        for (int c8 = 0; c8 < 8; ++c8) {
            int co = cog * 8 + c8;
            float mx = fmaxf(fmaxf(acc[c8][0], acc[c8][1]), fmaxf(acc[c8][2], acc[c8][3])) + bias[co];
            zcq[((size_t)(b * 324 + px)) * 128 + co] = fmaxf(mx, 0.f);
        }
    }
}

// ---------------- skip conv2 (16->128) + relu + pool, 8 co per thread ----------------
__global__ void se2_v2(const float* __restrict__ zs1,  // (16,16,128,128)
                       const float* __restrict__ w,    // (128,16,3,3)
                       const float* __restrict__ bias,
                       float* __restrict__ zs) {       // (16,128,64,64)
    int bx = blockIdx.x;            // 16 b * 16 cog * 16 tiles = 4096
    int b = bx >> 8, rem = bx & 255;
    int cog = rem >> 4, tile = rem & 15;
    int px = tile * 256 + threadIdx.x;  // 0..4095
    int ph = px >> 6, pw = px & 63;
    const float* ib = zs1 + (size_t)b * 16 * 16384;
    float acc[8][4];
#pragma unroll
    for (int c8 = 0; c8 < 8; ++c8)
#pragma unroll
        for (int t = 0; t < 4; ++t) acc[c8][t] = 0.f;
    for (int ci = 0; ci < 16; ++ci) {
        const float* p = ib + ci * 16384;
        float win[4][4];
#pragma unroll
        for (int r = 0; r < 4; ++r) {
            int rr = 2 * ph - 1 + r;
            bool vr = (rr >= 0 && rr < 128);
#pragma unroll
            for (int s = 0; s < 4; ++s) {
                int cc = 2 * pw - 1 + s;
                win[r][s] = (vr && cc >= 0 && cc < 128) ? p[rr * 128 + cc] : 0.f;
            }
        }
#pragma unroll
        for (int c8 = 0; c8 < 8; ++c8) {
            const float* w9 = w + ((size_t)(cog * 8 + c8) * 16 + ci) * 9;
#pragma unroll
            for (int kh = 0; kh < 3; ++kh)
#pragma unroll
                for (int kw = 0; kw < 3; ++kw) {
                    float wv = w9[kh * 3 + kw];
                    acc[c8][0] += win[kh][kw] * wv;
                    acc[c8][1] += win[kh][kw + 1] * wv;
                    acc[c8][2] += win[kh + 1][kw] * wv;
                    acc[c8][3] += win[kh + 1][kw + 1] * wv;
                }
        }
    }
#pragma unroll
    for (int c8 = 0; c8 < 8; ++c8) {
        int co = cog * 8 + c8;
        float bv = bias[co];
        float mx = fmaxf(fmaxf(acc[c8][0], acc[c8][1]), fmaxf(acc[c8][2], acc[c8][3])) + bv;
        zs[((size_t)b * 128 + co) * 4096 + px] = fmaxf(mx, 0.f);
    }
}

// ---------------- center matching v2 (unchanged) ----------------
__global__ void __launch_bounds__(256) match_center_v2(
        const float* __restrict__ zcq,    // (16*324, 128) raw queries
        const float* __restrict__ knR,    // (800,128) normalized keys
        const float* __restrict__ values, // (800,128)
        float* __restrict__ dcat) {       // (16,256,64,64), ch 0..127
    __shared__ float shk[128 * 65];
    __shared__ float qint[4 * 256];
    int tid = threadIdx.x;
    int w = tid >> 6, lane = tid & 63;
    int g0 = blockIdx.x * 8 + 2 * w;

#pragma unroll
    for (int i = 0; i < 2; ++i) {
        const float* qp = zcq + (size_t)(g0 + i) * 128;
        float v0 = qp[lane], v1 = qp[lane + 64];
        float ss = v0 * v0 + v1 * v1;
#pragma unroll
        for (int off = 32; off > 0; off >>= 1) ss += __shfl_xor(ss, off);
        float sc = 1.0f / fmaxf(sqrtf(ss), 1e-12f);
        qint[w * 256 + lane * 2 + i] = v0 * sc;
        qint[w * 256 + (lane + 64) * 2 + i] = v1 * sc;
    }

    float sim2[2][13];
#pragma unroll
    for (int k = 0; k < 13; ++k) { sim2[0][k] = 0.f; sim2[1][k] = 0.f; }

    for (int chunk = 0; chunk < 13; ++chunk) {
        int mbase = chunk << 6;
        __syncthreads();
#pragma unroll
        for (int t = 0; t < 8; ++t) {
            int idx = tid + t * 256;
            int kk = idx >> 5, c4 = idx & 31;
            int m = mbase + kk;
            float4 kv = (m < 800) ? *(const float4*)(knR + (size_t)m * 128 + c4 * 4)
                                  : make_float4(0.f, 0.f, 0.f, 0.f);
            shk[(4 * c4 + 0) * 65 + kk] = kv.x;
            shk[(4 * c4 + 1) * 65 + kk] = kv.y;
            shk[(4 * c4 + 2) * 65 + kk] = kv.z;
            shk[(4 * c4 + 3) * 65 + kk] = kv.w;
        }
        __syncthreads();
        float s0 = sim2[0][chunk], s1 = sim2[1][chunk];
        const float* qw = qint + w * 256;
#pragma unroll 4
        for (int c2 = 0; c2 < 64; ++c2) {
            float4 qq = *(const float4*)(qw + c2 * 4);
            float k0 = shk[(2 * c2) * 65 + lane];
            float k1 = shk[(2 * c2 + 1) * 65 + lane];
            s0 += qq.x * k0; s1 += qq.y * k0;
            s0 += qq.z * k1; s1 += qq.w * k1;
        }
        sim2[0][chunk] = s0; sim2[1][chunk] = s1;
    }

#pragma unroll
    for (int i = 0; i < 2; ++i) {
        int g = g0 + i;
        int b = g / 324, q = g - b * 324;
        int h = 23 + q / 18, ww = 23 + q % 18;
        int p = h * 64 + ww;

        float sim[13];
#pragma unroll
        for (int k = 0; k < 13; ++k)
            sim[k] = (lane + (k << 6) < 800) ? sim2[i][k] : NEG_INF;

        float topv[11]; int topm[11];
#pragma unroll
        for (int t = 0; t < 11; ++t) {
            float bvv = NEG_INF; int bm = 0x7fffffff;
#pragma unroll
            for (int k = 0; k < 13; ++k) {
                if (sim[k] > bvv) { bvv = sim[k]; bm = lane + (k << 6); }
            }
#pragma unroll
            for (int off = 32; off > 0; off >>= 1) {
                float ov = __shfl_xor(bvv, off);
                int om = __shfl_xor(bm, off);
                if (ov > bvv || (ov == bvv && om < bm)) { bvv = ov; bm = om; }
            }
            topv[t] = bvv; topm[t] = bm;
            if ((bm & 63) == lane) {
                int kk = bm >> 6;
#pragma unroll
                for (int k = 0; k < 13; ++k)
                    if (k == kk) sim[k] = NEG_INF;
            }
        }
        if (topv[9] - topv[10] < 1e-4f) {
            double s9 = 0.0, s10 = 0.0;
            const float* k9 = knR + (size_t)topm[9] * 128;
            const float* k10 = knR + (size_t)topm[10] * 128;
            for (int c = 0; c < 128; ++c) {
                double qc = (double)qint[w * 256 + c * 2 + i];
                s9 += qc * (double)k9[c];
                s10 += qc * (double)k10[c];
            }
            if ((s10 > s9) || (s10 == s9 && topm[10] < topm[9])) {
                topv[9] = topv[10]; topm[9] = topm[10];
            }
        }
        float mx = topv[0];
        float e[10], ssum = 0.f;
#pragma unroll
        for (int t = 0; t < 10; ++t) { e[t] = expf(topv[t] - mx); ssum += e[t]; }
        float inv = 1.0f / ssum;
        float o0 = 0.f, o1 = 0.f;
#pragma unroll
        for (int t = 0; t < 10; ++t) {
            float wt = e[t] * inv;
            const float* vr = values + (size_t)topm[t] * 128;
            o0 += wt * vr[lane];
            o1 += wt * vr[lane + 64];
        }
        float* ob = dcat + ((size_t)b * 256) * 4096 + p;
        ob[(size_t)lane * 4096] = o0;
        ob[(size_t)(lane + 64) * 4096] = o1;
    }
}

// ---------------- constant fill for out-of-region center matches ----------------
__global__ void fill_c0_k(const float* __restrict__ c0, float* __restrict__ dcat) {
    int idx = blockIdx.x * 256 + threadIdx.x;
    int p = idx & 4095;
    int c = (idx >> 12) & 127;
    int b = idx >> 19;
    int h = p >> 6, ww = p & 63;
    if (h >= 23 && h <= 40 && ww >= 23 && ww <= 40) return;
    dcat[((size_t)b * 256 + c) * 4096 + p] = c0[c];
}

// ---------------- skip matching v5: split-bf16 MFMA, windowed exact rescore ----------------
__global__ void __launch_bounds__(256, 2) match_skip_v5(
        const float* __restrict__ zs,    // (16,128,64,64) raw queries
        const float* __restrict__ hn,    // (800,128) normalized fp32 (rescore)
        const unsigned short* __restrict__ hh,  // (800,128) bf16 hi
        const unsigned short* __restrict__ hl,  // (800,128) bf16 lo
        const float* __restrict__ hard,  // (800,128) raw
        float* __restrict__ dcat) {      // ch 128..255
    __shared__ unsigned short sm[32768]; // 64KB
    int b = blockIdx.x >> 6, pt = blockIdx.x & 63;
    int pbase = pt * 64;
    int tid = threadIdx.x;
    int w = tid >> 6, lane = tid & 63;
    int l15 = lane & 15, quad = lane >> 4;

    {
        int p = tid & 63, c0 = tid >> 6;
        for (int k = 0; k < 32; ++k) {
            int c = c0 + k * 4;
            float v = zs[((size_t)b * 128 + c) * 4096 + pbase + p];
            unsigned short hi = bf16_rne(v);
            unsigned short lo = bf16_rne(v - bf16_tof(hi));
            int off = p * 128 + (((c >> 3) ^ (p & 15)) << 3) + (c & 7);
            sm[off] = hi;
            sm[8192 + off] = lo;
        }
    }

    float v1[4], v2[4]; int i1[4], i2[4];
#pragma unroll
    for (int u = 0; u < 4; ++u) { v1[u] = NEG_INF; v2[u] = NEG_INF; i1[u] = 0x7fffffff; i2[u] = 0x7fffffff; }

    for (int chunk = 0; chunk < 13; ++chunk) {
        int mbase = chunk << 6;
        __syncthreads();
#pragma unroll
        for (int t = 0; t < 4; ++t) {
            int idx = tid + t * 256;          // 0..1023
            int row = idx >> 4, cb = idx & 15;
            int gm = mbase + row;
            uint4 dh = make_uint4(0u, 0u, 0u, 0u), dl = make_uint4(0u, 0u, 0u, 0u);
            if (gm < 800) {
                dh = *(const uint4*)(hh + (size_t)gm * 128 + cb * 8);
                dl = *(const uint4*)(hl + (size_t)gm * 128 + cb * 8);
            }
            int off = row * 128 + ((cb ^ (row & 15)) << 3);
            *(uint4*)&sm[16384 + off] = dh;
            *(uint4*)&sm[24576 + off] = dl;
        }
        __syncthreads();

        f32x4 acc[4];
#pragma unroll
        for (int kt = 0; kt < 4; ++kt) acc[kt] = (f32x4){0.f, 0.f, 0.f, 0.f};

#pragma unroll
        for (int ks = 0; ks < 4; ++ks) {
            int qrow = 16 * w + l15;
            int cb = ks * 4 + quad;
            int qoff = qrow * 128 + ((cb ^ (qrow & 15)) << 3);
            short8 ahi = *(const short8*)&sm[qoff];
            short8 alo = *(const short8*)&sm[8192 + qoff];
#pragma unroll
            for (int kt = 0; kt < 4; ++kt) {
                int krow = l15 + 16 * kt;
                int koff = krow * 128 + ((cb ^ (krow & 15)) << 3);
                short8 bhi = *(const short8*)&sm[16384 + koff];
                short8 blo = *(const short8*)&sm[24576 + koff];
                acc[kt] = __builtin_amdgcn_mfma_f32_16x16x32_bf16(alo, bhi, acc[kt], 0, 0, 0);
                acc[kt] = __builtin_amdgcn_mfma_f32_16x16x32_bf16(ahi, blo, acc[kt], 0, 0, 0);
                acc[kt] = __builtin_amdgcn_mfma_f32_16x16x32_bf16(ahi, bhi, acc[kt], 0, 0, 0);
            }
        }
#pragma unroll
        for (int kt = 0; kt < 4; ++kt) {
            int m = mbase + 16 * kt + l15;
            if (m < 800) {
#pragma unroll
                for (int u = 0; u < 4; ++u) {
                    float sv = acc[kt][u];
                    if (sv > v1[u] || (sv == v1[u] && m < i1[u])) {
                        v2[u] = v1[u]; i2[u] = i1[u]; v1[u] = sv; i1[u] = m;
                    } else if (sv > v2[u] || (sv == v2[u] && m < i2[u])) {
                        v2[u] = sv; i2[u] = m;
                    }
                }
            }
        }
    }
    __syncthreads();
    float4* red = (float4*)&sm[16384];   // [64 q][17 slots] float4 = 8704 shorts
#pragma unroll
    for (int u = 0; u < 4; ++u) {
        int q = 16 * w + quad * 4 + u;
        red[q * 17 + l15] = make_float4(v1[u], v2[u], __int_as_float(i1[u]), __int_as_float(i2[u]));
    }
    __syncthreads();
    int* bi_sh = (int*)&sm[16384 + 8704];  // [64] ints, in-bounds
    if (tid < 64) {
        int q = tid;
        float V1 = NEG_INF; int I1 = 0x7fffffff;
        for (int k = 0; k < 16; ++k) {
            float4 e = red[q * 17 + k];
            float cv[2] = { e.x, e.y };
            int ci_[2] = { __float_as_int(e.z), __float_as_int(e.w) };
#pragma unroll
            for (int t = 0; t < 2; ++t) {
                if (cv[t] > V1 || (cv[t] == V1 && ci_[t] < I1)) { V1 = cv[t]; I1 = ci_[t]; }
            }
        }
        float qn2 = 0.f;
        for (int c = 0; c < 128; ++c) {
            int off = q * 128 + (((c >> 3) ^ (q & 15)) << 3) + (c & 7);
            float qc = bf16_tof(sm[off]) + bf16_tof(sm[8192 + off]);
            qn2 += qc * qc;
        }
        float tau = 1.5e-4f * sqrtf(qn2) + 1e-12f;
        float thr = V1 - tau;
        int ncand = 0;
        for (int k = 0; k < 16; ++k) {
            float4 e = red[q * 17 + k];
            if (e.x >= thr && __float_as_int(e.z) != 0x7fffffff) ++ncand;
            if (e.y >= thr && __float_as_int(e.w) != 0x7fffffff) ++ncand;
        }
        int bi = I1;
        if (ncand > 1) {
            double bestd = -1.0e300; int besti = 0x7fffffff;
            for (int k = 0; k < 16; ++k) {
                float4 e = red[q * 17 + k];
                float cv[2] = { e.x, e.y };
                int ci_[2] = { __float_as_int(e.z), __float_as_int(e.w) };
                for (int t = 0; t < 2; ++t) {
                    if (cv[t] >= thr && ci_[t] != 0x7fffffff) {
                        const float* hr = hn + (size_t)ci_[t] * 128;
                        double d = 0.0;
                        for (int c = 0; c < 128; ++c) {
                            double qc = (double)zs[((size_t)b * 128 + c) * 4096 + pbase + q];
                            d += qc * (double)hr[c];
                        }
                        if (d > bestd || (d == bestd && ci_[t] < besti)) { bestd = d; besti = ci_[t]; }
                    }
                }
            }
            bi = besti;
        }
        bi_sh[q] = bi;
    }
    __syncthreads();
    {
        int q = tid & 63, seg = tid >> 6;
        int bi = bi_sh[q];
        const float* hr = hard + (size_t)bi * 128;
        float* ob = dcat + ((size_t)b * 256 + 128) * 4096 + pbase + q;
#pragma unroll
        for (int i = 0; i < 32; ++i) {
            int c = seg * 32 + i;
            ob[(size_t)c * 4096] = hr[c];
        }
    }
}

// ---------------- decoder conv1 v7: MFMA implicit GEMM + register-prefetch pipeline ----------------
// Same math/layout as v6; staging loads for chunk k+1 issue before compute of chunk k.
__global__ void __launch_bounds__(256, 2) dec1_v7(
        const float* __restrict__ dcat, // (16,256,64,64)
        const unsigned short* __restrict__ wph,  // prepped weights hi
        const unsigned short* __restrict__ wpl,  // prepped weights lo
        const float* __restrict__ bias,
        float* __restrict__ d1) {       // (16,64,64,64)
    __shared__ unsigned short smem[31104];
    int bx = blockIdx.x;                // 16 b * 64 r0 * 2 cog = 2048
    int b = bx >> 7, rem = bx & 127;
    int r0 = rem >> 1, cog = rem & 1;
    int tid = threadIdx.x;
    int w = tid >> 6, lane = tid & 63;
    int l15 = lane & 15, quad = lane >> 4;
    int mt = w & 1, nh = w >> 1;
    int gx = quad ^ ((l15 >> 2) & 3);

    int lofA[13], gofA[13];
#pragma unroll
    for (int k = 0; k < 13; ++k) {
        int f = tid + k * 256;
        lofA[k] = 0; gofA[k] = -1;
        if (f < 3168) {
            int p = f / 198, rm = f % 198;
            int row = rm / 66, col = rm % 66;
            lofA[k] = ((row * 4 + (p >> 2)) * 66 + col) * 8 + (p & 3) * 2;
            int gr = r0 - 1 + row, gc = col - 1;
            if (gr >= 0 && gr < 64 && gc >= 0 && gc < 64)
                gofA[k] = (2 * p) * 4096 + gr * 64 + gc;
        }
    }
#pragma unroll
    for (int k = 0; k < 13; ++k) {
        int f = tid + k * 256;
        if (f < 3168 && gofA[k] < 0) {
            *(unsigned*)&smem[lofA[k]] = 0u;
            *(unsigned*)&smem[6336 + lofA[k]] = 0u;
        }
    }
    // weight staging descriptor
    int wt_t = -1, wt_tap = 0, wt_wi = 0;
    {
        // thread covers up to 5 slots; precompute slot ids
    }

    float pfx0[13], pfx1[13];
    uint4 pfwh[5], pfwl[5];

    // ---- load chunk 0 into registers ----
    {
        const float* xb = dcat + ((size_t)b * 256) * 4096;
#pragma unroll
        for (int k = 0; k < 13; ++k)
            if (gofA[k] >= 0) { pfx0[k] = xb[gofA[k]]; pfx1[k] = xb[gofA[k] + 4096]; }
#pragma unroll
        for (int k = 0; k < 5; ++k) {
            int t = tid + k * 256;
            if (t < 1152) {
                int tap = t >> 7, wi = t & 127;
                size_t src = ((size_t)((0 * 9 + tap) * 2 + cog)) * 1024 + wi * 8;
                pfwh[k] = *(const uint4*)(wph + src);
                pfwl[k] = *(const uint4*)(wpl + src);
            }
        }
    }
    // ---- store chunk 0 to LDS ----
#pragma unroll
    for (int k = 0; k < 13; ++k) {
        if (gofA[k] >= 0) {
            unsigned short h0 = bf16_rne(pfx0[k]), h1 = bf16_rne(pfx1[k]);
            unsigned short l0 = bf16_rne(pfx0[k] - bf16_tof(h0));
            unsigned short l1 = bf16_rne(pfx1[k] - bf16_tof(h1));
            *(unsigned*)&smem[lofA[k]] = (unsigned)h0 | ((unsigned)h1 << 16);
            *(unsigned*)&smem[6336 + lofA[k]] = (unsigned)l0 | ((unsigned)l1 << 16);
        }
    }
#pragma unroll
    for (int k = 0; k < 5; ++k) {
        int t = tid + k * 256;
        if (t < 1152) {
            int tap = t >> 7, wi = t & 127;
            int dst = 12672 + tap * 1024 + wi * 8;
            *(uint4*)&smem[dst]        = pfwh[k];
            *(uint4*)&smem[dst + 9216] = pfwl[k];
        }
    }
    __syncthreads();

    f32x4 acc[2];
    acc[0] = (f32x4){0.f, 0.f, 0.f, 0.f};
    acc[1] = (f32x4){0.f, 0.f, 0.f, 0.f};

    for (int chunk = 0; chunk < 8; ++chunk) {
        // issue prefetch loads for chunk+1 (overlap with compute below)
        if (chunk < 7) {
            const float* xb = dcat + ((size_t)b * 256 + (chunk + 1) * 32) * 4096;
#pragma unroll
            for (int k = 0; k < 13; ++k)
                if (gofA[k] >= 0) { pfx0[k] = xb[gofA[k]]; pfx1[k] = xb[gofA[k] + 4096]; }
#pragma unroll
            for (int k = 0; k < 5; ++k) {
                int t = tid + k * 256;
                if (t < 1152) {
                    int tap = t >> 7, wi = t & 127;
                    size_t src = ((size_t)(((chunk + 1) * 9 + tap) * 2 + cog)) * 1024 + wi * 8;
                    pfwh[k] = *(const uint4*)(wph + src);
                    pfwl[k] = *(const uint4*)(wpl + src);
                }
            }
        }
        // compute current chunk from LDS
#pragma unroll
        for (int tap = 0; tap < 9; ++tap) {
            int kh = tap / 3, kw = tap % 3;
            int aoff = 12672 + tap * 1024 + (mt * 16 + l15) * 32 + gx * 8;
            short8 ahi = *(const short8*)&smem[aoff];
            short8 alo = *(const short8*)&smem[aoff + 9216];
#pragma unroll
            for (int n2 = 0; n2 < 2; ++n2) {
                int nt = nh * 2 + n2;
                int boff = ((kh * 4 + quad) * 66 + nt * 16 + l15 + kw) * 8;
                short8 bhi = *(const short8*)&smem[boff];
                short8 blo = *(const short8*)&smem[boff + 6336];
                acc[n2] = __builtin_amdgcn_mfma_f32_16x16x32_bf16(alo, bhi, acc[n2], 0, 0, 0);
                acc[n2] = __builtin_amdgcn_mfma_f32_16x16x32_bf16(ahi, blo, acc[n2], 0, 0, 0);
                acc[n2] = __builtin_amdgcn_mfma_f32_16x16x32_bf16(ahi, bhi, acc[n2], 0, 0, 0);
            }
        }
        if (chunk < 7) {
            __syncthreads();   // all waves finished reading current LDS contents
            // store prefetched chunk+1
#pragma unroll
            for (int k = 0; k < 13; ++k) {
                if (gofA[k] >= 0) {
                    unsigned short h0 = bf16_rne(pfx0[k]), h1 = bf16_rne(pfx1[k]);
                    unsigned short l0 = bf16_rne(pfx0[k] - bf16_tof(h0));
                    unsigned short l1 = bf16_rne(pfx1[k] - bf16_tof(h1));
                    *(unsigned*)&smem[lofA[k]] = (unsigned)h0 | ((unsigned)h1 << 16);
                    *(unsigned*)&smem[6336 + lofA[k]] = (unsigned)l0 | ((unsigned)l1 << 16);
                }
            }
#pragma unroll
            for (int k = 0; k < 5; ++k) {
                int t = tid + k * 256;
                if (t < 1152) {
                    int tap = t >> 7, wi = t & 127;
                    int dst = 12672 + tap * 1024 + wi * 8;
                    *(uint4*)&smem[dst]        = pfwh[k];
                    *(uint4*)&smem[dst + 9216] = pfwl[k];
                }
            }
            __syncthreads();   // stores visible before next compute
        }
    }
#pragma unroll
    for (int n2 = 0; n2 < 2; ++n2) {
        int nt = nh * 2 + n2;
#pragma unroll
        for (int u = 0; u < 4; ++u) {
            int co = cog * 32 + mt * 16 + quad * 4 + u;
            float v = acc[n2][u] + bias[co];
            d1[((size_t)b * 64 + co) * 4096 + r0 * 64 + nt * 16 + l15] = fmaxf(v, 0.f);
        }
    }
}

// ---------------- transposed conv v3: quad-parity, weights staged in LDS, COG=8 ----------------
template <int CIN, int COUT, int COG, int H>
__global__ void __launch_bounds__(256) tconv_v3(
        const float* __restrict__ x,   // (16,CIN,H,H)
        const float* __restrict__ w,   // (CIN,COUT,4,4)
        const float* __restrict__ bias,
        float* __restrict__ out) {     // (16,COUT,2H,2H)
    constexpr int NCOG = COUT / COG;
    constexpr int TPS = H / 16;
    constexpr int TILES = TPS * TPS;
    constexpr int HO = 2 * H;
    __shared__ float wsh[CIN * COG * 16];
    int bx = blockIdx.x;
    int b = bx / (NCOG * TILES), rem = bx % (NCOG * TILES);
    int cog = rem / TILES, tile = rem % TILES;
    int ti = tile / TPS, tj = tile % TPS;
    int tid = threadIdx.x;

    for (int f = tid; f < CIN * COG * 4; f += 256) {
        int ci = f / (COG * 4), r = f % (COG * 4);
        int co = r >> 2, qq = r & 3;
        *(float4*)&wsh[(ci * COG + co) * 16 + qq * 4] =
            *(const float4*)(w + (((size_t)ci * COUT + cog * COG + co) << 4) + qq * 4);
    }
    __syncthreads();

    int i = ti * 16 + (tid >> 4);
    int j = tj * 16 + (tid & 15);

    float acc[2][2][COG];
#pragma unroll
    for (int pr = 0; pr < 2; ++pr)
#pragma unroll
        for (int pc = 0; pc < 2; ++pc)
#pragma unroll
            for (int co = 0; co < COG; ++co) acc[pr][pc][co] = 0.f;

    const float* xb = x + (size_t)b * CIN * H * H;
    for (int ci = 0; ci < CIN; ++ci) {
        const float* xp = xb + (size_t)ci * H * H;
        float xr[3][3];
#pragma unroll
        for (int dr = 0; dr < 3; ++dr) {
            int gr = i - 1 + dr;
            bool vr = (gr >= 0 && gr < H);
#pragma unroll
            for (int dc = 0; dc < 3; ++dc) {
                int gc = j - 1 + dc;
                xr[dr][dc] = (vr && gc >= 0 && gc < H) ? xp[gr * H + gc] : 0.f;
            }
        }
        const float* wp = &wsh[ci * COG * 16];
#pragma unroll
        for (int co = 0; co < COG; ++co) {
            float4 w0 = *(const float4*)(wp + co * 16);
            float4 w1 = *(const float4*)(wp + co * 16 + 4);
            float4 w2 = *(const float4*)(wp + co * 16 + 8);
            float4 w3 = *(const float4*)(wp + co * 16 + 12);
            float wr[16] = { w0.x, w0.y, w0.z, w0.w, w1.x, w1.y, w1.z, w1.w,
                             w2.x, w2.y, w2.z, w2.w, w3.x, w3.y, w3.z, w3.w };
#pragma unroll
            for (int pr = 0; pr < 2; ++pr)
#pragma unroll
                for (int a = 0; a < 2; ++a)
#pragma unroll
                    for (int pc = 0; pc < 2; ++pc)
#pragma unroll
                        for (int bb = 0; bb < 2; ++bb)
                            acc[pr][pc][co] += xr[pr + a][pc + bb] *
                                               wr[(3 - pr - 2 * a) * 4 + (3 - pc - 2 * bb)];
        }
    }
#pragma unroll
    for (int co = 0; co < COG; ++co) {
        float bv = bias[cog * COG + co];
        float* ob = out + ((size_t)b * COUT + cog * COG + co) * HO * HO;
#pragma unroll
        for (int pr = 0; pr < 2; ++pr)
#pragma unroll
            for (int pc = 0; pc < 2; ++pc)
                ob[(2 * i + pr) * HO + 2 * j + pc] = fmaxf(acc[pr][pc][co] + bv, 0.f);
    }
}

// ---------------- final conv (16->1) 3x3, 4 px per thread ----------------
__global__ void final_v2(const float* __restrict__ t2,  // (16,16,256,256)
                         const float* __restrict__ w,   // (1,16,3,3)
                         const float* __restrict__ bias,
                         float* __restrict__ out) {     // (16,1,256,256)
    int g = blockIdx.x * 256 + threadIdx.x;
    int pxb = g * 4;
    int b = pxb >> 16, p = pxb & 65535;
    int h = p >> 8, c0 = p & 255;
    const float* tb = t2 + (size_t)b * 16 * 65536;
    float acc[4];
    float bv = bias[0];
#pragma unroll
    for (int t = 0; t < 4; ++t) acc[t] = bv;
    for (int ci = 0; ci < 16; ++ci) {
        const float* pp = tb + (size_t)ci * 65536;
        const float* w9 = w + ci * 9;
        float win[3][6];
#pragma unroll
        for (int dr = 0; dr < 3; ++dr) {
            int rr = h - 1 + dr;
            bool vr = (rr >= 0 && rr < 256);
#pragma unroll
            for (int dc = 0; dc < 6; ++dc) {
                int cc = c0 - 1 + dc;
                win[dr][dc] = (vr && cc >= 0 && cc < 256) ? pp[rr * 256 + cc] : 0.f;
            }
        }
#pragma unroll
        for (int t = 0; t < 4; ++t)
#pragma unroll
            for (int dr = 0; dr < 3; ++dr)
#pragma unroll
                for (int dc = 0; dc < 3; ++dc)
                    acc[t] += win[dr][t + dc] * w9[dr * 3 + dc];
    }
    *(float4*)(out + pxb) = make_float4(acc[0], acc[1], acc[2], acc[3]);
}

// ---------------- launch ----------------
extern "C" void kernel_launch(void* const* d_in, const int* in_sizes, int n_in,
                              void* d_out, int out_size, void* d_ws, size_t ws_size,
                              hipStream_t stream) {
    (void)in_sizes; (void)n_in; (void)out_size; (void)ws_size;
    const float* x     = (const float*)d_in[0];
    const float* cw1   = (const float*)d_in[1];
    const float* cb1   = (const float*)d_in[2];
    const float* cw2   = (const float*)d_in[3];
    const float* cb2   = (const float*)d_in[4];
    const float* sw1   = (const float*)d_in[5];
    const float* sb1   = (const float*)d_in[6];
    const float* sw2   = (const float*)d_in[7];
    const float* sb2   = (const float*)d_in[8];
    const float* mkeys = (const float*)d_in[9];
    const float* mvals = (const float*)d_in[10];
    const float* mhard = (const float*)d_in[11];
    const float* dw1   = (const float*)d_in[12];
    const float* db1   = (const float*)d_in[13];
    const float* tw1   = (const float*)d_in[14];
    const float* tb1   = (const float*)d_in[15];
    const float* tw2   = (const float*)d_in[16];
    const float* tb2   = (const float*)d_in[17];
    const float* dw2   = (const float*)d_in[18];
    const float* db2   = (const float*)d_in[19];
    float* out = (float*)d_out;
    float* ws  = (float*)d_ws;

    const size_t OFF_KN  = 0;                   // knR: 800*128
    const size_t OFF_HN  = 102400;              // hn:  800*128
    const size_t OFF_C0  = 204800;              // c0:  128
    const size_t OFF_R14 = 204928;              // zc1 -> zs -> t1
    const size_t OFF_R2  = OFF_R14 + 8388608;   // (spare)
    const size_t OFF_R3  = OFF_R2 + 8388608;    // zs1 -> d1
    const size_t OFF_R5  = OFF_R3 + 4194304;    // dcat -> t2
    const size_t OFF_ZCQ = OFF_R5 + 16777216;   // zcq: 16*324*128
    const size_t OFF_HH  = OFF_ZCQ + 663552;    // hh
    const size_t OFF_HL  = OFF_HH + 51200;      // hl
    const size_t OFF_WH  = OFF_HL + 51200;      // wph
    const size_t OFF_WL  = OFF_WH + 73728;      // wpl

    float* knR  = ws + OFF_KN;
    float* hn   = ws + OFF_HN;
    float* c0   = ws + OFF_C0;
    float* zc1  = ws + OFF_R14;
    float* zs   = ws + OFF_R14;
    float* t1   = ws + OFF_R14;
    float* zs1  = ws + OFF_R3;
    float* d1b  = ws + OFF_R3;
    float* dcat = ws + OFF_R5;
    float* t2   = ws + OFF_R5;
    float* zcq  = ws + OFF_ZCQ;
    unsigned short* hhp = (unsigned short*)(ws + OFF_HH);
    unsigned short* hlp = (unsigned short*)(ws + OFF_HL);
    unsigned short* wph = (unsigned short*)(ws + OFF_WH);
    unsigned short* wpl = (unsigned short*)(ws + OFF_WL);

    prep_norm_k<<<800, 128, 0, stream>>>(mkeys, mhard, knR, hn, hhp, hlp);
    prep_c0_k<<<1, 128, 0, stream>>>(mvals, c0);
    prep_w1_k<<<576, 256, 0, stream>>>(dw1, wph, wpl);

    ce1_k<<<16 * 2 * 6, 256, 0, stream>>>(x, cw1, cb1, zc1);
    se1_k<<<16 * 64, 256, 0, stream>>>(x, sw1, sb1, zs1);
    ce2_v3<<<16 * 16, 256, 0, stream>>>(zc1, cw2, cb2, zcq);
    se2_v2<<<16 * 16 * 16, 256, 0, stream>>>(zs1, sw2, sb2, zs);  // overwrites zc1 (dead)

    match_center_v2<<<648, 256, 0, stream>>>(zcq, knR, mvals, dcat);
    fill_c0_k<<<32768, 256, 0, stream>>>(c0, dcat);
    match_skip_v5<<<16 * 64, 256, 0, stream>>>(zs, hn, hhp, hlp, mhard, dcat);

    dec1_v7<<<2048, 256, 0, stream>>>(dcat, wph, wpl, db1, d1b);

    tconv_v3<64, 32, 8, 64><<<16 * 4 * 16, 256, 0, stream>>>(d1b, tw1, tb1, t1);    // overwrites zs (dead)
    tconv_v3<32, 16, 8, 128><<<16 * 2 * 64, 256, 0, stream>>>(t1, tw2, tb2, t2);    // overwrites dcat (dead)
    final_v2<<<1024, 256, 0, stream>>>(t2, dw2, db2, out);
}

// Round 14
// 918.058 us; speedup vs baseline: 1.9632x; 1.0963x over previous
//
#include <hip/hip_runtime.h>
#include <cstdint>
#include <cstddef>

#define NEG_INF (-3.0e38f)

typedef __attribute__((ext_vector_type(8))) short short8;
typedef __attribute__((ext_vector_type(4))) float f32x4;

__device__ inline unsigned short bf16_rne(float x) {
    unsigned u = __float_as_uint(x);
    unsigned r = u + 0x7fffu + ((u >> 16) & 1u);
    return (unsigned short)(r >> 16);
}
__device__ inline float bf16_tof(unsigned short h) {
    return __uint_as_float(((unsigned)h) << 16);
}

// ---------------- prep: normalize keys/hard + bf16 hi/lo split of hn ----------------
__global__ void prep_norm_k(const float* __restrict__ keys,
                            const float* __restrict__ hard,
                            float* __restrict__ knR,   // [800][128] normalized keys
                            float* __restrict__ hn,    // [800][128] normalized hard
                            unsigned short* __restrict__ hh,  // [800][128] bf16 hi
                            unsigned short* __restrict__ hl) {// [800][128] bf16 lo
    int m = blockIdx.x;      // 0..799
    int c = threadIdx.x;     // 0..127
    float kv = keys[m * 128 + c];
    float hv = hard[m * 128 + c];
    __shared__ float s1[128];
    __shared__ float s2[128];
    s1[c] = kv * kv;
    s2[c] = hv * hv;
    __syncthreads();
    for (int off = 64; off > 0; off >>= 1) {
        if (c < off) { s1[c] += s1[c + off]; s2[c] += s2[c + off]; }
        __syncthreads();
    }
    float ks = 1.0f / fmaxf(sqrtf(s1[0]), 1e-12f);
    float hs = 1.0f / fmaxf(sqrtf(s2[0]), 1e-12f);
    knR[m * 128 + c] = kv * ks;
    float hnv = hv * hs;
    hn[m * 128 + c] = hnv;
    unsigned short hi = bf16_rne(hnv);
    hh[m * 128 + c] = hi;
    hl[m * 128 + c] = bf16_rne(hnv - bf16_tof(hi));
}

__global__ void prep_c0_k(const float* __restrict__ values, float* __restrict__ c0) {
    int c = threadIdx.x;  // 128 threads
    float s = 0.f;
    for (int m = 0; m < 10; ++m) s += values[m * 128 + c];
    c0[c] = s * 0.1f;
}

// ---------------- prep: dec1 weights -> chunked bf16 hi/lo, MFMA A-layout w/ bank swizzle ----------------
__global__ void prep_w1_k(const float* __restrict__ dw1,   // (64,256,3,3)
                          unsigned short* __restrict__ wph,
                          unsigned short* __restrict__ wpl) {
    int idx = blockIdx.x * 256 + threadIdx.x;   // 147456 total
    int co = idx / 2304, r2 = idx % 2304;
    int ci = r2 / 9, tap = r2 % 9;
    float v = dw1[idx];
    int chunk = ci >> 5, cog = co >> 5, co32 = co & 31;
    int cil = ci & 31, g = cil >> 3, j = cil & 7;
    int gs = g ^ ((co32 >> 2) & 3);
    int off = ((((chunk * 9 + tap) * 2 + cog) * 32 + co32) * 4 + gs) * 8 + j;
    unsigned short hi = bf16_rne(v);
    wph[off] = hi;
    wpl[off] = bf16_rne(v - bf16_tof(hi));
}

// ---------------- center conv1+pool: only pooled rect [45,83)^2 ----------------
__global__ void ce1_k(const float* __restrict__ x,   // (16,1,256,256)
                      const float* __restrict__ w,   // (32,1,3,3)
                      const float* __restrict__ bias,
                      float* __restrict__ out) {     // (16,32,128,128) rect only
    int bx = blockIdx.x;            // 16 b * 2 cog * 6 tiles
    int b = bx / 12, rem = bx % 12;
    int cog = rem / 6, tile = rem % 6;
    int idx = tile * 256 + threadIdx.x;
    if (idx >= 1444) return;
    int ph = 45 + idx / 38, pw = 45 + idx % 38;
    const float* xb = x + (size_t)b * 65536;
    float win[4][4];
#pragma unroll
    for (int r = 0; r < 4; ++r) {
        int ih = 2 * ph - 1 + r;
        bool vr = (ih >= 96 && ih < 160);
#pragma unroll
        for (int c = 0; c < 4; ++c) {
            int iw = 2 * pw - 1 + c;
            win[r][c] = (vr && iw >= 96 && iw < 160) ? xb[ih * 256 + iw] : 0.f;
        }
    }
#pragma unroll
    for (int co8 = 0; co8 < 16; ++co8) {
        int co = cog * 16 + co8;
        const float* w9 = w + co * 9;
        float bv = bias[co];
        float a00 = bv, a01 = bv, a10 = bv, a11 = bv;
#pragma unroll
        for (int kh = 0; kh < 3; ++kh)
#pragma unroll
            for (int kw = 0; kw < 3; ++kw) {
                float wv = w9[kh * 3 + kw];
                a00 += win[kh][kw] * wv;
                a01 += win[kh][kw + 1] * wv;
                a10 += win[kh + 1][kw] * wv;
                a11 += win[kh + 1][kw + 1] * wv;
            }
        float mx = fmaxf(fmaxf(a00, a01), fmaxf(a10, a11));
        out[((size_t)b * 32 + co) * 16384 + ph * 128 + pw] = fmaxf(mx, 0.f);
    }
}

// ---------------- skip conv1+pool: full, 16 co per thread ----------------
__global__ void se1_k(const float* __restrict__ x,   // (16,1,256,256)
                      const float* __restrict__ w,   // (16,1,3,3)
                      const float* __restrict__ bias,
                      float* __restrict__ out) {     // (16,16,128,128)
    int bx = blockIdx.x;            // 16 b * 64 tiles
    int b = bx >> 6, tile = bx & 63;
    int idx = tile * 256 + threadIdx.x;   // 0..16383
    int ph = idx >> 7, pw = idx & 127;
    const float* xb = x + (size_t)b * 65536;
    float win[4][4];
#pragma unroll
    for (int r = 0; r < 4; ++r) {
        int ih = 2 * ph - 1 + r;
        bool vr = (ih >= 0 && ih < 256);
#pragma unroll
        for (int c = 0; c < 4; ++c) {
            int iw = 2 * pw - 1 + c;
            win[r][c] = (vr && iw >= 0 && iw < 256) ? xb[ih * 256 + iw] : 0.f;
        }
    }
#pragma unroll
    for (int co = 0; co < 16; ++co) {
        const float* w9 = w + co * 9;
        float bv = bias[co];
        float a00 = bv, a01 = bv, a10 = bv, a11 = bv;
#pragma unroll
        for (int kh = 0; kh < 3; ++kh)
#pragma unroll
            for (int kw = 0; kw < 3; ++kw) {
                float wv = w9[kh * 3 + kw];
                a00 += win[kh][kw] * wv;
                a01 += win[kh][kw + 1] * wv;
                a10 += win[kh + 1][kw] * wv;
                a11 += win[kh + 1][kw + 1] * wv;
            }
        float mx = fmaxf(fmaxf(a00, a01), fmaxf(a10, a11));
        out[((size_t)b * 16 + co) * 16384 + idx] = fmaxf(mx, 0.f);
    }
}

// ---------------- center conv2 v3 (32->128) + relu + pool -> query-major zcq ----------------
__global__ void __launch_bounds__(256) ce2_v3(
        const float* __restrict__ zc1,  // (16,32,128,128)
        const float* __restrict__ w,    // (128,32,3,3)
        const float* __restrict__ bias,
        float* __restrict__ zcq) {      // (16*324, 128) query-major
    int bx = blockIdx.x;                // 16 b * 16 cog
    int b = bx >> 4, cog = bx & 15;
    const float* ib = zc1 + (size_t)b * 32 * 16384;
    for (int px = threadIdx.x; px < 324; px += 256) {
        int h = 23 + px / 18, ww = 23 + px % 18;
        float acc[8][4];
#pragma unroll
        for (int c8 = 0; c8 < 8; ++c8)
#pragma unroll
            for (int t = 0; t < 4; ++t) acc[c8][t] = 0.f;
        for (int ci = 0; ci < 32; ++ci) {
            const float* p = ib + ci * 16384 + (2 * h - 1) * 128 + (2 * ww - 1);
            float win[4][4];
#pragma unroll
            for (int r = 0; r < 4; ++r)
#pragma unroll
                for (int s = 0; s < 4; ++s) win[r][s] = p[r * 128 + s];
#pragma unroll
            for (int c8 = 0; c8 < 8; ++c8) {
                const float* w9 = w + ((size_t)(cog * 8 + c8) * 32 + ci) * 9;
#pragma unroll
                for (int kh = 0; kh < 3; ++kh)
#pragma unroll
                    for (int kw = 0; kw < 3; ++kw) {
                        float wv = w9[kh * 3 + kw];
                        acc[c8][0] += win[kh][kw] * wv;
                        acc[c8][1] += win[kh][kw + 1] * wv;
                        acc[c8][2] += win[kh + 1][kw] * wv;
                        acc[c8][3] += win[kh + 1][kw + 1] * wv;
                    }
            }
        }
#pragma unroll
        for (int c8 = 0; c8 < 8; ++c8) {
            int co = cog * 8 + c8;
            float mx = fmaxf(fmaxf(acc[c8][0], acc[c8][1]), fmaxf(acc[c8][2], acc[c8][3])) + bias[co];
            zcq[((size_t)(b * 324 + px)) * 128 + co] = fmaxf(mx, 0.f);
        }
    }
}

// ---------------- skip conv2 (16->128) + relu + pool, 8 co per thread ----------------
__global__ void se2_v2(const float* __restrict__ zs1,  // (16,16,128,128)
                       const float* __restrict__ w,    // (128,16,3,3)
                       const float* __restrict__ bias,
                       float* __restrict__ zs) {       // (16,128,64,64)
    int bx = blockIdx.x;            // 16 b * 16 cog * 16 tiles = 4096
    int b = bx >> 8, rem = bx & 255;
    int cog = rem >> 4, tile = rem & 15;
    int px = tile * 256 + threadIdx.x;  // 0..4095
    int ph = px >> 6, pw = px & 63;
    const float* ib = zs1 + (size_t)b * 16 * 16384;
    float acc[8][4];
#pragma unroll
    for (int c8 = 0; c8 < 8; ++c8)
#pragma unroll
        for (int t = 0; t < 4; ++t) acc[c8][t] = 0.f;
    for (int ci = 0; ci < 16; ++ci) {
        const float* p = ib + ci * 16384;
        float win[4][4];
#pragma unroll
        for (int r = 0; r < 4; ++r) {
            int rr = 2 * ph - 1 + r;
            bool vr = (rr >= 0 && rr < 128);
#pragma unroll
            for (int s = 0; s < 4; ++s) {
                int cc = 2 * pw - 1 + s;
                win[r][s] = (vr && cc >= 0 && cc < 128) ? p[rr * 128 + cc] : 0.f;
            }
        }
#pragma unroll
        for (int c8 = 0; c8 < 8; ++c8) {
            const float* w9 = w + ((size_t)(cog * 8 + c8) * 16 + ci) * 9;
#pragma unroll
            for (int kh = 0; kh < 3; ++kh)
#pragma unroll
                for (int kw = 0; kw < 3; ++kw) {
                    float wv = w9[kh * 3 + kw];
                    acc[c8][0] += win[kh][kw] * wv;
                    acc[c8][1] += win[kh][kw + 1] * wv;
                    acc[c8][2] += win[kh + 1][kw] * wv;
                    acc[c8][3] += win[kh + 1][kw + 1] * wv;
                }
        }
    }
#pragma unroll
    for (int c8 = 0; c8 < 8; ++c8) {
        int co = cog * 8 + c8;
        float bv = bias[co];
        float mx = fmaxf(fmaxf(acc[c8][0], acc[c8][1]), fmaxf(acc[c8][2], acc[c8][3])) + bv;
        zs[((size_t)b * 128 + co) * 4096 + px] = fmaxf(mx, 0.f);
    }
}

// ---------------- center matching v2 (unchanged) ----------------
__global__ void __launch_bounds__(256) match_center_v2(
        const float* __restrict__ zcq,    // (16*324, 128) raw queries
        const float* __restrict__ knR,    // (800,128) normalized keys
        const float* __restrict__ values, // (800,128)
        float* __restrict__ dcat) {       // (16,256,64,64), ch 0..127
    __shared__ float shk[128 * 65];
    __shared__ float qint[4 * 256];
    int tid = threadIdx.x;
    int w = tid >> 6, lane = tid & 63;
    int g0 = blockIdx.x * 8 + 2 * w;

#pragma unroll
    for (int i = 0; i < 2; ++i) {
        const float* qp = zcq + (size_t)(g0 + i) * 128;
        float v0 = qp[lane], v1 = qp[lane + 64];
        float ss = v0 * v0 + v1 * v1;
#pragma unroll
        for (int off = 32; off > 0; off >>= 1) ss += __shfl_xor(ss, off);
        float sc = 1.0f / fmaxf(sqrtf(ss), 1e-12f);
        qint[w * 256 + lane * 2 + i] = v0 * sc;
        qint[w * 256 + (lane + 64) * 2 + i] = v1 * sc;
    }

    float sim2[2][13];
#pragma unroll
    for (int k = 0; k < 13; ++k) { sim2[0][k] = 0.f; sim2[1][k] = 0.f; }

    for (int chunk = 0; chunk < 13; ++chunk) {
        int mbase = chunk << 6;
        __syncthreads();
#pragma unroll
        for (int t = 0; t < 8; ++t) {
            int idx = tid + t * 256;
            int kk = idx >> 5, c4 = idx & 31;
            int m = mbase + kk;
            float4 kv = (m < 800) ? *(const float4*)(knR + (size_t)m * 128 + c4 * 4)
                                  : make_float4(0.f, 0.f, 0.f, 0.f);
            shk[(4 * c4 + 0) * 65 + kk] = kv.x;
            shk[(4 * c4 + 1) * 65 + kk] = kv.y;
            shk[(4 * c4 + 2) * 65 + kk] = kv.z;
            shk[(4 * c4 + 3) * 65 + kk] = kv.w;
        }
        __syncthreads();
        float s0 = sim2[0][chunk], s1 = sim2[1][chunk];
        const float* qw = qint + w * 256;
#pragma unroll 4
        for (int c2 = 0; c2 < 64; ++c2) {
            float4 qq = *(const float4*)(qw + c2 * 4);
            float k0 = shk[(2 * c2) * 65 + lane];
            float k1 = shk[(2 * c2 + 1) * 65 + lane];
            s0 += qq.x * k0; s1 += qq.y * k0;
            s0 += qq.z * k1; s1 += qq.w * k1;
        }
        sim2[0][chunk] = s0; sim2[1][chunk] = s1;
    }

#pragma unroll
    for (int i = 0; i < 2; ++i) {
        int g = g0 + i;
        int b = g / 324, q = g - b * 324;
        int h = 23 + q / 18, ww = 23 + q % 18;
        int p = h * 64 + ww;

        float sim[13];
#pragma unroll
        for (int k = 0; k < 13; ++k)
            sim[k] = (lane + (k << 6) < 800) ? sim2[i][k] : NEG_INF;

        float topv[11]; int topm[11];
#pragma unroll
        for (int t = 0; t < 11; ++t) {
            float bvv = NEG_INF; int bm = 0x7fffffff;
#pragma unroll
            for (int k = 0; k < 13; ++k) {
                if (sim[k] > bvv) { bvv = sim[k]; bm = lane + (k << 6); }
            }
#pragma unroll
            for (int off = 32; off > 0; off >>= 1) {
                float ov = __shfl_xor(bvv, off);
                int om = __shfl_xor(bm, off);
                if (ov > bvv || (ov == bvv && om < bm)) { bvv = ov; bm = om; }
            }
            topv[t] = bvv; topm[t] = bm;
            if ((bm & 63) == lane) {
                int kk = bm >> 6;
#pragma unroll
                for (int k = 0; k < 13; ++k)
                    if (k == kk) sim[k] = NEG_INF;
            }
        }
        if (topv[9] - topv[10] < 1e-4f) {
            double s9 = 0.0, s10 = 0.0;
            const float* k9 = knR + (size_t)topm[9] * 128;
            const float* k10 = knR + (size_t)topm[10] * 128;
            for (int c = 0; c < 128; ++c) {
                double qc = (double)qint[w * 256 + c * 2 + i];
                s9 += qc * (double)k9[c];
                s10 += qc * (double)k10[c];
            }
            if ((s10 > s9) || (s10 == s9 && topm[10] < topm[9])) {
                topv[9] = topv[10]; topm[9] = topm[10];
            }
        }
        float mx = topv[0];
        float e[10], ssum = 0.f;
#pragma unroll
        for (int t = 0; t < 10; ++t) { e[t] = expf(topv[t] - mx); ssum += e[t]; }
        float inv = 1.0f / ssum;
        float o0 = 0.f, o1 = 0.f;
#pragma unroll
        for (int t = 0; t < 10; ++t) {
            float wt = e[t] * inv;
            const float* vr = values + (size_t)topm[t] * 128;
            o0 += wt * vr[lane];
            o1 += wt * vr[lane + 64];
        }
        float* ob = dcat + ((size_t)b * 256) * 4096 + p;
        ob[(size_t)lane * 4096] = o0;
        ob[(size_t)(lane + 64) * 4096] = o1;
    }
}

// ---------------- constant fill for out-of-region center matches ----------------
__global__ void fill_c0_k(const float* __restrict__ c0, float* __restrict__ dcat) {
    int idx = blockIdx.x * 256 + threadIdx.x;
    int p = idx & 4095;
    int c = (idx >> 12) & 127;
    int b = idx >> 19;
    int h = p >> 6, ww = p & 63;
    if (h >= 23 && h <= 40 && ww >= 23 && ww <= 40) return;
    dcat[((size_t)b * 256 + c) * 4096 + p] = c0[c];
}

// ---------------- skip matching v5: split-bf16 MFMA, windowed exact rescore ----------------
__global__ void __launch_bounds__(256, 2) match_skip_v5(
        const float* __restrict__ zs,    // (16,128,64,64) raw queries
        const float* __restrict__ hn,    // (800,128) normalized fp32 (rescore)
        const unsigned short* __restrict__ hh,  // (800,128) bf16 hi
        const unsigned short* __restrict__ hl,  // (800,128) bf16 lo
        const float* __restrict__ hard,  // (800,128) raw
        float* __restrict__ dcat) {      // ch 128..255
    __shared__ unsigned short sm[32768]; // 64KB
    int b = blockIdx.x >> 6, pt = blockIdx.x & 63;
    int pbase = pt * 64;
    int tid = threadIdx.x;
    int w = tid >> 6, lane = tid & 63;
    int l15 = lane & 15, quad = lane >> 4;

    {
        int p = tid & 63, c0 = tid >> 6;
        for (int k = 0; k < 32; ++k) {
            int c = c0 + k * 4;
            float v = zs[((size_t)b * 128 + c) * 4096 + pbase + p];
            unsigned short hi = bf16_rne(v);
            unsigned short lo = bf16_rne(v - bf16_tof(hi));
            int off = p * 128 + (((c >> 3) ^ (p & 15)) << 3) + (c & 7);
            sm[off] = hi;
            sm[8192 + off] = lo;
        }
    }

    float v1[4], v2[4]; int i1[4], i2[4];
#pragma unroll
    for (int u = 0; u < 4; ++u) { v1[u] = NEG_INF; v2[u] = NEG_INF; i1[u] = 0x7fffffff; i2[u] = 0x7fffffff; }

    for (int chunk = 0; chunk < 13; ++chunk) {
        int mbase = chunk << 6;
        __syncthreads();
#pragma unroll
        for (int t = 0; t < 4; ++t) {
            int idx = tid + t * 256;          // 0..1023
            int row = idx >> 4, cb = idx & 15;
            int gm = mbase + row;
            uint4 dh = make_uint4(0u, 0u, 0u, 0u), dl = make_uint4(0u, 0u, 0u, 0u);
            if (gm < 800) {
                dh = *(const uint4*)(hh + (size_t)gm * 128 + cb * 8);
                dl = *(const uint4*)(hl + (size_t)gm * 128 + cb * 8);
            }
            int off = row * 128 + ((cb ^ (row & 15)) << 3);
            *(uint4*)&sm[16384 + off] = dh;
            *(uint4*)&sm[24576 + off] = dl;
        }
        __syncthreads();

        f32x4 acc[4];
#pragma unroll
        for (int kt = 0; kt < 4; ++kt) acc[kt] = (f32x4){0.f, 0.f, 0.f, 0.f};

#pragma unroll
        for (int ks = 0; ks < 4; ++ks) {
            int qrow = 16 * w + l15;
            int cb = ks * 4 + quad;
            int qoff = qrow * 128 + ((cb ^ (qrow & 15)) << 3);
            short8 ahi = *(const short8*)&sm[qoff];
            short8 alo = *(const short8*)&sm[8192 + qoff];
#pragma unroll
            for (int kt = 0; kt < 4; ++kt) {
                int krow = l15 + 16 * kt;
                int koff = krow * 128 + ((cb ^ (krow & 15)) << 3);
                short8 bhi = *(const short8*)&sm[16384 + koff];
                short8 blo = *(const short8*)&sm[24576 + koff];
                acc[kt] = __builtin_amdgcn_mfma_f32_16x16x32_bf16(alo, bhi, acc[kt], 0, 0, 0);
                acc[kt] = __builtin_amdgcn_mfma_f32_16x16x32_bf16(ahi, blo, acc[kt], 0, 0, 0);
                acc[kt] = __builtin_amdgcn_mfma_f32_16x16x32_bf16(ahi, bhi, acc[kt], 0, 0, 0);
            }
        }
#pragma unroll
        for (int kt = 0; kt < 4; ++kt) {
            int m = mbase + 16 * kt + l15;
            if (m < 800) {
#pragma unroll
                for (int u = 0; u < 4; ++u) {
                    float sv = acc[kt][u];
                    if (sv > v1[u] || (sv == v1[u] && m < i1[u])) {
                        v2[u] = v1[u]; i2[u] = i1[u]; v1[u] = sv; i1[u] = m;
                    } else if (sv > v2[u] || (sv == v2[u] && m < i2[u])) {
                        v2[u] = sv; i2[u] = m;
                    }
                }
            }
        }
    }
    __syncthreads();
    float4* red = (float4*)&sm[16384];   // [64 q][17 slots] float4 = 8704 shorts
#pragma unroll
    for (int u = 0; u < 4; ++u) {
        int q = 16 * w + quad * 4 + u;
        red[q * 17 + l15] = make_float4(v1[u], v2[u], __int_as_float(i1[u]), __int_as_float(i2[u]));
    }
    __syncthreads();
    int* bi_sh = (int*)&sm[16384 + 8704];  // [64] ints, in-bounds
    if (tid < 64) {
        int q = tid;
        float V1 = NEG_INF; int I1 = 0x7fffffff;
        for (int k = 0; k < 16; ++k) {
            float4 e = red[q * 17 + k];
            float cv[2] = { e.x, e.y };
            int ci_[2] = { __float_as_int(e.z), __float_as_int(e.w) };
#pragma unroll
            for (int t = 0; t < 2; ++t) {
                if (cv[t] > V1 || (cv[t] == V1 && ci_[t] < I1)) { V1 = cv[t]; I1 = ci_[t]; }
            }
        }
        float qn2 = 0.f;
        for (int c = 0; c < 128; ++c) {
            int off = q * 128 + (((c >> 3) ^ (q & 15)) << 3) + (c & 7);
            float qc = bf16_tof(sm[off]) + bf16_tof(sm[8192 + off]);
            qn2 += qc * qc;
        }
        float tau = 1.5e-4f * sqrtf(qn2) + 1e-12f;
        float thr = V1 - tau;
        int ncand = 0;
        for (int k = 0; k < 16; ++k) {
            float4 e = red[q * 17 + k];
            if (e.x >= thr && __float_as_int(e.z) != 0x7fffffff) ++ncand;
            if (e.y >= thr && __float_as_int(e.w) != 0x7fffffff) ++ncand;
        }
        int bi = I1;
        if (ncand > 1) {
            double bestd = -1.0e300; int besti = 0x7fffffff;
            for (int k = 0; k < 16; ++k) {
                float4 e = red[q * 17 + k];
                float cv[2] = { e.x, e.y };
                int ci_[2] = { __float_as_int(e.z), __float_as_int(e.w) };
                for (int t = 0; t < 2; ++t) {
                    if (cv[t] >= thr && ci_[t] != 0x7fffffff) {
                        const float* hr = hn + (size_t)ci_[t] * 128;
                        double d = 0.0;
                        for (int c = 0; c < 128; ++c) {
                            double qc = (double)zs[((size_t)b * 128 + c) * 4096 + pbase + q];
                            d += qc * (double)hr[c];
                        }
                        if (d > bestd || (d == bestd && ci_[t] < besti)) { bestd = d; besti = ci_[t]; }
                    }
                }
            }
            bi = besti;
        }
        bi_sh[q] = bi;
    }
    __syncthreads();
    {
        int q = tid & 63, seg = tid >> 6;
        int bi = bi_sh[q];
        const float* hr = hard + (size_t)bi * 128;
        float* ob = dcat + ((size_t)b * 256 + 128) * 4096 + pbase + q;
#pragma unroll
        for (int i = 0; i < 32; ++i) {
            int c = seg * 32 + i;
            ob[(size_t)c * 4096] = hr[c];
        }
    }
}

// ---------------- decoder conv1 v8: v6 structure + x-only register prefetch ----------------
// R13 lesson: 66-VGPR prefetch payload (x + weights) spilled (WRITE 594MB). v8 prefetches only
// the HBM-latency-dominated x stream (26 VGPRs); weights (L2-hot, 10 uint4) stay direct->LDS.
__global__ void __launch_bounds__(256, 2) dec1_v8(
        const float* __restrict__ dcat, // (16,256,64,64)
        const unsigned short* __restrict__ wph,  // prepped weights hi
        const unsigned short* __restrict__ wpl,  // prepped weights lo
        const float* __restrict__ bias,
        float* __restrict__ d1) {       // (16,64,64,64)
    __shared__ unsigned short smem[31104];
    int bx = blockIdx.x;                // 16 b * 64 r0 * 2 cog = 2048
    int b = bx >> 7, rem = bx & 127;
    int r0 = rem >> 1, cog = rem & 1;
    int tid = threadIdx.x;
    int w = tid >> 6, lane = tid & 63;
    int l15 = lane & 15, quad = lane >> 4;
    int mt = w & 1, nh = w >> 1;
    int gx = quad ^ ((l15 >> 2) & 3);

    int lofA[13], gofA[13];
#pragma unroll
    for (int k = 0; k < 13; ++k) {
        int f = tid + k * 256;
        lofA[k] = 0; gofA[k] = -1;
        if (f < 3168) {
            int p = f / 198, rm = f % 198;
            int row = rm / 66, col = rm % 66;
            lofA[k] = ((row * 4 + (p >> 2)) * 66 + col) * 8 + (p & 3) * 2;
            int gr = r0 - 1 + row, gc = col - 1;
            if (gr >= 0 && gr < 64 && gc >= 0 && gc < 64)
                gofA[k] = (2 * p) * 4096 + gr * 64 + gc;
        }
    }
#pragma unroll
    for (int k = 0; k < 13; ++k) {
        int f = tid + k * 256;
        if (f < 3168 && gofA[k] < 0) {
            *(unsigned*)&smem[lofA[k]] = 0u;
            *(unsigned*)&smem[6336 + lofA[k]] = 0u;
        }
    }

    float pfx0[13], pfx1[13];
    // load chunk-0 x into registers
    {
        const float* xb = dcat + ((size_t)b * 256) * 4096;
#pragma unroll
        for (int k = 0; k < 13; ++k)
            if (gofA[k] >= 0) { pfx0[k] = xb[gofA[k]]; pfx1[k] = xb[gofA[k] + 4096]; }
    }
    // store chunk-0 x; stage chunk-0 weights direct->LDS
#pragma unroll
    for (int k = 0; k < 13; ++k) {
        if (gofA[k] >= 0) {
            unsigned short h0 = bf16_rne(pfx0[k]), h1 = bf16_rne(pfx1[k]);
            unsigned short l0 = bf16_rne(pfx0[k] - bf16_tof(h0));
            unsigned short l1 = bf16_rne(pfx1[k] - bf16_tof(h1));
            *(unsigned*)&smem[lofA[k]] = (unsigned)h0 | ((unsigned)h1 << 16);
            *(unsigned*)&smem[6336 + lofA[k]] = (unsigned)l0 | ((unsigned)l1 << 16);
        }
    }
#pragma unroll
    for (int k = 0; k < 5; ++k) {
        int t = tid + k * 256;
        if (t < 1152) {
            int tap = t >> 7, wi = t & 127;
            size_t src = ((size_t)((0 * 9 + tap) * 2 + cog)) * 1024 + wi * 8;
            int dst = 12672 + tap * 1024 + wi * 8;
            *(uint4*)&smem[dst]        = *(const uint4*)(wph + src);
            *(uint4*)&smem[dst + 9216] = *(const uint4*)(wpl + src);
        }
    }
    __syncthreads();

    f32x4 acc[2];
    acc[0] = (f32x4){0.f, 0.f, 0.f, 0.f};
    acc[1] = (f32x4){0.f, 0.f, 0.f, 0.f};

    for (int chunk = 0; chunk < 8; ++chunk) {
        // issue x prefetch for chunk+1 (overlaps the MFMA phase below)
        if (chunk < 7) {
            const float* xb = dcat + ((size_t)b * 256 + (chunk + 1) * 32) * 4096;
#pragma unroll
            for (int k = 0; k < 13; ++k)
                if (gofA[k] >= 0) { pfx0[k] = xb[gofA[k]]; pfx1[k] = xb[gofA[k] + 4096]; }
        }
        // compute current chunk from LDS
#pragma unroll
        for (int tap = 0; tap < 9; ++tap) {
            int kh = tap / 3, kw = tap % 3;
            int aoff = 12672 + tap * 1024 + (mt * 16 + l15) * 32 + gx * 8;
            short8 ahi = *(const short8*)&smem[aoff];
            short8 alo = *(const short8*)&smem[aoff + 9216];
#pragma unroll
            for (int n2 = 0; n2 < 2; ++n2) {
                int nt = nh * 2 + n2;
                int boff = ((kh * 4 + quad) * 66 + nt * 16 + l15 + kw) * 8;
                short8 bhi = *(const short8*)&smem[boff];
                short8 blo = *(const short8*)&smem[boff + 6336];
                acc[n2] = __builtin_amdgcn_mfma_f32_16x16x32_bf16(alo, bhi, acc[n2], 0, 0, 0);
                acc[n2] = __builtin_amdgcn_mfma_f32_16x16x32_bf16(ahi, blo, acc[n2], 0, 0, 0);
                acc[n2] = __builtin_amdgcn_mfma_f32_16x16x32_bf16(ahi, bhi, acc[n2], 0, 0, 0);
            }
        }
        if (chunk < 7) {
            __syncthreads();   // all waves done reading current LDS
            // store prefetched x; stage next weights direct->LDS (L2-hot)
#pragma unroll
            for (int k = 0; k < 13; ++k) {
                if (gofA[k] >= 0) {
                    unsigned short h0 = bf16_rne(pfx0[k]), h1 = bf16_rne(pfx1[k]);
                    unsigned short l0 = bf16_rne(pfx0[k] - bf16_tof(h0));
                    unsigned short l1 = bf16_rne(pfx1[k] - bf16_tof(h1));
                    *(unsigned*)&smem[lofA[k]] = (unsigned)h0 | ((unsigned)h1 << 16);
                    *(unsigned*)&smem[6336 + lofA[k]] = (unsigned)l0 | ((unsigned)l1 << 16);
                }
            }
#pragma unroll
            for (int k = 0; k < 5; ++k) {
                int t = tid + k * 256;
                if (t < 1152) {
                    int tap = t >> 7, wi = t & 127;
                    size_t src = ((size_t)(((chunk + 1) * 9 + tap) * 2 + cog)) * 1024 + wi * 8;
                    int dst = 12672 + tap * 1024 + wi * 8;
                    *(uint4*)&smem[dst]        = *(const uint4*)(wph + src);
                    *(uint4*)&smem[dst + 9216] = *(const uint4*)(wpl + src);
                }
            }
            __syncthreads();
        }
    }
#pragma unroll
    for (int n2 = 0; n2 < 2; ++n2) {
        int nt = nh * 2 + n2;
#pragma unroll
        for (int u = 0; u < 4; ++u) {
            int co = cog * 32 + mt * 16 + quad * 4 + u;
            float v = acc[n2][u] + bias[co];
            d1[((size_t)b * 64 + co) * 4096 + r0 * 64 + nt * 16 + l15] = fmaxf(v, 0.f);
        }
    }
}

// ---------------- transposed conv v3: quad-parity, weights staged in LDS, COG=8 ----------------
template <int CIN, int COUT, int COG, int H>
__global__ void __launch_bounds__(256) tconv_v3(
        const float* __restrict__ x,   // (16,CIN,H,H)
        const float* __restrict__ w,   // (CIN,COUT,4,4)
        const float* __restrict__ bias,
        float* __restrict__ out) {     // (16,COUT,2H,2H)
    constexpr int NCOG = COUT / COG;
    constexpr int TPS = H / 16;
    constexpr int TILES = TPS * TPS;
    constexpr int HO = 2 * H;
    __shared__ float wsh[CIN * COG * 16];
    int bx = blockIdx.x;
    int b = bx / (NCOG * TILES), rem = bx % (NCOG * TILES);
    int cog = rem / TILES, tile = rem % TILES;
    int ti = tile / TPS, tj = tile % TPS;
    int tid = threadIdx.x;

    for (int f = tid; f < CIN * COG * 4; f += 256) {
        int ci = f / (COG * 4), r = f % (COG * 4);
        int co = r >> 2, qq = r & 3;
        *(float4*)&wsh[(ci * COG + co) * 16 + qq * 4] =
            *(const float4*)(w + (((size_t)ci * COUT + cog * COG + co) << 4) + qq * 4);
    }
    __syncthreads();

    int i = ti * 16 + (tid >> 4);
    int j = tj * 16 + (tid & 15);

    float acc[2][2][COG];
#pragma unroll
    for (int pr = 0; pr < 2; ++pr)
#pragma unroll
        for (int pc = 0; pc < 2; ++pc)
#pragma unroll
            for (int co = 0; co < COG; ++co) acc[pr][pc][co] = 0.f;

    const float* xb = x + (size_t)b * CIN * H * H;
    for (int ci = 0; ci < CIN; ++ci) {
        const float* xp = xb + (size_t)ci * H * H;
        float xr[3][3];
#pragma unroll
        for (int dr = 0; dr < 3; ++dr) {
            int gr = i - 1 + dr;
            bool vr = (gr >= 0 && gr < H);
#pragma unroll
            for (int dc = 0; dc < 3; ++dc) {
                int gc = j - 1 + dc;
                xr[dr][dc] = (vr && gc >= 0 && gc < H) ? xp[gr * H + gc] : 0.f;
            }
        }
        const float* wp = &wsh[ci * COG * 16];
#pragma unroll
        for (int co = 0; co < COG; ++co) {
            float4 w0 = *(const float4*)(wp + co * 16);
            float4 w1 = *(const float4*)(wp + co * 16 + 4);
            float4 w2 = *(const float4*)(wp + co * 16 + 8);
            float4 w3 = *(const float4*)(wp + co * 16 + 12);
            float wr[16] = { w0.x, w0.y, w0.z, w0.w, w1.x, w1.y, w1.z, w1.w,
                             w2.x, w2.y, w2.z, w2.w, w3.x, w3.y, w3.z, w3.w };
#pragma unroll
            for (int pr = 0; pr < 2; ++pr)
#pragma unroll
                for (int a = 0; a < 2; ++a)
#pragma unroll
                    for (int pc = 0; pc < 2; ++pc)
#pragma unroll
                        for (int bb = 0; bb < 2; ++bb)
                            acc[pr][pc][co] += xr[pr + a][pc + bb] *
                                               wr[(3 - pr - 2 * a) * 4 + (3 - pc - 2 * bb)];
        }
    }
#pragma unroll
    for (int co = 0; co < COG; ++co) {
        float bv = bias[cog * COG + co];
        float* ob = out + ((size_t)b * COUT + cog * COG + co) * HO * HO;
#pragma unroll
        for (int pr = 0; pr < 2; ++pr)
#pragma unroll
            for (int pc = 0; pc < 2; ++pc)
                ob[(2 * i + pr) * HO + 2 * j + pc] = fmaxf(acc[pr][pc][co] + bv, 0.f);
    }
}

// ---------------- final conv (16->1) 3x3, 4 px per thread ----------------
__global__ void final_v2(const float* __restrict__ t2,  // (16,16,256,256)
                         const float* __restrict__ w,   // (1,16,3,3)
                         const float* __restrict__ bias,
                         float* __restrict__ out) {     // (16,1,256,256)
    int g = blockIdx.x * 256 + threadIdx.x;
    int pxb = g * 4;
    int b = pxb >> 16, p = pxb & 65535;
    int h = p >> 8, c0 = p & 255;
    const float* tb = t2 + (size_t)b * 16 * 65536;
    float acc[4];
    float bv = bias[0];
#pragma unroll
    for (int t = 0; t < 4; ++t) acc[t] = bv;
    for (int ci = 0; ci < 16; ++ci) {
        const float* pp = tb + (size_t)ci * 65536;
        const float* w9 = w + ci * 9;
        float win[3][6];
#pragma unroll
        for (int dr = 0; dr < 3; ++dr) {
            int rr = h - 1 + dr;
            bool vr = (rr >= 0 && rr < 256);
#pragma unroll
            for (int dc = 0; dc < 6; ++dc) {
                int cc = c0 - 1 + dc;
                win[dr][dc] = (vr && cc >= 0 && cc < 256) ? pp[rr * 256 + cc] : 0.f;
            }
        }
#pragma unroll
        for (int t = 0; t < 4; ++t)
#pragma unroll
            for (int dr = 0; dr < 3; ++dr)
#pragma unroll
                for (int dc = 0; dc < 3; ++dc)
                    acc[t] += win[dr][t + dc] * w9[dr * 3 + dc];
    }
    *(float4*)(out + pxb) = make_float4(acc[0], acc[1], acc[2], acc[3]);
}

// ---------------- launch ----------------
extern "C" void kernel_launch(void* const* d_in, const int* in_sizes, int n_in,
                              void* d_out, int out_size, void* d_ws, size_t ws_size,
                              hipStream_t stream) {
    (void)in_sizes; (void)n_in; (void)out_size; (void)ws_size;
    const float* x     = (const float*)d_in[0];
    const float* cw1   = (const float*)d_in[1];
    const float* cb1   = (const float*)d_in[2];
    const float* cw2   = (const float*)d_in[3];
    const float* cb2   = (const float*)d_in[4];
    const float* sw1   = (const float*)d_in[5];
    const float* sb1   = (const float*)d_in[6];
    const float* sw2   = (const float*)d_in[7];
    const float* sb2   = (const float*)d_in[8];
    const float* mkeys = (const float*)d_in[9];
    const float* mvals = (const float*)d_in[10];
    const float* mhard = (const float*)d_in[11];
    const float* dw1   = (const float*)d_in[12];
    const float* db1   = (const float*)d_in[13];
    const float* tw1   = (const float*)d_in[14];
    const float* tb1   = (const float*)d_in[15];
    const float* tw2   = (const float*)d_in[16];
    const float* tb2   = (const float*)d_in[17];
    const float* dw2   = (const float*)d_in[18];
    const float* db2   = (const float*)d_in[19];
    float* out = (float*)d_out;
    float* ws  = (float*)d_ws;

    const size_t OFF_KN  = 0;                   // knR: 800*128
    const size_t OFF_HN  = 102400;              // hn:  800*128
    const size_t OFF_C0  = 204800;              // c0:  128
    const size_t OFF_R14 = 204928;              // zc1 -> zs -> t1
    const size_t OFF_R2  = OFF_R14 + 8388608;   // (spare)
    const size_t OFF_R3  = OFF_R2 + 8388608;    // zs1 -> d1
    const size_t OFF_R5  = OFF_R3 + 4194304;    // dcat -> t2
    const size_t OFF_ZCQ = OFF_R5 + 16777216;   // zcq: 16*324*128
    const size_t OFF_HH  = OFF_ZCQ + 663552;    // hh
    const size_t OFF_HL  = OFF_HH + 51200;      // hl
    const size_t OFF_WH  = OFF_HL + 51200;      // wph
    const size_t OFF_WL  = OFF_WH + 73728;      // wpl

    float* knR  = ws + OFF_KN;
    float* hn   = ws + OFF_HN;
    float* c0   = ws + OFF_C0;
    float* zc1  = ws + OFF_R14;
    float* zs   = ws + OFF_R14;
    float* t1   = ws + OFF_R14;
    float* zs1  = ws + OFF_R3;
    float* d1b  = ws + OFF_R3;
    float* dcat = ws + OFF_R5;
    float* t2   = ws + OFF_R5;
    float* zcq  = ws + OFF_ZCQ;
    unsigned short* hhp = (unsigned short*)(ws + OFF_HH);
    unsigned short* hlp = (unsigned short*)(ws + OFF_HL);
    unsigned short* wph = (unsigned short*)(ws + OFF_WH);
    unsigned short* wpl = (unsigned short*)(ws + OFF_WL);

    prep_norm_k<<<800, 128, 0, stream>>>(mkeys, mhard, knR, hn, hhp, hlp);
    prep_c0_k<<<1, 128, 0, stream>>>(mvals, c0);
    prep_w1_k<<<576, 256, 0, stream>>>(dw1, wph, wpl);

    ce1_k<<<16 * 2 * 6, 256, 0, stream>>>(x, cw1, cb1, zc1);
    se1_k<<<16 * 64, 256, 0, stream>>>(x, sw1, sb1, zs1);
    ce2_v3<<<16 * 16, 256, 0, stream>>>(zc1, cw2, cb2, zcq);
    se2_v2<<<16 * 16 * 16, 256, 0, stream>>>(zs1, sw2, sb2, zs);  // overwrites zc1 (dead)

    match_center_v2<<<648, 256, 0, stream>>>(zcq, knR, mvals, dcat);
    fill_c0_k<<<32768, 256, 0, stream>>>(c0, dcat);
    match_skip_v5<<<16 * 64, 256, 0, stream>>>(zs, hn, hhp, hlp, mhard, dcat);

    dec1_v8<<<2048, 256, 0, stream>>>(dcat, wph, wpl, db1, d1b);

    tconv_v3<64, 32, 8, 64><<<16 * 4 * 16, 256, 0, stream>>>(d1b, tw1, tb1, t1);    // overwrites zs (dead)
    tconv_v3<32, 16, 8, 128><<<16 * 2 * 64, 256, 0, stream>>>(t1, tw2, tb2, t2);    // overwrites dcat (dead)
    final_v2<<<1024, 256, 0, stream>>>(t2, dw2, db2, out);
}